// Round 1
// baseline (1309.704 us; speedup 1.0000x reference)
//
#include <hip/hip_runtime.h>

// UserGraphNet: B=64 graphs, n=714 nodes, E=16384 edges (+n self loops), C=128.
// Pipeline: embed-gather fused GEMM -> GCN -> 3x(GAT,GAT with residual) -> GCN -> FC -> FC.
// All fp32. Aggregations via per-graph CSR (by col) built once per call.

#define BB 64
#define NN 714
#define EE 16384
#define ET (EE + NN)          // 17098 edges incl self loops
#define NBt (BB * NN)         // 45696 total nodes
#define CC 128
#define RP (NN + 1)           // rowptr entries per graph

__device__ __forceinline__ float lrelu01(float x) { return x > 0.f ? x : 0.01f * x; }
__device__ __forceinline__ float lrelu2(float x)  { return x > 0.f ? x : 0.2f  * x; }

__device__ __forceinline__ float wsum(float x) {
#pragma unroll
    for (int o = 32; o > 0; o >>= 1) x += __shfl_xor(x, o);
    return x;
}
__device__ __forceinline__ float wmax(float x) {
#pragma unroll
    for (int o = 32; o > 0; o >>= 1) x = fmaxf(x, __shfl_xor(x, o));
    return x;
}

// ---- edge prep: int64->int32 row/col (self loops appended), in-degree count ----
__global__ void k_edge_prep(const int* __restrict__ edges, int* __restrict__ row32,
                            int* __restrict__ col32, float* __restrict__ deg) {
    int idx = blockIdx.x * blockDim.x + threadIdx.x;
    if (idx >= BB * ET) return;
    int b = idx / ET, e = idx - b * ET;
    int r, c;
    if (e < EE) { r = edges[b * 2 * EE + e]; c = edges[b * 2 * EE + EE + e]; }
    else        { r = c = e - EE; }
    row32[idx] = r; col32[idx] = c;
    atomicAdd(&deg[b * NN + c], 1.0f);
}

// ---- per-graph prefix scan of deg -> rowptr/cursor; dinv = rsqrt(deg) ----
__global__ void k_scan(float* degdinv, int* __restrict__ rowptr, int* __restrict__ cursor) {
    __shared__ int s[1024];
    int b = blockIdx.x, v = threadIdx.x;
    int cnt = 0; float d = 0.f;
    if (v < NN) { d = degdinv[b * NN + v]; cnt = (int)d; }
    s[v] = cnt;
    __syncthreads();
    for (int off = 1; off < 1024; off <<= 1) {
        int val = (v >= off) ? s[v - off] : 0;
        __syncthreads();
        s[v] += val;
        __syncthreads();
    }
    if (v < NN) {
        degdinv[b * NN + v] = d > 0.f ? rsqrtf(d) : 0.f;
        rowptr[b * RP + v + 1] = s[v];
        cursor[b * RP + v] = (v == 0) ? 0 : s[v - 1];
    }
    if (v == 0) rowptr[b * RP] = 0;
}

// ---- scatter edges into CSR slots (order within a segment nondeterministic; fp-noise only) ----
__global__ void k_scatter(const int* __restrict__ row32, const int* __restrict__ col32,
                          int* __restrict__ cursor, int* __restrict__ csr_row) {
    int idx = blockIdx.x * blockDim.x + threadIdx.x;
    if (idx >= BB * ET) return;
    int b = idx / ET;
    int c = col32[idx];
    int slot = atomicAdd(&cursor[b * RP + c], 1);
    csr_row[b * ET + slot] = row32[idx];
}

// ---- fused embedding-gather + X@W_in : out[g][c] (no bias yet) ----
__global__ __launch_bounds__(128) void k_embed_gemm(
    const int* __restrict__ feature, const float* __restrict__ poi,
    const float* __restrict__ cat, const float* __restrict__ lat,
    const float* __restrict__ lon, const float* __restrict__ Wi,
    float* __restrict__ out) {
    __shared__ __align__(16) float xs[8 * 800];
    int tx = threadIdx.x;
    int g0 = blockIdx.x * 8;
#pragma unroll
    for (int j = 0; j < 8; ++j) {
        int g = g0 + j;
        const int* f = feature + g * 5;
        int f0 = f[0], f1 = f[1], f3 = f[3], f4 = f[4];
        for (int k = tx; k < 800; k += 128) {
            float val;
            if (k < 300)      val = poi[f0 * 300 + k];
            else if (k < 400) val = cat[f1 * 100 + (k - 300)];
            else if (k < 600) val = lat[f3 * 200 + (k - 400)];
            else              val = lon[f4 * 200 + (k - 600)];
            xs[j * 800 + k] = val;
        }
    }
    __syncthreads();
    float acc[8] = {0, 0, 0, 0, 0, 0, 0, 0};
    const float4* xs4 = (const float4*)xs;
    for (int k4 = 0; k4 < 200; ++k4) {
        int kb = k4 * 4;
        float w0 = Wi[(kb + 0) * CC + tx];
        float w1 = Wi[(kb + 1) * CC + tx];
        float w2 = Wi[(kb + 2) * CC + tx];
        float w3 = Wi[(kb + 3) * CC + tx];
#pragma unroll
        for (int j = 0; j < 8; ++j) {
            float4 x = xs4[j * 200 + k4];
            acc[j] = fmaf(x.x, w0, acc[j]);
            acc[j] = fmaf(x.y, w1, acc[j]);
            acc[j] = fmaf(x.z, w2, acc[j]);
            acc[j] = fmaf(x.w, w3, acc[j]);
        }
    }
#pragma unroll
    for (int j = 0; j < 8; ++j) out[(size_t)(g0 + j) * CC + tx] = acc[j];
}

// ---- GCN aggregate: out[v] = lrelu01( dinv[v]*sum_e dinv[r]*H[r] + bias ) ----
__global__ __launch_bounds__(256) void k_gcn_agg(
    const float* __restrict__ H, const float* __restrict__ dinv,
    const int* __restrict__ rowptr, const int* __restrict__ csr_row,
    const float* __restrict__ bias, float* __restrict__ out) {
    int wid = threadIdx.x >> 6, lane = threadIdx.x & 63;
    int g = blockIdx.x * 4 + wid;
    int b = g / NN, v = g - b * NN;
    int s0 = rowptr[b * RP + v], s1 = rowptr[b * RP + v + 1];
    float dv = dinv[g];
    float a0 = 0.f, a1 = 0.f;
    for (int j = s0; j < s1; ++j) {
        int r = csr_row[b * ET + j];
        float dr = dinv[b * NN + r];
        const float* Hr = H + (size_t)(b * NN + r) * CC;
        a0 = fmaf(dr, Hr[lane], a0);
        a1 = fmaf(dr, Hr[64 + lane], a1);
    }
    out[(size_t)g * CC + lane]      = lrelu01(a0 * dv + bias[lane]);
    out[(size_t)g * CC + 64 + lane] = lrelu01(a1 * dv + bias[64 + lane]);
}

// ---- GAT gemm: Hp = h@W, plus fused asrc = Hp.a_src, adst = Hp.a_dst ----
__global__ __launch_bounds__(128) void k_gat_gemm(
    const float* __restrict__ hin, const float* __restrict__ W,
    const float* __restrict__ avs, const float* __restrict__ avd,
    float* __restrict__ Hp, float* __restrict__ asrc, float* __restrict__ adst) {
    __shared__ __align__(16) float hs[8 * CC];
    __shared__ float part[2][8][2];
    int tx = threadIdx.x;
    int g0 = blockIdx.x * 8;
#pragma unroll
    for (int j = 0; j < 8; ++j) hs[j * CC + tx] = hin[(size_t)(g0 + j) * CC + tx];
    __syncthreads();
    float a_s = avs[tx], a_d = avd[tx];
    float acc[8] = {0, 0, 0, 0, 0, 0, 0, 0};
    const float4* hs4 = (const float4*)hs;
    for (int k4 = 0; k4 < 32; ++k4) {
        int kb = k4 * 4;
        float w0 = W[(kb + 0) * CC + tx];
        float w1 = W[(kb + 1) * CC + tx];
        float w2 = W[(kb + 2) * CC + tx];
        float w3 = W[(kb + 3) * CC + tx];
#pragma unroll
        for (int j = 0; j < 8; ++j) {
            float4 x = hs4[j * 32 + k4];
            acc[j] = fmaf(x.x, w0, acc[j]);
            acc[j] = fmaf(x.y, w1, acc[j]);
            acc[j] = fmaf(x.z, w2, acc[j]);
            acc[j] = fmaf(x.w, w3, acc[j]);
        }
    }
    int wv = tx >> 6, lane = tx & 63;
#pragma unroll
    for (int j = 0; j < 8; ++j) {
        Hp[(size_t)(g0 + j) * CC + tx] = acc[j];
        float ps = wsum(acc[j] * a_s);
        float pd = wsum(acc[j] * a_d);
        if (lane == 0) { part[wv][j][0] = ps; part[wv][j][1] = pd; }
    }
    __syncthreads();
    if (tx < 8) {
        asrc[g0 + tx] = part[0][tx][0] + part[1][tx][0];
        adst[g0 + tx] = part[0][tx][1] + part[1][tx][1];
    }
}

// ---- GAT aggregate with online softmax over incoming edges ----
// MODE 0: out = lrelu01(t)+t (first GAT of unit); MODE 1: out = lrelu01(t).
template <int MODE>
__global__ __launch_bounds__(256) void k_gat_agg(
    const float* __restrict__ Hp, const float* __restrict__ asrc,
    const float* __restrict__ adst, const int* __restrict__ rowptr,
    const int* __restrict__ csr_row, const float* __restrict__ bias,
    float* __restrict__ out) {
    int wid = threadIdx.x >> 6, lane = threadIdx.x & 63;
    int g = blockIdx.x * 4 + wid;
    int b = g / NN, v = g - b * NN;
    int s0 = rowptr[b * RP + v], s1 = rowptr[b * RP + v + 1];
    float adv = adst[g];
    float m = -3.0e38f;
    for (int j = s0 + lane; j < s1; j += 64) {
        int r = csr_row[b * ET + j];
        m = fmaxf(m, lrelu2(asrc[b * NN + r] + adv));
    }
    m = wmax(m);
    float ssum = 0.f;
    for (int j = s0 + lane; j < s1; j += 64) {
        int r = csr_row[b * ET + j];
        ssum += __expf(lrelu2(asrc[b * NN + r] + adv) - m);
    }
    ssum = wsum(ssum);
    float inv = 1.f / (ssum + 1e-16f);
    float a0 = 0.f, a1 = 0.f;
    for (int j = s0; j < s1; ++j) {
        int r = csr_row[b * ET + j];
        float e = lrelu2(asrc[b * NN + r] + adv);
        float w = __expf(e - m) * inv;
        const float* Hr = Hp + (size_t)(b * NN + r) * CC;
        a0 = fmaf(w, Hr[lane], a0);
        a1 = fmaf(w, Hr[64 + lane], a1);
    }
    float t0 = a0 + bias[lane], t1 = a1 + bias[64 + lane];
    if (MODE == 0) {
        out[(size_t)g * CC + lane]      = lrelu01(t0) + t0;
        out[(size_t)g * CC + 64 + lane] = lrelu01(t1) + t1;
    } else {
        out[(size_t)g * CC + lane]      = lrelu01(t0);
        out[(size_t)g * CC + 64 + lane] = lrelu01(t1);
    }
}

// ---- GCN2 per-node dot: p[g] = h[g,:].W_out ----
__global__ __launch_bounds__(256) void k_out_dot(
    const float* __restrict__ h, const float* __restrict__ Wout,
    float* __restrict__ p) {
    int wid = threadIdx.x >> 6, lane = threadIdx.x & 63;
    int g = blockIdx.x * 4 + wid;
    float x = h[(size_t)g * CC + lane] * Wout[lane] + h[(size_t)g * CC + 64 + lane] * Wout[64 + lane];
    x = wsum(x);
    if (lane == 0) p[g] = x;
}

// ---- GCN2 aggregate (scalar features) -> g vector ----
__global__ __launch_bounds__(256) void k_out_agg(
    const float* __restrict__ p, const float* __restrict__ dinv,
    const int* __restrict__ rowptr, const int* __restrict__ csr_row,
    const float* __restrict__ bout, float* __restrict__ gv) {
    int wid = threadIdx.x >> 6, lane = threadIdx.x & 63;
    int g = blockIdx.x * 4 + wid;
    int b = g / NN, v = g - b * NN;
    int s0 = rowptr[b * RP + v], s1 = rowptr[b * RP + v + 1];
    float acc = 0.f;
    for (int j = s0 + lane; j < s1; j += 64) {
        int r = csr_row[b * ET + j];
        acc += dinv[b * NN + r] * p[b * NN + r];
    }
    acc = wsum(acc);
    if (lane == 0) gv[g] = lrelu01(acc * dinv[g] + bout[0]);
}

// ---- FC head: out = lrelu01(g@W1+b1) @ W2 + b2 ----
__global__ __launch_bounds__(128) void k_fc(
    const float* __restrict__ gv, const float* __restrict__ W1,
    const float* __restrict__ b1, const float* __restrict__ W2,
    const float* __restrict__ b2, float* __restrict__ outp) {
    __shared__ float gs[NN];
    __shared__ float s1[CC];
    int b = blockIdx.x, tx = threadIdx.x;
    for (int v = tx; v < NN; v += 128) gs[v] = gv[b * NN + v];
    __syncthreads();
    float acc = 0.f;
    for (int v = 0; v < NN; ++v) acc = fmaf(gs[v], W1[v * CC + tx], acc);
    float t = lrelu01(acc + b1[tx]);
    s1[tx] = t;
    __syncthreads();
    float acc2 = 0.f;
#pragma unroll
    for (int k = 0; k < CC; ++k) acc2 = fmaf(s1[k], W2[k * CC + tx], acc2);
    outp[b * CC + tx] = acc2 + b2[tx];
}

extern "C" void kernel_launch(void* const* d_in, const int* in_sizes, int n_in,
                              void* d_out, int out_size, void* d_ws, size_t ws_size,
                              hipStream_t stream) {
    const int*   feature  = (const int*)d_in[0];
    const int*   edges    = (const int*)d_in[1];
    // d_in[2] = weight (unused by the math)
    const float* poi      = (const float*)d_in[3];
    const float* cat      = (const float*)d_in[4];
    const float* lat      = (const float*)d_in[5];
    const float* lon      = (const float*)d_in[6];
    const float* W_in     = (const float*)d_in[7];
    const float* b_in     = (const float*)d_in[8];
    const float* gat_W    = (const float*)d_in[9];
    const float* gat_asrc = (const float*)d_in[10];
    const float* gat_adst = (const float*)d_in[11];
    const float* gat_b    = (const float*)d_in[12];
    const float* W_out    = (const float*)d_in[13];
    const float* b_out    = (const float*)d_in[14];
    const float* W_fc1    = (const float*)d_in[15];
    const float* b_fc1    = (const float*)d_in[16];
    const float* W_fc2    = (const float*)d_in[17];
    const float* b_fc2    = (const float*)d_in[18];
    float* outp = (float*)d_out;

    // workspace layout (~61 MB)
    char* ws = (char*)d_ws;
    size_t off = 0;
    auto take = [&](size_t bytes) -> char* {
        char* pp = ws + off;
        off = (off + bytes + 255) & ~(size_t)255;
        return pp;
    };
    int*   row32  = (int*)take((size_t)BB * ET * 4);
    int*   col32  = (int*)take((size_t)BB * ET * 4);
    int*   csr    = (int*)take((size_t)BB * ET * 4);
    int*   rowptr = (int*)take((size_t)BB * RP * 4);
    int*   cursor = (int*)take((size_t)BB * RP * 4);
    float* dinv   = (float*)take((size_t)NBt * 4);
    float* asrc   = (float*)take((size_t)NBt * 4);
    float* adst   = (float*)take((size_t)NBt * 4);
    float* pscal  = (float*)take((size_t)NBt * 4);
    float* gvec   = (float*)take((size_t)NBt * 4);
    float* bufA   = (float*)take((size_t)NBt * CC * 4);
    float* bufB   = (float*)take((size_t)NBt * CC * 4);

    const int nE = BB * ET;
    hipMemsetAsync(dinv, 0, (size_t)NBt * 4, stream);
    k_edge_prep<<<(nE + 255) / 256, 256, 0, stream>>>(edges, row32, col32, dinv);
    k_scan<<<BB, 1024, 0, stream>>>(dinv, rowptr, cursor);
    k_scatter<<<(nE + 255) / 256, 256, 0, stream>>>(row32, col32, cursor, csr);

    k_embed_gemm<<<NBt / 8, 128, 0, stream>>>(feature, poi, cat, lat, lon, W_in, bufB);
    k_gcn_agg<<<NBt / 4, 256, 0, stream>>>(bufB, dinv, rowptr, csr, b_in, bufA);

    for (int i = 0; i < 3; ++i) {
        const float* W  = gat_W + (size_t)i * CC * CC;
        const float* as = gat_asrc + (size_t)i * CC;
        const float* ad = gat_adst + (size_t)i * CC;
        const float* gb = gat_b + (size_t)i * CC;
        k_gat_gemm<<<NBt / 8, 128, 0, stream>>>(bufA, W, as, ad, bufB, asrc, adst);
        k_gat_agg<0><<<NBt / 4, 256, 0, stream>>>(bufB, asrc, adst, rowptr, csr, gb, bufA);
        k_gat_gemm<<<NBt / 8, 128, 0, stream>>>(bufA, W, as, ad, bufB, asrc, adst);
        k_gat_agg<1><<<NBt / 4, 256, 0, stream>>>(bufB, asrc, adst, rowptr, csr, gb, bufA);
    }

    k_out_dot<<<NBt / 4, 256, 0, stream>>>(bufA, W_out, pscal);
    k_out_agg<<<NBt / 4, 256, 0, stream>>>(pscal, dinv, rowptr, csr, b_out, gvec);
    k_fc<<<BB, 128, 0, stream>>>(gvec, W_fc1, b_fc1, W_fc2, b_fc2, outp);
}

// Round 3
// 805.356 us; speedup vs baseline: 1.6262x; 1.6262x over previous
//
#include <hip/hip_runtime.h>

// UserGraphNet: B=64 graphs, n=714 nodes, E=16384 edges (+n self loops), C=128.
// Round 2: fix embed staging at segment boundaries (gk==288 poi/cat, gk==592 lat/lon).
// GEMMs via MFMA 16x16x32_f16 split-f16 (hi+lo, 3 terms, fp32 acc); CSR aggregations.

#define BB 64
#define NN 714
#define EE 16384
#define ET (EE + NN)          // 17098 edges incl self loops
#define NBt (BB * NN)         // 45696 total nodes
#define CC 128
#define RP (NN + 1)           // rowptr entries per graph
#define KSE 26                // embed k-steps (K=800 padded to 832)
#define CHE 13                // embed 64-wide k-chunks

typedef _Float16 f16;
typedef __attribute__((ext_vector_type(8))) _Float16 f16x8;
typedef __attribute__((ext_vector_type(4))) float f32x4;

__device__ __forceinline__ float lrelu01(float x) { return x > 0.f ? x : 0.01f * x; }
__device__ __forceinline__ float lrelu2(float x)  { return x > 0.f ? x : 0.2f  * x; }

__device__ __forceinline__ float wsum(float x) {
#pragma unroll
    for (int o = 32; o > 0; o >>= 1) x += __shfl_xor(x, o);
    return x;
}
__device__ __forceinline__ float wmax(float x) {
#pragma unroll
    for (int o = 32; o > 0; o >>= 1) x = fmaxf(x, __shfl_xor(x, o));
    return x;
}

// ---- edge prep ----
__global__ void k_edge_prep(const int* __restrict__ edges, int* __restrict__ row32,
                            int* __restrict__ col32, float* __restrict__ deg) {
    int idx = blockIdx.x * blockDim.x + threadIdx.x;
    if (idx >= BB * ET) return;
    int b = idx / ET, e = idx - b * ET;
    int r, c;
    if (e < EE) { r = edges[b * 2 * EE + e]; c = edges[b * 2 * EE + EE + e]; }
    else        { r = c = e - EE; }
    row32[idx] = r; col32[idx] = c;
    atomicAdd(&deg[b * NN + c], 1.0f);
}

__global__ void k_scan(float* degdinv, int* __restrict__ rowptr, int* __restrict__ cursor) {
    __shared__ int s[1024];
    int b = blockIdx.x, v = threadIdx.x;
    int cnt = 0; float d = 0.f;
    if (v < NN) { d = degdinv[b * NN + v]; cnt = (int)d; }
    s[v] = cnt;
    __syncthreads();
    for (int off = 1; off < 1024; off <<= 1) {
        int val = (v >= off) ? s[v - off] : 0;
        __syncthreads();
        s[v] += val;
        __syncthreads();
    }
    if (v < NN) {
        degdinv[b * NN + v] = d > 0.f ? rsqrtf(d) : 0.f;
        rowptr[b * RP + v + 1] = s[v];
        cursor[b * RP + v] = (v == 0) ? 0 : s[v - 1];
    }
    if (v == 0) rowptr[b * RP] = 0;
}

__global__ void k_scatter(const int* __restrict__ row32, const int* __restrict__ col32,
                          int* __restrict__ cursor, int* __restrict__ csr_row) {
    int idx = blockIdx.x * blockDim.x + threadIdx.x;
    if (idx >= BB * ET) return;
    int b = idx / ET;
    int c = col32[idx];
    int slot = atomicAdd(&cursor[b * RP + c], 1);
    csr_row[b * ET + slot] = row32[idx];
}

// ---- pack W_in (800x128, K padded to 832) into frag layout hi/lo ----
__global__ void k_pack_Win(const float* __restrict__ W, f16* __restrict__ Bh, f16* __restrict__ Bl) {
    int idx = blockIdx.x * 256 + threadIdx.x;     // (ks*8+ct)*64 + lane
    if (idx >= KSE * 8 * 64) return;
    int lane = idx & 63, tc = idx >> 6;
    int ct = tc & 7, ks = tc >> 3;
    f16x8 ph, pl;
#pragma unroll
    for (int j = 0; j < 8; ++j) {
        int k = ks * 32 + (lane >> 4) * 8 + j;
        int c = ct * 16 + (lane & 15);
        float v = (k < 800) ? W[k * CC + c] : 0.f;
        f16 hi = (f16)v;
        ph[j] = hi; pl[j] = (f16)(v - (float)hi);
    }
    *(f16x8*)(Bh + (size_t)idx * 8) = ph;
    *(f16x8*)(Bl + (size_t)idx * 8) = pl;
}

// ---- pack gat_W (3 x 128x128) into frag layout hi/lo ----
__global__ void k_pack_Wgat(const float* __restrict__ W, f16* __restrict__ Bh, f16* __restrict__ Bl) {
    int idx = blockIdx.x * 256 + threadIdx.x;     // ((i*4+ks)*8+ct)*64 + lane
    if (idx >= 3 * 4 * 8 * 64) return;
    int lane = idx & 63, tc = idx >> 6;
    int ct = tc & 7; tc >>= 3;
    int ks = tc & 3, li = tc >> 2;
    const float* Wl = W + (size_t)li * CC * CC;
    f16x8 ph, pl;
#pragma unroll
    for (int j = 0; j < 8; ++j) {
        int k = ks * 32 + (lane >> 4) * 8 + j;
        int c = ct * 16 + (lane & 15);
        float v = Wl[k * CC + c];
        f16 hi = (f16)v;
        ph[j] = hi; pl[j] = (f16)(v - (float)hi);
    }
    *(f16x8*)(Bh + (size_t)idx * 8) = ph;
    *(f16x8*)(Bl + (size_t)idx * 8) = pl;
}

// ---- w_s = W.a_src, w_d = W.a_dst per layer (so asrc = h.w_s pre-GEMM) ----
__global__ void k_wsd(const float* __restrict__ gat_W, const float* __restrict__ a_s,
                      const float* __restrict__ a_d, float* __restrict__ wsv, float* __restrict__ wdv) {
    int i = blockIdx.x, k = threadIdx.x;
    const float* W = gat_W + (size_t)i * CC * CC;
    float s = 0.f, d = 0.f;
#pragma unroll 4
    for (int c = 0; c < CC; ++c) {
        float w = W[k * CC + c];
        s = fmaf(w, a_s[i * CC + c], s);
        d = fmaf(w, a_d[i * CC + c], d);
    }
    wsv[i * CC + k] = s; wdv[i * CC + k] = d;
}

// ---- fused embedding-gather + X@W_in via MFMA split-f16 ----
__global__ __launch_bounds__(256) void k_embed_gemm(
    const int* __restrict__ feature, const float* __restrict__ poi,
    const float* __restrict__ cat, const float* __restrict__ lat,
    const float* __restrict__ lon, const f16* __restrict__ Bh,
    const f16* __restrict__ Bl, float* __restrict__ out) {
    __shared__ __align__(16) f16 Ah[64 * 64];
    __shared__ __align__(16) f16 Al[64 * 64];
    int t = threadIdx.x, g0 = blockIdx.x * 64;
    int lane = t & 63, w = t >> 6;
    int sr = t >> 2;            // staging row
    int skb = (t & 3) * 16;     // staging k base within chunk
    const int* f = feature + (size_t)(g0 + sr) * 5;
    int f0 = f[0], f1 = f[1], f3 = f[3], f4 = f[4];
    f32x4 acc[4][2];
#pragma unroll
    for (int rt = 0; rt < 4; ++rt)
#pragma unroll
        for (int c = 0; c < 2; ++c) acc[rt][c] = (f32x4){0.f, 0.f, 0.f, 0.f};
    int ct0 = w * 2;

    for (int ch = 0; ch < CHE; ++ch) {
        int kc = ch * 64;
        __syncthreads();
        // ---- stage 16 elems/thread, convert to hi/lo, swizzled LDS write ----
        float v[16];
        int gk = kc + skb;
        if (gk >= 800) {
#pragma unroll
            for (int m = 0; m < 16; ++m) v[m] = 0.f;
        } else if (gk == 288 || gk == 592) {
            // block crosses a concat-segment boundary (300 or 600): scalar ladder
#pragma unroll
            for (int m = 0; m < 16; ++m) {
                int k = gk + m;
                float val;
                if (k < 300)      val = poi[(size_t)f0 * 300 + k];
                else if (k < 400) val = cat[(size_t)f1 * 100 + (k - 300)];
                else if (k < 600) val = lat[(size_t)f3 * 200 + (k - 400)];
                else              val = lon[(size_t)f4 * 200 + (k - 600)];
                v[m] = val;
            }
        } else {
            const float* src;
            if (gk >= 600)      src = lon + (size_t)f4 * 200 + (gk - 600);
            else if (gk >= 400) src = lat + (size_t)f3 * 200 + (gk - 400);
            else if (gk >= 300) src = cat + (size_t)f1 * 100 + (gk - 300);
            else                src = poi + (size_t)f0 * 300 + gk;
            const float4* s4 = (const float4*)src;
#pragma unroll
            for (int q = 0; q < 4; ++q) {
                float4 x = s4[q];
                v[q * 4 + 0] = x.x; v[q * 4 + 1] = x.y; v[q * 4 + 2] = x.z; v[q * 4 + 3] = x.w;
            }
        }
        f16x8 ph0, ph1, pl0, pl1;
#pragma unroll
        for (int j = 0; j < 8; ++j) {
            f16 h0 = (f16)v[j];     ph0[j] = h0; pl0[j] = (f16)(v[j] - (float)h0);
            f16 h1 = (f16)v[8 + j]; ph1[j] = h1; pl1[j] = (f16)(v[8 + j] - (float)h1);
        }
        int kg0 = skb >> 3;
        int a0i = sr * 64 + ((kg0 ^ (sr & 7)) << 3);
        int a1i = sr * 64 + (((kg0 + 1) ^ (sr & 7)) << 3);
        *(f16x8*)&Ah[a0i] = ph0; *(f16x8*)&Ah[a1i] = ph1;
        *(f16x8*)&Al[a0i] = pl0; *(f16x8*)&Al[a1i] = pl1;
        __syncthreads();
        // ---- 2 k-steps of MFMA ----
#pragma unroll
        for (int kh = 0; kh < 2; ++kh) {
            int ks = ch * 2 + kh;
            f16x8 ahf[4], alf[4];
#pragma unroll
            for (int rt = 0; rt < 4; ++rt) {
                int r = rt * 16 + (lane & 15);
                int kg = (lane >> 4) + kh * 4;
                int ad = r * 64 + ((kg ^ (r & 7)) << 3);
                ahf[rt] = *(const f16x8*)&Ah[ad];
                alf[rt] = *(const f16x8*)&Al[ad];
            }
#pragma unroll
            for (int cti = 0; cti < 2; ++cti) {
                int ct = ct0 + cti;
                f16x8 bh = *(const f16x8*)(Bh + ((size_t)(ks * 8 + ct) * 64 + lane) * 8);
                f16x8 bl = *(const f16x8*)(Bl + ((size_t)(ks * 8 + ct) * 64 + lane) * 8);
#pragma unroll
                for (int rt = 0; rt < 4; ++rt) {
                    acc[rt][cti] = __builtin_amdgcn_mfma_f32_16x16x32_f16(ahf[rt], bh, acc[rt][cti], 0, 0, 0);
                    acc[rt][cti] = __builtin_amdgcn_mfma_f32_16x16x32_f16(alf[rt], bh, acc[rt][cti], 0, 0, 0);
                    acc[rt][cti] = __builtin_amdgcn_mfma_f32_16x16x32_f16(ahf[rt], bl, acc[rt][cti], 0, 0, 0);
                }
            }
        }
    }
#pragma unroll
    for (int rt = 0; rt < 4; ++rt)
#pragma unroll
        for (int cti = 0; cti < 2; ++cti)
#pragma unroll
            for (int i = 0; i < 4; ++i) {
                int row = g0 + rt * 16 + (lane >> 4) * 4 + i;
                int col = (ct0 + cti) * 16 + (lane & 15);
                out[(size_t)row * CC + col] = acc[rt][cti][i];
            }
}

// ---- GAT gemm via MFMA split-f16; asrc/adst fused into staging via w_s/w_d ----
__global__ __launch_bounds__(256) void k_gat_gemm(
    const float* __restrict__ hin, const f16* __restrict__ Bh, const f16* __restrict__ Bl,
    const float* __restrict__ wsv, const float* __restrict__ wdv,
    float* __restrict__ Hp, float* __restrict__ asrc, float* __restrict__ adst) {
    __shared__ __align__(16) f16 Ah[64 * 128];
    __shared__ __align__(16) f16 Al[64 * 128];
    __shared__ float reds[256], redd[256];
    int t = threadIdx.x, g0 = blockIdx.x * 64;
    int lane = t & 63, w = t >> 6;
    int sr = t >> 2, skb = (t & 3) * 32;
    // ---- stage + fused asrc/adst partials ----
    const float4* hrow = (const float4*)(hin + (size_t)(g0 + sr) * CC + skb);
    float v[32];
    float ps = 0.f, pd = 0.f;
#pragma unroll
    for (int q = 0; q < 8; ++q) {
        float4 x = hrow[q];
        v[q * 4 + 0] = x.x; v[q * 4 + 1] = x.y; v[q * 4 + 2] = x.z; v[q * 4 + 3] = x.w;
    }
#pragma unroll
    for (int m = 0; m < 32; ++m) {
        ps = fmaf(v[m], wsv[skb + m], ps);
        pd = fmaf(v[m], wdv[skb + m], pd);
    }
#pragma unroll
    for (int q = 0; q < 4; ++q) {
        f16x8 ph, pl;
#pragma unroll
        for (int j = 0; j < 8; ++j) {
            float x = v[q * 8 + j];
            f16 hi = (f16)x;
            ph[j] = hi; pl[j] = (f16)(x - (float)hi);
        }
        int kg = (skb >> 3) + q;
        int ad = sr * 128 + ((kg ^ (sr & 7)) << 3);
        *(f16x8*)&Ah[ad] = ph; *(f16x8*)&Al[ad] = pl;
    }
    reds[t] = ps; redd[t] = pd;
    __syncthreads();
    if (t < 64) {
        asrc[g0 + t] = reds[t * 4] + reds[t * 4 + 1] + reds[t * 4 + 2] + reds[t * 4 + 3];
        adst[g0 + t] = redd[t * 4] + redd[t * 4 + 1] + redd[t * 4 + 2] + redd[t * 4 + 3];
    }
    // ---- MFMA ----
    f32x4 acc[4][2];
#pragma unroll
    for (int rt = 0; rt < 4; ++rt)
#pragma unroll
        for (int c = 0; c < 2; ++c) acc[rt][c] = (f32x4){0.f, 0.f, 0.f, 0.f};
    int ct0 = w * 2;
#pragma unroll
    for (int ks = 0; ks < 4; ++ks) {
        f16x8 ahf[4], alf[4];
#pragma unroll
        for (int rt = 0; rt < 4; ++rt) {
            int r = rt * 16 + (lane & 15);
            int kg = (lane >> 4) + ks * 4;
            int ad = r * 128 + ((kg ^ (r & 7)) << 3);
            ahf[rt] = *(const f16x8*)&Ah[ad];
            alf[rt] = *(const f16x8*)&Al[ad];
        }
#pragma unroll
        for (int cti = 0; cti < 2; ++cti) {
            int ct = ct0 + cti;
            f16x8 bh = *(const f16x8*)(Bh + ((size_t)(ks * 8 + ct) * 64 + lane) * 8);
            f16x8 bl = *(const f16x8*)(Bl + ((size_t)(ks * 8 + ct) * 64 + lane) * 8);
#pragma unroll
            for (int rt = 0; rt < 4; ++rt) {
                acc[rt][cti] = __builtin_amdgcn_mfma_f32_16x16x32_f16(ahf[rt], bh, acc[rt][cti], 0, 0, 0);
                acc[rt][cti] = __builtin_amdgcn_mfma_f32_16x16x32_f16(alf[rt], bh, acc[rt][cti], 0, 0, 0);
                acc[rt][cti] = __builtin_amdgcn_mfma_f32_16x16x32_f16(ahf[rt], bl, acc[rt][cti], 0, 0, 0);
            }
        }
    }
#pragma unroll
    for (int rt = 0; rt < 4; ++rt)
#pragma unroll
        for (int cti = 0; cti < 2; ++cti)
#pragma unroll
            for (int i = 0; i < 4; ++i) {
                int row = g0 + rt * 16 + (lane >> 4) * 4 + i;
                int col = (ct0 + cti) * 16 + (lane & 15);
                Hp[(size_t)row * CC + col] = acc[rt][cti][i];
            }
}

// ---- GCN aggregate (float2 lanes, 2-edge unroll) ----
__global__ __launch_bounds__(256) void k_gcn_agg(
    const float* __restrict__ H, const float* __restrict__ dinv,
    const int* __restrict__ rowptr, const int* __restrict__ csr_row,
    const float* __restrict__ bias, float* __restrict__ out) {
    int wid = threadIdx.x >> 6, lane = threadIdx.x & 63;
    int g = blockIdx.x * 4 + wid;
    int b = g / NN, v = g - b * NN;
    int bN = b * NN, bE = b * ET;
    int s0 = rowptr[b * RP + v], s1 = rowptr[b * RP + v + 1];
    float dv = dinv[g];
    float a0 = 0.f, a1 = 0.f, c0 = 0.f, c1 = 0.f;
    int j = s0;
    for (; j + 1 < s1; j += 2) {
        int r0 = csr_row[bE + j], r1 = csr_row[bE + j + 1];
        float d0 = dinv[bN + r0], d1 = dinv[bN + r1];
        float2 h0 = ((const float2*)(H + (size_t)(bN + r0) * CC))[lane];
        float2 h1 = ((const float2*)(H + (size_t)(bN + r1) * CC))[lane];
        a0 = fmaf(d0, h0.x, a0); a1 = fmaf(d0, h0.y, a1);
        c0 = fmaf(d1, h1.x, c0); c1 = fmaf(d1, h1.y, c1);
    }
    if (j < s1) {
        int r0 = csr_row[bE + j];
        float d0 = dinv[bN + r0];
        float2 h0 = ((const float2*)(H + (size_t)(bN + r0) * CC))[lane];
        a0 = fmaf(d0, h0.x, a0); a1 = fmaf(d0, h0.y, a1);
    }
    a0 += c0; a1 += c1;
    float2 bb = ((const float2*)bias)[lane];
    float2 o;
    o.x = lrelu01(a0 * dv + bb.x);
    o.y = lrelu01(a1 * dv + bb.y);
    ((float2*)(out + (size_t)g * CC))[lane] = o;
}

// ---- GAT aggregate with online softmax (float2 lanes, 2-edge unroll) ----
template <int MODE>
__global__ __launch_bounds__(256) void k_gat_agg(
    const float* __restrict__ Hp, const float* __restrict__ asrc,
    const float* __restrict__ adst, const int* __restrict__ rowptr,
    const int* __restrict__ csr_row, const float* __restrict__ bias,
    float* __restrict__ out) {
    int wid = threadIdx.x >> 6, lane = threadIdx.x & 63;
    int g = blockIdx.x * 4 + wid;
    int b = g / NN, v = g - b * NN;
    int bN = b * NN, bE = b * ET;
    int s0 = rowptr[b * RP + v], s1 = rowptr[b * RP + v + 1];
    float adv = adst[g];
    float m = -3.0e38f;
    for (int j = s0 + lane; j < s1; j += 64)
        m = fmaxf(m, lrelu2(asrc[bN + csr_row[bE + j]] + adv));
    m = wmax(m);
    float ssum = 0.f;
    for (int j = s0 + lane; j < s1; j += 64)
        ssum += __expf(lrelu2(asrc[bN + csr_row[bE + j]] + adv) - m);
    ssum = wsum(ssum);
    float inv = 1.f / (ssum + 1e-16f);
    float a0 = 0.f, a1 = 0.f, c0 = 0.f, c1 = 0.f;
    int j = s0;
    for (; j + 1 < s1; j += 2) {
        int r0 = csr_row[bE + j], r1 = csr_row[bE + j + 1];
        float w0 = __expf(lrelu2(asrc[bN + r0] + adv) - m) * inv;
        float w1 = __expf(lrelu2(asrc[bN + r1] + adv) - m) * inv;
        float2 h0 = ((const float2*)(Hp + (size_t)(bN + r0) * CC))[lane];
        float2 h1 = ((const float2*)(Hp + (size_t)(bN + r1) * CC))[lane];
        a0 = fmaf(w0, h0.x, a0); a1 = fmaf(w0, h0.y, a1);
        c0 = fmaf(w1, h1.x, c0); c1 = fmaf(w1, h1.y, c1);
    }
    if (j < s1) {
        int r0 = csr_row[bE + j];
        float w0 = __expf(lrelu2(asrc[bN + r0] + adv) - m) * inv;
        float2 h0 = ((const float2*)(Hp + (size_t)(bN + r0) * CC))[lane];
        a0 = fmaf(w0, h0.x, a0); a1 = fmaf(w0, h0.y, a1);
    }
    a0 += c0; a1 += c1;
    float2 bb = ((const float2*)bias)[lane];
    float t0 = a0 + bb.x, t1 = a1 + bb.y;
    float2 o;
    if (MODE == 0) { o.x = lrelu01(t0) + t0; o.y = lrelu01(t1) + t1; }
    else           { o.x = lrelu01(t0);      o.y = lrelu01(t1); }
    ((float2*)(out + (size_t)g * CC))[lane] = o;
}

// ---- GCN2 per-node dot ----
__global__ __launch_bounds__(256) void k_out_dot(
    const float* __restrict__ h, const float* __restrict__ Wout,
    float* __restrict__ p) {
    int wid = threadIdx.x >> 6, lane = threadIdx.x & 63;
    int g = blockIdx.x * 4 + wid;
    float2 h2 = ((const float2*)(h + (size_t)g * CC))[lane];
    float2 w2 = ((const float2*)Wout)[lane];
    float x = wsum(h2.x * w2.x + h2.y * w2.y);
    if (lane == 0) p[g] = x;
}

__global__ __launch_bounds__(256) void k_out_agg(
    const float* __restrict__ p, const float* __restrict__ dinv,
    const int* __restrict__ rowptr, const int* __restrict__ csr_row,
    const float* __restrict__ bout, float* __restrict__ gv) {
    int wid = threadIdx.x >> 6, lane = threadIdx.x & 63;
    int g = blockIdx.x * 4 + wid;
    int b = g / NN, v = g - b * NN;
    int s0 = rowptr[b * RP + v], s1 = rowptr[b * RP + v + 1];
    float acc = 0.f;
    for (int j = s0 + lane; j < s1; j += 64) {
        int r = csr_row[b * ET + j];
        acc += dinv[b * NN + r] * p[b * NN + r];
    }
    acc = wsum(acc);
    if (lane == 0) gv[g] = lrelu01(acc * dinv[g] + bout[0]);
}

__global__ __launch_bounds__(128) void k_fc(
    const float* __restrict__ gv, const float* __restrict__ W1,
    const float* __restrict__ b1, const float* __restrict__ W2,
    const float* __restrict__ b2, float* __restrict__ outp) {
    __shared__ float gs[NN];
    __shared__ float s1[CC];
    int b = blockIdx.x, tx = threadIdx.x;
    for (int v = tx; v < NN; v += 128) gs[v] = gv[b * NN + v];
    __syncthreads();
    float acc = 0.f;
    for (int v = 0; v < NN; ++v) acc = fmaf(gs[v], W1[v * CC + tx], acc);
    float t = lrelu01(acc + b1[tx]);
    s1[tx] = t;
    __syncthreads();
    float acc2 = 0.f;
#pragma unroll
    for (int k = 0; k < CC; ++k) acc2 = fmaf(s1[k], W2[k * CC + tx], acc2);
    outp[b * CC + tx] = acc2 + b2[tx];
}

extern "C" void kernel_launch(void* const* d_in, const int* in_sizes, int n_in,
                              void* d_out, int out_size, void* d_ws, size_t ws_size,
                              hipStream_t stream) {
    const int*   feature  = (const int*)d_in[0];
    const int*   edges    = (const int*)d_in[1];
    const float* poi      = (const float*)d_in[3];
    const float* cat      = (const float*)d_in[4];
    const float* lat      = (const float*)d_in[5];
    const float* lon      = (const float*)d_in[6];
    const float* W_in     = (const float*)d_in[7];
    const float* b_in     = (const float*)d_in[8];
    const float* gat_W    = (const float*)d_in[9];
    const float* gat_asrc = (const float*)d_in[10];
    const float* gat_adst = (const float*)d_in[11];
    const float* gat_b    = (const float*)d_in[12];
    const float* W_out    = (const float*)d_in[13];
    const float* b_out    = (const float*)d_in[14];
    const float* W_fc1    = (const float*)d_in[15];
    const float* b_fc1    = (const float*)d_in[16];
    const float* W_fc2    = (const float*)d_in[17];
    const float* b_fc2    = (const float*)d_in[18];
    float* outp = (float*)d_out;

    char* ws = (char*)d_ws;
    size_t off = 0;
    auto take = [&](size_t bytes) -> char* {
        char* pp = ws + off;
        off = (off + bytes + 255) & ~(size_t)255;
        return pp;
    };
    int*   row32  = (int*)take((size_t)BB * ET * 4);
    int*   col32  = (int*)take((size_t)BB * ET * 4);
    int*   csr    = (int*)take((size_t)BB * ET * 4);
    int*   rowptr = (int*)take((size_t)BB * RP * 4);
    int*   cursor = (int*)take((size_t)BB * RP * 4);
    float* dinv   = (float*)take((size_t)NBt * 4);
    float* asrc   = (float*)take((size_t)NBt * 4);
    float* adst   = (float*)take((size_t)NBt * 4);
    float* pscal  = (float*)take((size_t)NBt * 4);
    float* gvec   = (float*)take((size_t)NBt * 4);
    float* bufA   = (float*)take((size_t)NBt * CC * 4);
    float* bufB   = (float*)take((size_t)NBt * CC * 4);
    f16*   BWh    = (f16*)take((size_t)KSE * 8 * 64 * 8 * 2);
    f16*   BWl    = (f16*)take((size_t)KSE * 8 * 64 * 8 * 2);
    f16*   BGh    = (f16*)take((size_t)3 * 4 * 8 * 64 * 8 * 2);
    f16*   BGl    = (f16*)take((size_t)3 * 4 * 8 * 64 * 8 * 2);
    float* wsv    = (float*)take((size_t)3 * CC * 4);
    float* wdv    = (float*)take((size_t)3 * CC * 4);

    const int nE = BB * ET;
    hipMemsetAsync(dinv, 0, (size_t)NBt * 4, stream);
    k_edge_prep<<<(nE + 255) / 256, 256, 0, stream>>>(edges, row32, col32, dinv);
    k_scan<<<BB, 1024, 0, stream>>>(dinv, rowptr, cursor);
    k_scatter<<<(nE + 255) / 256, 256, 0, stream>>>(row32, col32, cursor, csr);

    k_pack_Win<<<(KSE * 8 * 64 + 255) / 256, 256, 0, stream>>>(W_in, BWh, BWl);
    k_pack_Wgat<<<(3 * 4 * 8 * 64 + 255) / 256, 256, 0, stream>>>(gat_W, BGh, BGl);
    k_wsd<<<3, 128, 0, stream>>>(gat_W, gat_asrc, gat_adst, wsv, wdv);

    k_embed_gemm<<<NBt / 64, 256, 0, stream>>>(feature, poi, cat, lat, lon, BWh, BWl, bufB);
    k_gcn_agg<<<NBt / 4, 256, 0, stream>>>(bufB, dinv, rowptr, csr, b_in, bufA);

    for (int i = 0; i < 3; ++i) {
        const f16* bh = BGh + (size_t)i * 4 * 8 * 64 * 8;
        const f16* bl = BGl + (size_t)i * 4 * 8 * 64 * 8;
        const float* ws_i = wsv + (size_t)i * CC;
        const float* wd_i = wdv + (size_t)i * CC;
        const float* gb = gat_b + (size_t)i * CC;
        k_gat_gemm<<<NBt / 64, 256, 0, stream>>>(bufA, bh, bl, ws_i, wd_i, bufB, asrc, adst);
        k_gat_agg<0><<<NBt / 4, 256, 0, stream>>>(bufB, asrc, adst, rowptr, csr, gb, bufA);
        k_gat_gemm<<<NBt / 64, 256, 0, stream>>>(bufA, bh, bl, ws_i, wd_i, bufB, asrc, adst);
        k_gat_agg<1><<<NBt / 4, 256, 0, stream>>>(bufB, asrc, adst, rowptr, csr, gb, bufA);
    }

    k_out_dot<<<NBt / 4, 256, 0, stream>>>(bufA, W_out, pscal);
    k_out_agg<<<NBt / 4, 256, 0, stream>>>(pscal, dinv, rowptr, csr, b_out, gvec);
    k_fc<<<BB, 128, 0, stream>>>(gvec, W_fc1, b_fc1, W_fc2, b_fc2, outp);
}

// Round 4
// 684.077 us; speedup vs baseline: 1.9146x; 1.1773x over previous
//
#include <hip/hip_runtime.h>

// UserGraphNet: B=64 graphs, n=714 nodes, E=16384 edges (+n self loops), C=128.
// Round 3: XCD-aware bijective block swizzle (T1) on agg+gemm kernels so each XCD's
// L2 owns a contiguous ~8-graph chunk; 4-row unrolled gathers for latency hiding.
// GEMMs via MFMA 16x16x32_f16 split-f16 (hi+lo, 3 terms, fp32 acc); CSR aggregations.

#define BB 64
#define NN 714
#define EE 16384
#define ET (EE + NN)          // 17098 edges incl self loops
#define NBt (BB * NN)         // 45696 total nodes
#define CC 128
#define RP (NN + 1)           // rowptr entries per graph
#define KSE 26                // embed k-steps (K=800 padded to 832)
#define CHE 13                // embed 64-wide k-chunks

typedef _Float16 f16;
typedef __attribute__((ext_vector_type(8))) _Float16 f16x8;
typedef __attribute__((ext_vector_type(4))) float f32x4;

__device__ __forceinline__ float lrelu01(float x) { return x > 0.f ? x : 0.01f * x; }
__device__ __forceinline__ float lrelu2(float x)  { return x > 0.f ? x : 0.2f  * x; }

__device__ __forceinline__ float wsum(float x) {
#pragma unroll
    for (int o = 32; o > 0; o >>= 1) x += __shfl_xor(x, o);
    return x;
}
__device__ __forceinline__ float wmax(float x) {
#pragma unroll
    for (int o = 32; o > 0; o >>= 1) x = fmaxf(x, __shfl_xor(x, o));
    return x;
}

// Bijective XCD swizzle (m204): hw round-robins bid->XCD bid%8; remap so XCD x
// processes a contiguous chunk of work. Valid for any nwg.
__device__ __forceinline__ int xcd_swz(int bid, int nwg) {
    int q = nwg >> 3, r = nwg & 7;
    int x = bid & 7, l = bid >> 3;
    int base = (x < r) ? x * (q + 1) : r * (q + 1) + (x - r) * q;
    return base + l;
}

// ---- edge prep ----
__global__ void k_edge_prep(const int* __restrict__ edges, int* __restrict__ row32,
                            int* __restrict__ col32, float* __restrict__ deg) {
    int idx = blockIdx.x * blockDim.x + threadIdx.x;
    if (idx >= BB * ET) return;
    int b = idx / ET, e = idx - b * ET;
    int r, c;
    if (e < EE) { r = edges[b * 2 * EE + e]; c = edges[b * 2 * EE + EE + e]; }
    else        { r = c = e - EE; }
    row32[idx] = r; col32[idx] = c;
    atomicAdd(&deg[b * NN + c], 1.0f);
}

__global__ void k_scan(float* degdinv, int* __restrict__ rowptr, int* __restrict__ cursor) {
    __shared__ int s[1024];
    int b = blockIdx.x, v = threadIdx.x;
    int cnt = 0; float d = 0.f;
    if (v < NN) { d = degdinv[b * NN + v]; cnt = (int)d; }
    s[v] = cnt;
    __syncthreads();
    for (int off = 1; off < 1024; off <<= 1) {
        int val = (v >= off) ? s[v - off] : 0;
        __syncthreads();
        s[v] += val;
        __syncthreads();
    }
    if (v < NN) {
        degdinv[b * NN + v] = d > 0.f ? rsqrtf(d) : 0.f;
        rowptr[b * RP + v + 1] = s[v];
        cursor[b * RP + v] = (v == 0) ? 0 : s[v - 1];
    }
    if (v == 0) rowptr[b * RP] = 0;
}

__global__ void k_scatter(const int* __restrict__ row32, const int* __restrict__ col32,
                          int* __restrict__ cursor, int* __restrict__ csr_row) {
    int idx = blockIdx.x * blockDim.x + threadIdx.x;
    if (idx >= BB * ET) return;
    int b = idx / ET;
    int c = col32[idx];
    int slot = atomicAdd(&cursor[b * RP + c], 1);
    csr_row[b * ET + slot] = row32[idx];
}

// ---- pack W_in (800x128, K padded to 832) into frag layout hi/lo ----
__global__ void k_pack_Win(const float* __restrict__ W, f16* __restrict__ Bh, f16* __restrict__ Bl) {
    int idx = blockIdx.x * 256 + threadIdx.x;     // (ks*8+ct)*64 + lane
    if (idx >= KSE * 8 * 64) return;
    int lane = idx & 63, tc = idx >> 6;
    int ct = tc & 7, ks = tc >> 3;
    f16x8 ph, pl;
#pragma unroll
    for (int j = 0; j < 8; ++j) {
        int k = ks * 32 + (lane >> 4) * 8 + j;
        int c = ct * 16 + (lane & 15);
        float v = (k < 800) ? W[k * CC + c] : 0.f;
        f16 hi = (f16)v;
        ph[j] = hi; pl[j] = (f16)(v - (float)hi);
    }
    *(f16x8*)(Bh + (size_t)idx * 8) = ph;
    *(f16x8*)(Bl + (size_t)idx * 8) = pl;
}

// ---- pack gat_W (3 x 128x128) into frag layout hi/lo ----
__global__ void k_pack_Wgat(const float* __restrict__ W, f16* __restrict__ Bh, f16* __restrict__ Bl) {
    int idx = blockIdx.x * 256 + threadIdx.x;     // ((i*4+ks)*8+ct)*64 + lane
    if (idx >= 3 * 4 * 8 * 64) return;
    int lane = idx & 63, tc = idx >> 6;
    int ct = tc & 7; tc >>= 3;
    int ks = tc & 3, li = tc >> 2;
    const float* Wl = W + (size_t)li * CC * CC;
    f16x8 ph, pl;
#pragma unroll
    for (int j = 0; j < 8; ++j) {
        int k = ks * 32 + (lane >> 4) * 8 + j;
        int c = ct * 16 + (lane & 15);
        float v = Wl[k * CC + c];
        f16 hi = (f16)v;
        ph[j] = hi; pl[j] = (f16)(v - (float)hi);
    }
    *(f16x8*)(Bh + (size_t)idx * 8) = ph;
    *(f16x8*)(Bl + (size_t)idx * 8) = pl;
}

// ---- w_s = W.a_src, w_d = W.a_dst per layer ----
__global__ void k_wsd(const float* __restrict__ gat_W, const float* __restrict__ a_s,
                      const float* __restrict__ a_d, float* __restrict__ wsv, float* __restrict__ wdv) {
    int i = blockIdx.x, k = threadIdx.x;
    const float* W = gat_W + (size_t)i * CC * CC;
    float s = 0.f, d = 0.f;
#pragma unroll 4
    for (int c = 0; c < CC; ++c) {
        float w = W[k * CC + c];
        s = fmaf(w, a_s[i * CC + c], s);
        d = fmaf(w, a_d[i * CC + c], d);
    }
    wsv[i * CC + k] = s; wdv[i * CC + k] = d;
}

// ---- fused embedding-gather + X@W_in via MFMA split-f16 ----
__global__ __launch_bounds__(256) void k_embed_gemm(
    const int* __restrict__ feature, const float* __restrict__ poi,
    const float* __restrict__ cat, const float* __restrict__ lat,
    const float* __restrict__ lon, const f16* __restrict__ Bh,
    const f16* __restrict__ Bl, float* __restrict__ out) {
    __shared__ __align__(16) f16 Ah[64 * 64];
    __shared__ __align__(16) f16 Al[64 * 64];
    int t = threadIdx.x;
    int g0 = xcd_swz(blockIdx.x, gridDim.x) * 64;
    int lane = t & 63, w = t >> 6;
    int sr = t >> 2;            // staging row
    int skb = (t & 3) * 16;     // staging k base within chunk
    const int* f = feature + (size_t)(g0 + sr) * 5;
    int f0 = f[0], f1 = f[1], f3 = f[3], f4 = f[4];
    f32x4 acc[4][2];
#pragma unroll
    for (int rt = 0; rt < 4; ++rt)
#pragma unroll
        for (int c = 0; c < 2; ++c) acc[rt][c] = (f32x4){0.f, 0.f, 0.f, 0.f};
    int ct0 = w * 2;

    for (int ch = 0; ch < CHE; ++ch) {
        int kc = ch * 64;
        __syncthreads();
        float v[16];
        int gk = kc + skb;
        if (gk >= 800) {
#pragma unroll
            for (int m = 0; m < 16; ++m) v[m] = 0.f;
        } else if (gk == 288 || gk == 592) {
            // block crosses a concat-segment boundary (300 or 600): scalar ladder
#pragma unroll
            for (int m = 0; m < 16; ++m) {
                int k = gk + m;
                float val;
                if (k < 300)      val = poi[(size_t)f0 * 300 + k];
                else if (k < 400) val = cat[(size_t)f1 * 100 + (k - 300)];
                else if (k < 600) val = lat[(size_t)f3 * 200 + (k - 400)];
                else              val = lon[(size_t)f4 * 200 + (k - 600)];
                v[m] = val;
            }
        } else {
            const float* src;
            if (gk >= 600)      src = lon + (size_t)f4 * 200 + (gk - 600);
            else if (gk >= 400) src = lat + (size_t)f3 * 200 + (gk - 400);
            else if (gk >= 300) src = cat + (size_t)f1 * 100 + (gk - 300);
            else                src = poi + (size_t)f0 * 300 + gk;
            const float4* s4 = (const float4*)src;
#pragma unroll
            for (int q = 0; q < 4; ++q) {
                float4 x = s4[q];
                v[q * 4 + 0] = x.x; v[q * 4 + 1] = x.y; v[q * 4 + 2] = x.z; v[q * 4 + 3] = x.w;
            }
        }
        f16x8 ph0, ph1, pl0, pl1;
#pragma unroll
        for (int j = 0; j < 8; ++j) {
            f16 h0 = (f16)v[j];     ph0[j] = h0; pl0[j] = (f16)(v[j] - (float)h0);
            f16 h1 = (f16)v[8 + j]; ph1[j] = h1; pl1[j] = (f16)(v[8 + j] - (float)h1);
        }
        int kg0 = skb >> 3;
        int a0i = sr * 64 + ((kg0 ^ (sr & 7)) << 3);
        int a1i = sr * 64 + (((kg0 + 1) ^ (sr & 7)) << 3);
        *(f16x8*)&Ah[a0i] = ph0; *(f16x8*)&Ah[a1i] = ph1;
        *(f16x8*)&Al[a0i] = pl0; *(f16x8*)&Al[a1i] = pl1;
        __syncthreads();
#pragma unroll
        for (int kh = 0; kh < 2; ++kh) {
            int ks = ch * 2 + kh;
            f16x8 ahf[4], alf[4];
#pragma unroll
            for (int rt = 0; rt < 4; ++rt) {
                int r = rt * 16 + (lane & 15);
                int kg = (lane >> 4) + kh * 4;
                int ad = r * 64 + ((kg ^ (r & 7)) << 3);
                ahf[rt] = *(const f16x8*)&Ah[ad];
                alf[rt] = *(const f16x8*)&Al[ad];
            }
#pragma unroll
            for (int cti = 0; cti < 2; ++cti) {
                int ct = ct0 + cti;
                f16x8 bh = *(const f16x8*)(Bh + ((size_t)(ks * 8 + ct) * 64 + lane) * 8);
                f16x8 bl = *(const f16x8*)(Bl + ((size_t)(ks * 8 + ct) * 64 + lane) * 8);
#pragma unroll
                for (int rt = 0; rt < 4; ++rt) {
                    acc[rt][cti] = __builtin_amdgcn_mfma_f32_16x16x32_f16(ahf[rt], bh, acc[rt][cti], 0, 0, 0);
                    acc[rt][cti] = __builtin_amdgcn_mfma_f32_16x16x32_f16(alf[rt], bh, acc[rt][cti], 0, 0, 0);
                    acc[rt][cti] = __builtin_amdgcn_mfma_f32_16x16x32_f16(ahf[rt], bl, acc[rt][cti], 0, 0, 0);
                }
            }
        }
    }
#pragma unroll
    for (int rt = 0; rt < 4; ++rt)
#pragma unroll
        for (int cti = 0; cti < 2; ++cti)
#pragma unroll
            for (int i = 0; i < 4; ++i) {
                int row = g0 + rt * 16 + (lane >> 4) * 4 + i;
                int col = (ct0 + cti) * 16 + (lane & 15);
                out[(size_t)row * CC + col] = acc[rt][cti][i];
            }
}

// ---- GAT gemm via MFMA split-f16; asrc/adst fused into staging ----
__global__ __launch_bounds__(256) void k_gat_gemm(
    const float* __restrict__ hin, const f16* __restrict__ Bh, const f16* __restrict__ Bl,
    const float* __restrict__ wsv, const float* __restrict__ wdv,
    float* __restrict__ Hp, float* __restrict__ asrc, float* __restrict__ adst) {
    __shared__ __align__(16) f16 Ah[64 * 128];
    __shared__ __align__(16) f16 Al[64 * 128];
    __shared__ float reds[256], redd[256];
    int t = threadIdx.x;
    int g0 = xcd_swz(blockIdx.x, gridDim.x) * 64;
    int lane = t & 63, w = t >> 6;
    int sr = t >> 2, skb = (t & 3) * 32;
    const float4* hrow = (const float4*)(hin + (size_t)(g0 + sr) * CC + skb);
    float v[32];
    float ps = 0.f, pd = 0.f;
#pragma unroll
    for (int q = 0; q < 8; ++q) {
        float4 x = hrow[q];
        v[q * 4 + 0] = x.x; v[q * 4 + 1] = x.y; v[q * 4 + 2] = x.z; v[q * 4 + 3] = x.w;
    }
#pragma unroll
    for (int m = 0; m < 32; ++m) {
        ps = fmaf(v[m], wsv[skb + m], ps);
        pd = fmaf(v[m], wdv[skb + m], pd);
    }
#pragma unroll
    for (int q = 0; q < 4; ++q) {
        f16x8 ph, pl;
#pragma unroll
        for (int j = 0; j < 8; ++j) {
            float x = v[q * 8 + j];
            f16 hi = (f16)x;
            ph[j] = hi; pl[j] = (f16)(x - (float)hi);
        }
        int kg = (skb >> 3) + q;
        int ad = sr * 128 + ((kg ^ (sr & 7)) << 3);
        *(f16x8*)&Ah[ad] = ph; *(f16x8*)&Al[ad] = pl;
    }
    reds[t] = ps; redd[t] = pd;
    __syncthreads();
    if (t < 64) {
        asrc[g0 + t] = reds[t * 4] + reds[t * 4 + 1] + reds[t * 4 + 2] + reds[t * 4 + 3];
        adst[g0 + t] = redd[t * 4] + redd[t * 4 + 1] + redd[t * 4 + 2] + redd[t * 4 + 3];
    }
    f32x4 acc[4][2];
#pragma unroll
    for (int rt = 0; rt < 4; ++rt)
#pragma unroll
        for (int c = 0; c < 2; ++c) acc[rt][c] = (f32x4){0.f, 0.f, 0.f, 0.f};
    int ct0 = w * 2;
#pragma unroll
    for (int ks = 0; ks < 4; ++ks) {
        f16x8 ahf[4], alf[4];
#pragma unroll
        for (int rt = 0; rt < 4; ++rt) {
            int r = rt * 16 + (lane & 15);
            int kg = (lane >> 4) + ks * 4;
            int ad = r * 128 + ((kg ^ (r & 7)) << 3);
            ahf[rt] = *(const f16x8*)&Ah[ad];
            alf[rt] = *(const f16x8*)&Al[ad];
        }
#pragma unroll
        for (int cti = 0; cti < 2; ++cti) {
            int ct = ct0 + cti;
            f16x8 bh = *(const f16x8*)(Bh + ((size_t)(ks * 8 + ct) * 64 + lane) * 8);
            f16x8 bl = *(const f16x8*)(Bl + ((size_t)(ks * 8 + ct) * 64 + lane) * 8);
#pragma unroll
            for (int rt = 0; rt < 4; ++rt) {
                acc[rt][cti] = __builtin_amdgcn_mfma_f32_16x16x32_f16(ahf[rt], bh, acc[rt][cti], 0, 0, 0);
                acc[rt][cti] = __builtin_amdgcn_mfma_f32_16x16x32_f16(alf[rt], bh, acc[rt][cti], 0, 0, 0);
                acc[rt][cti] = __builtin_amdgcn_mfma_f32_16x16x32_f16(ahf[rt], bl, acc[rt][cti], 0, 0, 0);
            }
        }
    }
#pragma unroll
    for (int rt = 0; rt < 4; ++rt)
#pragma unroll
        for (int cti = 0; cti < 2; ++cti)
#pragma unroll
            for (int i = 0; i < 4; ++i) {
                int row = g0 + rt * 16 + (lane >> 4) * 4 + i;
                int col = (ct0 + cti) * 16 + (lane & 15);
                Hp[(size_t)row * CC + col] = acc[rt][cti][i];
            }
}

// ---- GCN aggregate (float2 lanes, 4-edge unroll, XCD-swizzled) ----
__global__ __launch_bounds__(256) void k_gcn_agg(
    const float* __restrict__ H, const float* __restrict__ dinv,
    const int* __restrict__ rowptr, const int* __restrict__ csr_row,
    const float* __restrict__ bias, float* __restrict__ out) {
    int wid = threadIdx.x >> 6, lane = threadIdx.x & 63;
    int g = xcd_swz(blockIdx.x, gridDim.x) * 4 + wid;
    int b = g / NN, v = g - b * NN;
    int bN = b * NN, bE = b * ET;
    int s0 = rowptr[b * RP + v], s1 = rowptr[b * RP + v + 1];
    float dv = dinv[g];
    float a0 = 0.f, a1 = 0.f, c0 = 0.f, c1 = 0.f;
    float e0 = 0.f, e1 = 0.f, f0 = 0.f, f1 = 0.f;
    int j = s0;
    for (; j + 3 < s1; j += 4) {
        int r0 = csr_row[bE + j],     r1 = csr_row[bE + j + 1];
        int r2 = csr_row[bE + j + 2], r3 = csr_row[bE + j + 3];
        float d0 = dinv[bN + r0], d1 = dinv[bN + r1];
        float d2 = dinv[bN + r2], d3 = dinv[bN + r3];
        float2 h0 = ((const float2*)(H + (size_t)(bN + r0) * CC))[lane];
        float2 h1 = ((const float2*)(H + (size_t)(bN + r1) * CC))[lane];
        float2 h2 = ((const float2*)(H + (size_t)(bN + r2) * CC))[lane];
        float2 h3 = ((const float2*)(H + (size_t)(bN + r3) * CC))[lane];
        a0 = fmaf(d0, h0.x, a0); a1 = fmaf(d0, h0.y, a1);
        c0 = fmaf(d1, h1.x, c0); c1 = fmaf(d1, h1.y, c1);
        e0 = fmaf(d2, h2.x, e0); e1 = fmaf(d2, h2.y, e1);
        f0 = fmaf(d3, h3.x, f0); f1 = fmaf(d3, h3.y, f1);
    }
    for (; j < s1; ++j) {
        int r0 = csr_row[bE + j];
        float d0 = dinv[bN + r0];
        float2 h0 = ((const float2*)(H + (size_t)(bN + r0) * CC))[lane];
        a0 = fmaf(d0, h0.x, a0); a1 = fmaf(d0, h0.y, a1);
    }
    a0 += c0 + e0 + f0; a1 += c1 + e1 + f1;
    float2 bb = ((const float2*)bias)[lane];
    float2 o;
    o.x = lrelu01(a0 * dv + bb.x);
    o.y = lrelu01(a1 * dv + bb.y);
    ((float2*)(out + (size_t)g * CC))[lane] = o;
}

// ---- GAT aggregate with softmax (float2 lanes, 4-edge unroll, XCD-swizzled) ----
template <int MODE>
__global__ __launch_bounds__(256) void k_gat_agg(
    const float* __restrict__ Hp, const float* __restrict__ asrc,
    const float* __restrict__ adst, const int* __restrict__ rowptr,
    const int* __restrict__ csr_row, const float* __restrict__ bias,
    float* __restrict__ out) {
    int wid = threadIdx.x >> 6, lane = threadIdx.x & 63;
    int g = xcd_swz(blockIdx.x, gridDim.x) * 4 + wid;
    int b = g / NN, v = g - b * NN;
    int bN = b * NN, bE = b * ET;
    int s0 = rowptr[b * RP + v], s1 = rowptr[b * RP + v + 1];
    float adv = adst[g];
    float m = -3.0e38f;
    for (int j = s0 + lane; j < s1; j += 64)
        m = fmaxf(m, lrelu2(asrc[bN + csr_row[bE + j]] + adv));
    m = wmax(m);
    float ssum = 0.f;
    for (int j = s0 + lane; j < s1; j += 64)
        ssum += __expf(lrelu2(asrc[bN + csr_row[bE + j]] + adv) - m);
    ssum = wsum(ssum);
    float inv = 1.f / (ssum + 1e-16f);
    float a0 = 0.f, a1 = 0.f, c0 = 0.f, c1 = 0.f;
    float e0 = 0.f, e1 = 0.f, f0 = 0.f, f1 = 0.f;
    int j = s0;
    for (; j + 3 < s1; j += 4) {
        int r0 = csr_row[bE + j],     r1 = csr_row[bE + j + 1];
        int r2 = csr_row[bE + j + 2], r3 = csr_row[bE + j + 3];
        float w0 = __expf(lrelu2(asrc[bN + r0] + adv) - m) * inv;
        float w1 = __expf(lrelu2(asrc[bN + r1] + adv) - m) * inv;
        float w2 = __expf(lrelu2(asrc[bN + r2] + adv) - m) * inv;
        float w3 = __expf(lrelu2(asrc[bN + r3] + adv) - m) * inv;
        float2 h0 = ((const float2*)(Hp + (size_t)(bN + r0) * CC))[lane];
        float2 h1 = ((const float2*)(Hp + (size_t)(bN + r1) * CC))[lane];
        float2 h2 = ((const float2*)(Hp + (size_t)(bN + r2) * CC))[lane];
        float2 h3 = ((const float2*)(Hp + (size_t)(bN + r3) * CC))[lane];
        a0 = fmaf(w0, h0.x, a0); a1 = fmaf(w0, h0.y, a1);
        c0 = fmaf(w1, h1.x, c0); c1 = fmaf(w1, h1.y, c1);
        e0 = fmaf(w2, h2.x, e0); e1 = fmaf(w2, h2.y, e1);
        f0 = fmaf(w3, h3.x, f0); f1 = fmaf(w3, h3.y, f1);
    }
    for (; j < s1; ++j) {
        int r0 = csr_row[bE + j];
        float w0 = __expf(lrelu2(asrc[bN + r0] + adv) - m) * inv;
        float2 h0 = ((const float2*)(Hp + (size_t)(bN + r0) * CC))[lane];
        a0 = fmaf(w0, h0.x, a0); a1 = fmaf(w0, h0.y, a1);
    }
    a0 += c0 + e0 + f0; a1 += c1 + e1 + f1;
    float2 bb = ((const float2*)bias)[lane];
    float t0 = a0 + bb.x, t1 = a1 + bb.y;
    float2 o;
    if (MODE == 0) { o.x = lrelu01(t0) + t0; o.y = lrelu01(t1) + t1; }
    else           { o.x = lrelu01(t0);      o.y = lrelu01(t1); }
    ((float2*)(out + (size_t)g * CC))[lane] = o;
}

// ---- GCN2 per-node dot ----
__global__ __launch_bounds__(256) void k_out_dot(
    const float* __restrict__ h, const float* __restrict__ Wout,
    float* __restrict__ p) {
    int wid = threadIdx.x >> 6, lane = threadIdx.x & 63;
    int g = blockIdx.x * 4 + wid;
    float2 h2 = ((const float2*)(h + (size_t)g * CC))[lane];
    float2 w2 = ((const float2*)Wout)[lane];
    float x = wsum(h2.x * w2.x + h2.y * w2.y);
    if (lane == 0) p[g] = x;
}

__global__ __launch_bounds__(256) void k_out_agg(
    const float* __restrict__ p, const float* __restrict__ dinv,
    const int* __restrict__ rowptr, const int* __restrict__ csr_row,
    const float* __restrict__ bout, float* __restrict__ gv) {
    int wid = threadIdx.x >> 6, lane = threadIdx.x & 63;
    int g = xcd_swz(blockIdx.x, gridDim.x) * 4 + wid;
    int b = g / NN, v = g - b * NN;
    int s0 = rowptr[b * RP + v], s1 = rowptr[b * RP + v + 1];
    float acc = 0.f;
    for (int j = s0 + lane; j < s1; j += 64) {
        int r = csr_row[b * ET + j];
        acc += dinv[b * NN + r] * p[b * NN + r];
    }
    acc = wsum(acc);
    if (lane == 0) gv[g] = lrelu01(acc * dinv[g] + bout[0]);
}

__global__ __launch_bounds__(128) void k_fc(
    const float* __restrict__ gv, const float* __restrict__ W1,
    const float* __restrict__ b1, const float* __restrict__ W2,
    const float* __restrict__ b2, float* __restrict__ outp) {
    __shared__ float gs[NN];
    __shared__ float s1[CC];
    int b = blockIdx.x, tx = threadIdx.x;
    for (int v = tx; v < NN; v += 128) gs[v] = gv[b * NN + v];
    __syncthreads();
    float acc = 0.f;
    for (int v = 0; v < NN; ++v) acc = fmaf(gs[v], W1[v * CC + tx], acc);
    float t = lrelu01(acc + b1[tx]);
    s1[tx] = t;
    __syncthreads();
    float acc2 = 0.f;
#pragma unroll
    for (int k = 0; k < CC; ++k) acc2 = fmaf(s1[k], W2[k * CC + tx], acc2);
    outp[b * CC + tx] = acc2 + b2[tx];
}

extern "C" void kernel_launch(void* const* d_in, const int* in_sizes, int n_in,
                              void* d_out, int out_size, void* d_ws, size_t ws_size,
                              hipStream_t stream) {
    const int*   feature  = (const int*)d_in[0];
    const int*   edges    = (const int*)d_in[1];
    const float* poi      = (const float*)d_in[3];
    const float* cat      = (const float*)d_in[4];
    const float* lat      = (const float*)d_in[5];
    const float* lon      = (const float*)d_in[6];
    const float* W_in     = (const float*)d_in[7];
    const float* b_in     = (const float*)d_in[8];
    const float* gat_W    = (const float*)d_in[9];
    const float* gat_asrc = (const float*)d_in[10];
    const float* gat_adst = (const float*)d_in[11];
    const float* gat_b    = (const float*)d_in[12];
    const float* W_out    = (const float*)d_in[13];
    const float* b_out    = (const float*)d_in[14];
    const float* W_fc1    = (const float*)d_in[15];
    const float* b_fc1    = (const float*)d_in[16];
    const float* W_fc2    = (const float*)d_in[17];
    const float* b_fc2    = (const float*)d_in[18];
    float* outp = (float*)d_out;

    char* ws = (char*)d_ws;
    size_t off = 0;
    auto take = [&](size_t bytes) -> char* {
        char* pp = ws + off;
        off = (off + bytes + 255) & ~(size_t)255;
        return pp;
    };
    int*   row32  = (int*)take((size_t)BB * ET * 4);
    int*   col32  = (int*)take((size_t)BB * ET * 4);
    int*   csr    = (int*)take((size_t)BB * ET * 4);
    int*   rowptr = (int*)take((size_t)BB * RP * 4);
    int*   cursor = (int*)take((size_t)BB * RP * 4);
    float* dinv   = (float*)take((size_t)NBt * 4);
    float* asrc   = (float*)take((size_t)NBt * 4);
    float* adst   = (float*)take((size_t)NBt * 4);
    float* pscal  = (float*)take((size_t)NBt * 4);
    float* gvec   = (float*)take((size_t)NBt * 4);
    float* bufA   = (float*)take((size_t)NBt * CC * 4);
    float* bufB   = (float*)take((size_t)NBt * CC * 4);
    f16*   BWh    = (f16*)take((size_t)KSE * 8 * 64 * 8 * 2);
    f16*   BWl    = (f16*)take((size_t)KSE * 8 * 64 * 8 * 2);
    f16*   BGh    = (f16*)take((size_t)3 * 4 * 8 * 64 * 8 * 2);
    f16*   BGl    = (f16*)take((size_t)3 * 4 * 8 * 64 * 8 * 2);
    float* wsv    = (float*)take((size_t)3 * CC * 4);
    float* wdv    = (float*)take((size_t)3 * CC * 4);

    const int nE = BB * ET;
    hipMemsetAsync(dinv, 0, (size_t)NBt * 4, stream);
    k_edge_prep<<<(nE + 255) / 256, 256, 0, stream>>>(edges, row32, col32, dinv);
    k_scan<<<BB, 1024, 0, stream>>>(dinv, rowptr, cursor);
    k_scatter<<<(nE + 255) / 256, 256, 0, stream>>>(row32, col32, cursor, csr);

    k_pack_Win<<<(KSE * 8 * 64 + 255) / 256, 256, 0, stream>>>(W_in, BWh, BWl);
    k_pack_Wgat<<<(3 * 4 * 8 * 64 + 255) / 256, 256, 0, stream>>>(gat_W, BGh, BGl);
    k_wsd<<<3, 128, 0, stream>>>(gat_W, gat_asrc, gat_adst, wsv, wdv);

    k_embed_gemm<<<NBt / 64, 256, 0, stream>>>(feature, poi, cat, lat, lon, BWh, BWl, bufB);
    k_gcn_agg<<<NBt / 4, 256, 0, stream>>>(bufB, dinv, rowptr, csr, b_in, bufA);

    for (int i = 0; i < 3; ++i) {
        const f16* bh = BGh + (size_t)i * 4 * 8 * 64 * 8;
        const f16* bl = BGl + (size_t)i * 4 * 8 * 64 * 8;
        const float* ws_i = wsv + (size_t)i * CC;
        const float* wd_i = wdv + (size_t)i * CC;
        const float* gb = gat_b + (size_t)i * CC;
        k_gat_gemm<<<NBt / 64, 256, 0, stream>>>(bufA, bh, bl, ws_i, wd_i, bufB, asrc, adst);
        k_gat_agg<0><<<NBt / 4, 256, 0, stream>>>(bufB, asrc, adst, rowptr, csr, gb, bufA);
        k_gat_gemm<<<NBt / 64, 256, 0, stream>>>(bufA, bh, bl, ws_i, wd_i, bufB, asrc, adst);
        k_gat_agg<1><<<NBt / 4, 256, 0, stream>>>(bufB, asrc, adst, rowptr, csr, gb, bufA);
    }

    k_out_dot<<<NBt / 4, 256, 0, stream>>>(bufA, W_out, pscal);
    k_out_agg<<<NBt / 4, 256, 0, stream>>>(pscal, dinv, rowptr, csr, b_out, gvec);
    k_fc<<<BB, 128, 0, stream>>>(gvec, W_fc1, b_fc1, W_fc2, b_fc2, outp);
}

// Round 5
// 492.244 us; speedup vs baseline: 2.6607x; 1.3897x over previous
//
#include <hip/hip_runtime.h>

// UserGraphNet: B=64 graphs, n=714 nodes, E=16384 edges (+n self loops), C=128.
// Round 4: unified agg kernel — per-edge softmax weights precomputed once into LDS
// (phase 1), then float4 half-wave gather (2 edges/instruction, phase 2).
// XCD-aware bijective block swizzle (T1) throughout. GEMMs via MFMA split-f16.

#define BB 64
#define NN 714
#define EE 16384
#define ET (EE + NN)          // 17098 edges incl self loops
#define NBt (BB * NN)         // 45696 total nodes
#define CC 128
#define RP (NN + 1)           // rowptr entries per graph
#define KSE 26                // embed k-steps (K=800 padded to 832)
#define CHE 13                // embed 64-wide k-chunks
#define DMAX 256              // max degree on the fast agg path

typedef _Float16 f16;
typedef __attribute__((ext_vector_type(8))) _Float16 f16x8;
typedef __attribute__((ext_vector_type(4))) float f32x4;

__device__ __forceinline__ float lrelu01(float x) { return x > 0.f ? x : 0.01f * x; }
__device__ __forceinline__ float lrelu2(float x)  { return x > 0.f ? x : 0.2f  * x; }

__device__ __forceinline__ float wsum(float x) {
#pragma unroll
    for (int o = 32; o > 0; o >>= 1) x += __shfl_xor(x, o);
    return x;
}
__device__ __forceinline__ float wmax(float x) {
#pragma unroll
    for (int o = 32; o > 0; o >>= 1) x = fmaxf(x, __shfl_xor(x, o));
    return x;
}

// Bijective XCD swizzle (m204): hw round-robins bid->XCD bid%8; remap so XCD x
// processes a contiguous chunk of work. Valid for any nwg.
__device__ __forceinline__ int xcd_swz(int bid, int nwg) {
    int q = nwg >> 3, r = nwg & 7;
    int x = bid & 7, l = bid >> 3;
    int base = (x < r) ? x * (q + 1) : r * (q + 1) + (x - r) * q;
    return base + l;
}

// ---- edge prep ----
__global__ void k_edge_prep(const int* __restrict__ edges, int* __restrict__ row32,
                            int* __restrict__ col32, float* __restrict__ deg) {
    int idx = blockIdx.x * blockDim.x + threadIdx.x;
    if (idx >= BB * ET) return;
    int b = idx / ET, e = idx - b * ET;
    int r, c;
    if (e < EE) { r = edges[b * 2 * EE + e]; c = edges[b * 2 * EE + EE + e]; }
    else        { r = c = e - EE; }
    row32[idx] = r; col32[idx] = c;
    atomicAdd(&deg[b * NN + c], 1.0f);
}

__global__ void k_scan(float* degdinv, int* __restrict__ rowptr, int* __restrict__ cursor) {
    __shared__ int s[1024];
    int b = blockIdx.x, v = threadIdx.x;
    int cnt = 0; float d = 0.f;
    if (v < NN) { d = degdinv[b * NN + v]; cnt = (int)d; }
    s[v] = cnt;
    __syncthreads();
    for (int off = 1; off < 1024; off <<= 1) {
        int val = (v >= off) ? s[v - off] : 0;
        __syncthreads();
        s[v] += val;
        __syncthreads();
    }
    if (v < NN) {
        degdinv[b * NN + v] = d > 0.f ? rsqrtf(d) : 0.f;
        rowptr[b * RP + v + 1] = s[v];
        cursor[b * RP + v] = (v == 0) ? 0 : s[v - 1];
    }
    if (v == 0) rowptr[b * RP] = 0;
}

__global__ void k_scatter(const int* __restrict__ row32, const int* __restrict__ col32,
                          int* __restrict__ cursor, int* __restrict__ csr_row) {
    int idx = blockIdx.x * blockDim.x + threadIdx.x;
    if (idx >= BB * ET) return;
    int b = idx / ET;
    int c = col32[idx];
    int slot = atomicAdd(&cursor[b * RP + c], 1);
    csr_row[b * ET + slot] = row32[idx];
}

// ---- pack W_in (800x128, K padded to 832) into frag layout hi/lo ----
__global__ void k_pack_Win(const float* __restrict__ W, f16* __restrict__ Bh, f16* __restrict__ Bl) {
    int idx = blockIdx.x * 256 + threadIdx.x;     // (ks*8+ct)*64 + lane
    if (idx >= KSE * 8 * 64) return;
    int lane = idx & 63, tc = idx >> 6;
    int ct = tc & 7, ks = tc >> 3;
    f16x8 ph, pl;
#pragma unroll
    for (int j = 0; j < 8; ++j) {
        int k = ks * 32 + (lane >> 4) * 8 + j;
        int c = ct * 16 + (lane & 15);
        float v = (k < 800) ? W[k * CC + c] : 0.f;
        f16 hi = (f16)v;
        ph[j] = hi; pl[j] = (f16)(v - (float)hi);
    }
    *(f16x8*)(Bh + (size_t)idx * 8) = ph;
    *(f16x8*)(Bl + (size_t)idx * 8) = pl;
}

// ---- pack gat_W (3 x 128x128) into frag layout hi/lo ----
__global__ void k_pack_Wgat(const float* __restrict__ W, f16* __restrict__ Bh, f16* __restrict__ Bl) {
    int idx = blockIdx.x * 256 + threadIdx.x;     // ((i*4+ks)*8+ct)*64 + lane
    if (idx >= 3 * 4 * 8 * 64) return;
    int lane = idx & 63, tc = idx >> 6;
    int ct = tc & 7; tc >>= 3;
    int ks = tc & 3, li = tc >> 2;
    const float* Wl = W + (size_t)li * CC * CC;
    f16x8 ph, pl;
#pragma unroll
    for (int j = 0; j < 8; ++j) {
        int k = ks * 32 + (lane >> 4) * 8 + j;
        int c = ct * 16 + (lane & 15);
        float v = Wl[k * CC + c];
        f16 hi = (f16)v;
        ph[j] = hi; pl[j] = (f16)(v - (float)hi);
    }
    *(f16x8*)(Bh + (size_t)idx * 8) = ph;
    *(f16x8*)(Bl + (size_t)idx * 8) = pl;
}

// ---- w_s = W.a_src, w_d = W.a_dst per layer ----
__global__ void k_wsd(const float* __restrict__ gat_W, const float* __restrict__ a_s,
                      const float* __restrict__ a_d, float* __restrict__ wsv, float* __restrict__ wdv) {
    int i = blockIdx.x, k = threadIdx.x;
    const float* W = gat_W + (size_t)i * CC * CC;
    float s = 0.f, d = 0.f;
#pragma unroll 4
    for (int c = 0; c < CC; ++c) {
        float w = W[k * CC + c];
        s = fmaf(w, a_s[i * CC + c], s);
        d = fmaf(w, a_d[i * CC + c], d);
    }
    wsv[i * CC + k] = s; wdv[i * CC + k] = d;
}

// ---- fused embedding-gather + X@W_in via MFMA split-f16 ----
__global__ __launch_bounds__(256) void k_embed_gemm(
    const int* __restrict__ feature, const float* __restrict__ poi,
    const float* __restrict__ cat, const float* __restrict__ lat,
    const float* __restrict__ lon, const f16* __restrict__ Bh,
    const f16* __restrict__ Bl, float* __restrict__ out) {
    __shared__ __align__(16) f16 Ah[64 * 64];
    __shared__ __align__(16) f16 Al[64 * 64];
    int t = threadIdx.x;
    int g0 = xcd_swz(blockIdx.x, gridDim.x) * 64;
    int lane = t & 63, w = t >> 6;
    int sr = t >> 2;            // staging row
    int skb = (t & 3) * 16;     // staging k base within chunk
    const int* f = feature + (size_t)(g0 + sr) * 5;
    int f0 = f[0], f1 = f[1], f3 = f[3], f4 = f[4];
    f32x4 acc[4][2];
#pragma unroll
    for (int rt = 0; rt < 4; ++rt)
#pragma unroll
        for (int c = 0; c < 2; ++c) acc[rt][c] = (f32x4){0.f, 0.f, 0.f, 0.f};
    int ct0 = w * 2;

    for (int ch = 0; ch < CHE; ++ch) {
        int kc = ch * 64;
        __syncthreads();
        float v[16];
        int gk = kc + skb;
        if (gk >= 800) {
#pragma unroll
            for (int m = 0; m < 16; ++m) v[m] = 0.f;
        } else if (gk == 288 || gk == 592) {
            // block crosses a concat-segment boundary (300 or 600): scalar ladder
#pragma unroll
            for (int m = 0; m < 16; ++m) {
                int k = gk + m;
                float val;
                if (k < 300)      val = poi[(size_t)f0 * 300 + k];
                else if (k < 400) val = cat[(size_t)f1 * 100 + (k - 300)];
                else if (k < 600) val = lat[(size_t)f3 * 200 + (k - 400)];
                else              val = lon[(size_t)f4 * 200 + (k - 600)];
                v[m] = val;
            }
        } else {
            const float* src;
            if (gk >= 600)      src = lon + (size_t)f4 * 200 + (gk - 600);
            else if (gk >= 400) src = lat + (size_t)f3 * 200 + (gk - 400);
            else if (gk >= 300) src = cat + (size_t)f1 * 100 + (gk - 300);
            else                src = poi + (size_t)f0 * 300 + gk;
            const float4* s4 = (const float4*)src;
#pragma unroll
            for (int q = 0; q < 4; ++q) {
                float4 x = s4[q];
                v[q * 4 + 0] = x.x; v[q * 4 + 1] = x.y; v[q * 4 + 2] = x.z; v[q * 4 + 3] = x.w;
            }
        }
        f16x8 ph0, ph1, pl0, pl1;
#pragma unroll
        for (int j = 0; j < 8; ++j) {
            f16 h0 = (f16)v[j];     ph0[j] = h0; pl0[j] = (f16)(v[j] - (float)h0);
            f16 h1 = (f16)v[8 + j]; ph1[j] = h1; pl1[j] = (f16)(v[8 + j] - (float)h1);
        }
        int kg0 = skb >> 3;
        int a0i = sr * 64 + ((kg0 ^ (sr & 7)) << 3);
        int a1i = sr * 64 + (((kg0 + 1) ^ (sr & 7)) << 3);
        *(f16x8*)&Ah[a0i] = ph0; *(f16x8*)&Ah[a1i] = ph1;
        *(f16x8*)&Al[a0i] = pl0; *(f16x8*)&Al[a1i] = pl1;
        __syncthreads();
#pragma unroll
        for (int kh = 0; kh < 2; ++kh) {
            int ks = ch * 2 + kh;
            f16x8 ahf[4], alf[4];
#pragma unroll
            for (int rt = 0; rt < 4; ++rt) {
                int r = rt * 16 + (lane & 15);
                int kg = (lane >> 4) + kh * 4;
                int ad = r * 64 + ((kg ^ (r & 7)) << 3);
                ahf[rt] = *(const f16x8*)&Ah[ad];
                alf[rt] = *(const f16x8*)&Al[ad];
            }
#pragma unroll
            for (int cti = 0; cti < 2; ++cti) {
                int ct = ct0 + cti;
                f16x8 bh = *(const f16x8*)(Bh + ((size_t)(ks * 8 + ct) * 64 + lane) * 8);
                f16x8 bl = *(const f16x8*)(Bl + ((size_t)(ks * 8 + ct) * 64 + lane) * 8);
#pragma unroll
                for (int rt = 0; rt < 4; ++rt) {
                    acc[rt][cti] = __builtin_amdgcn_mfma_f32_16x16x32_f16(ahf[rt], bh, acc[rt][cti], 0, 0, 0);
                    acc[rt][cti] = __builtin_amdgcn_mfma_f32_16x16x32_f16(alf[rt], bh, acc[rt][cti], 0, 0, 0);
                    acc[rt][cti] = __builtin_amdgcn_mfma_f32_16x16x32_f16(ahf[rt], bl, acc[rt][cti], 0, 0, 0);
                }
            }
        }
    }
#pragma unroll
    for (int rt = 0; rt < 4; ++rt)
#pragma unroll
        for (int cti = 0; cti < 2; ++cti)
#pragma unroll
            for (int i = 0; i < 4; ++i) {
                int row = g0 + rt * 16 + (lane >> 4) * 4 + i;
                int col = (ct0 + cti) * 16 + (lane & 15);
                out[(size_t)row * CC + col] = acc[rt][cti][i];
            }
}

// ---- GAT gemm via MFMA split-f16; asrc/adst fused into staging ----
__global__ __launch_bounds__(256) void k_gat_gemm(
    const float* __restrict__ hin, const f16* __restrict__ Bh, const f16* __restrict__ Bl,
    const float* __restrict__ wsv, const float* __restrict__ wdv,
    float* __restrict__ Hp, float* __restrict__ asrc, float* __restrict__ adst) {
    __shared__ __align__(16) f16 Ah[64 * 128];
    __shared__ __align__(16) f16 Al[64 * 128];
    __shared__ float reds[256], redd[256];
    int t = threadIdx.x;
    int g0 = xcd_swz(blockIdx.x, gridDim.x) * 64;
    int lane = t & 63, w = t >> 6;
    int sr = t >> 2, skb = (t & 3) * 32;
    const float4* hrow = (const float4*)(hin + (size_t)(g0 + sr) * CC + skb);
    float v[32];
    float ps = 0.f, pd = 0.f;
#pragma unroll
    for (int q = 0; q < 8; ++q) {
        float4 x = hrow[q];
        v[q * 4 + 0] = x.x; v[q * 4 + 1] = x.y; v[q * 4 + 2] = x.z; v[q * 4 + 3] = x.w;
    }
#pragma unroll
    for (int m = 0; m < 32; ++m) {
        ps = fmaf(v[m], wsv[skb + m], ps);
        pd = fmaf(v[m], wdv[skb + m], pd);
    }
#pragma unroll
    for (int q = 0; q < 4; ++q) {
        f16x8 ph, pl;
#pragma unroll
        for (int j = 0; j < 8; ++j) {
            float x = v[q * 8 + j];
            f16 hi = (f16)x;
            ph[j] = hi; pl[j] = (f16)(x - (float)hi);
        }
        int kg = (skb >> 3) + q;
        int ad = sr * 128 + ((kg ^ (sr & 7)) << 3);
        *(f16x8*)&Ah[ad] = ph; *(f16x8*)&Al[ad] = pl;
    }
    reds[t] = ps; redd[t] = pd;
    __syncthreads();
    if (t < 64) {
        asrc[g0 + t] = reds[t * 4] + reds[t * 4 + 1] + reds[t * 4 + 2] + reds[t * 4 + 3];
        adst[g0 + t] = redd[t * 4] + redd[t * 4 + 1] + redd[t * 4 + 2] + redd[t * 4 + 3];
    }
    f32x4 acc[4][2];
#pragma unroll
    for (int rt = 0; rt < 4; ++rt)
#pragma unroll
        for (int c = 0; c < 2; ++c) acc[rt][c] = (f32x4){0.f, 0.f, 0.f, 0.f};
    int ct0 = w * 2;
#pragma unroll
    for (int ks = 0; ks < 4; ++ks) {
        f16x8 ahf[4], alf[4];
#pragma unroll
        for (int rt = 0; rt < 4; ++rt) {
            int r = rt * 16 + (lane & 15);
            int kg = (lane >> 4) + ks * 4;
            int ad = r * 128 + ((kg ^ (r & 7)) << 3);
            ahf[rt] = *(const f16x8*)&Ah[ad];
            alf[rt] = *(const f16x8*)&Al[ad];
        }
#pragma unroll
        for (int cti = 0; cti < 2; ++cti) {
            int ct = ct0 + cti;
            f16x8 bh = *(const f16x8*)(Bh + ((size_t)(ks * 8 + ct) * 64 + lane) * 8);
            f16x8 bl = *(const f16x8*)(Bl + ((size_t)(ks * 8 + ct) * 64 + lane) * 8);
#pragma unroll
            for (int rt = 0; rt < 4; ++rt) {
                acc[rt][cti] = __builtin_amdgcn_mfma_f32_16x16x32_f16(ahf[rt], bh, acc[rt][cti], 0, 0, 0);
                acc[rt][cti] = __builtin_amdgcn_mfma_f32_16x16x32_f16(alf[rt], bh, acc[rt][cti], 0, 0, 0);
                acc[rt][cti] = __builtin_amdgcn_mfma_f32_16x16x32_f16(ahf[rt], bl, acc[rt][cti], 0, 0, 0);
            }
        }
    }
#pragma unroll
    for (int rt = 0; rt < 4; ++rt)
#pragma unroll
        for (int cti = 0; cti < 2; ++cti)
#pragma unroll
            for (int i = 0; i < 4; ++i) {
                int row = g0 + rt * 16 + (lane >> 4) * 4 + i;
                int col = (ct0 + cti) * 16 + (lane & 15);
                Hp[(size_t)row * CC + col] = acc[rt][cti][i];
            }
}

// ---- unified aggregate kernel ----
// MODE 0: GAT, out = lrelu01(t)+t. MODE 1: GAT, out = lrelu01(t). MODE 2: GCN.
// aux = asrc (GAT) or dinv (GCN). Phase 1 computes per-edge weights (w,r) into LDS
// once; phase 2 gathers float4 rows with 2 edges in flight per half-wave.
template <int MODE>
__global__ __launch_bounds__(256) void k_agg(
    const float* __restrict__ Hp, const float* __restrict__ aux,
    const float* __restrict__ adst, const int* __restrict__ rowptr,
    const int* __restrict__ csr_row, const float* __restrict__ bias,
    float* __restrict__ out) {
    __shared__ float2 pr[4][DMAX];
    int wid = threadIdx.x >> 6, lane = threadIdx.x & 63;
    int g = xcd_swz(blockIdx.x, gridDim.x) * 4 + wid;
    int b = g / NN, v = g - b * NN;
    int bN = b * NN, bE = b * ET;
    int s0 = rowptr[b * RP + v], s1 = rowptr[b * RP + v + 1];
    int deg = s1 - s0;
    int half = lane >> 5, fl = lane & 31;

    if (deg <= DMAX) {
        // ---- phase 1: per-edge (weight, row) into LDS (each lane owns jj = lane mod 64) ----
        if (MODE == 2) {
            float dv = aux[g];
            for (int jj = lane; jj < deg; jj += 64) {
                int r = csr_row[bE + s0 + jj];
                pr[wid][jj] = make_float2(aux[bN + r] * dv, __int_as_float(r));
            }
        } else {
            float adv = adst[g];
            float m = -3.0e38f;
            for (int jj = lane; jj < deg; jj += 64) {
                int r = csr_row[bE + s0 + jj];
                float e = lrelu2(aux[bN + r] + adv);
                pr[wid][jj] = make_float2(e, __int_as_float(r));
                m = fmaxf(m, e);
            }
            m = wmax(m);
            float ss = 0.f;
            for (int jj = lane; jj < deg; jj += 64) {
                float w = __expf(pr[wid][jj].x - m);
                ss += w;
                pr[wid][jj].x = w;
            }
            ss = wsum(ss);
            float inv = 1.f / (ss + 1e-16f);
            for (int jj = lane; jj < deg; jj += 64) pr[wid][jj].x *= inv;
        }
        // DS unit is in-order per wave: phase-2 cross-lane reads see phase-1 writes.
        // ---- phase 2: float4 gather, 2 edges per half-wave step, 2 chains ----
        float4 a0 = {0.f, 0.f, 0.f, 0.f}, a1 = {0.f, 0.f, 0.f, 0.f};
        int jj = 0;
        for (; jj + 3 < deg; jj += 4) {
            float2 p0 = pr[wid][jj + half];
            float2 p1 = pr[wid][jj + 2 + half];
            int r0 = __float_as_int(p0.y), r1 = __float_as_int(p1.y);
            float4 h0 = ((const float4*)(Hp + (size_t)(bN + r0) * CC))[fl];
            float4 h1 = ((const float4*)(Hp + (size_t)(bN + r1) * CC))[fl];
            a0.x = fmaf(p0.x, h0.x, a0.x); a0.y = fmaf(p0.x, h0.y, a0.y);
            a0.z = fmaf(p0.x, h0.z, a0.z); a0.w = fmaf(p0.x, h0.w, a0.w);
            a1.x = fmaf(p1.x, h1.x, a1.x); a1.y = fmaf(p1.x, h1.y, a1.y);
            a1.z = fmaf(p1.x, h1.z, a1.z); a1.w = fmaf(p1.x, h1.w, a1.w);
        }
        for (; jj + 1 < deg; jj += 2) {
            float2 p0 = pr[wid][jj + half];
            int r0 = __float_as_int(p0.y);
            float4 h0 = ((const float4*)(Hp + (size_t)(bN + r0) * CC))[fl];
            a0.x = fmaf(p0.x, h0.x, a0.x); a0.y = fmaf(p0.x, h0.y, a0.y);
            a0.z = fmaf(p0.x, h0.z, a0.z); a0.w = fmaf(p0.x, h0.w, a0.w);
        }
        if (jj < deg && half == 0) {
            float2 p0 = pr[wid][jj];
            int r0 = __float_as_int(p0.y);
            float4 h0 = ((const float4*)(Hp + (size_t)(bN + r0) * CC))[fl];
            a0.x = fmaf(p0.x, h0.x, a0.x); a0.y = fmaf(p0.x, h0.y, a0.y);
            a0.z = fmaf(p0.x, h0.z, a0.z); a0.w = fmaf(p0.x, h0.w, a0.w);
        }
        a0.x += a1.x; a0.y += a1.y; a0.z += a1.z; a0.w += a1.w;
        a0.x += __shfl_xor(a0.x, 32); a0.y += __shfl_xor(a0.y, 32);
        a0.z += __shfl_xor(a0.z, 32); a0.w += __shfl_xor(a0.w, 32);
        if (half == 0) {
            float4 bb = ((const float4*)bias)[fl];
            float t0 = a0.x + bb.x, t1 = a0.y + bb.y, t2 = a0.z + bb.z, t3 = a0.w + bb.w;
            float4 o;
            if (MODE == 0) {
                o.x = lrelu01(t0) + t0; o.y = lrelu01(t1) + t1;
                o.z = lrelu01(t2) + t2; o.w = lrelu01(t3) + t3;
            } else {
                o.x = lrelu01(t0); o.y = lrelu01(t1);
                o.z = lrelu01(t2); o.w = lrelu01(t3);
            }
            ((float4*)(out + (size_t)g * CC))[fl] = o;
        }
        return;
    }
    // ---- fallback deg > DMAX (float2 full-wave path; practically never taken) ----
    if (MODE == 2) {
        float dv = aux[g];
        float x0 = 0.f, x1 = 0.f;
        for (int j = s0; j < s1; ++j) {
            int r = csr_row[bE + j];
            float d0 = aux[bN + r];
            float2 h = ((const float2*)(Hp + (size_t)(bN + r) * CC))[lane];
            x0 = fmaf(d0, h.x, x0); x1 = fmaf(d0, h.y, x1);
        }
        float2 bb = ((const float2*)bias)[lane];
        float2 o;
        o.x = lrelu01(x0 * dv + bb.x);
        o.y = lrelu01(x1 * dv + bb.y);
        ((float2*)(out + (size_t)g * CC))[lane] = o;
    } else {
        float adv = adst[g];
        float m = -3.0e38f;
        for (int j = s0 + lane; j < s1; j += 64)
            m = fmaxf(m, lrelu2(aux[bN + csr_row[bE + j]] + adv));
        m = wmax(m);
        float ssum = 0.f;
        for (int j = s0 + lane; j < s1; j += 64)
            ssum += __expf(lrelu2(aux[bN + csr_row[bE + j]] + adv) - m);
        ssum = wsum(ssum);
        float inv = 1.f / (ssum + 1e-16f);
        float x0 = 0.f, x1 = 0.f;
        for (int j = s0; j < s1; ++j) {
            int r = csr_row[bE + j];
            float wj = __expf(lrelu2(aux[bN + r] + adv) - m) * inv;
            float2 h = ((const float2*)(Hp + (size_t)(bN + r) * CC))[lane];
            x0 = fmaf(wj, h.x, x0); x1 = fmaf(wj, h.y, x1);
        }
        float2 bb = ((const float2*)bias)[lane];
        float t0 = x0 + bb.x, t1 = x1 + bb.y;
        float2 o;
        if (MODE == 0) { o.x = lrelu01(t0) + t0; o.y = lrelu01(t1) + t1; }
        else           { o.x = lrelu01(t0);      o.y = lrelu01(t1); }
        ((float2*)(out + (size_t)g * CC))[lane] = o;
    }
}

// ---- GCN2 per-node dot ----
__global__ __launch_bounds__(256) void k_out_dot(
    const float* __restrict__ h, const float* __restrict__ Wout,
    float* __restrict__ p) {
    int wid = threadIdx.x >> 6, lane = threadIdx.x & 63;
    int g = blockIdx.x * 4 + wid;
    float2 h2 = ((const float2*)(h + (size_t)g * CC))[lane];
    float2 w2 = ((const float2*)Wout)[lane];
    float x = wsum(h2.x * w2.x + h2.y * w2.y);
    if (lane == 0) p[g] = x;
}

__global__ __launch_bounds__(256) void k_out_agg(
    const float* __restrict__ p, const float* __restrict__ dinv,
    const int* __restrict__ rowptr, const int* __restrict__ csr_row,
    const float* __restrict__ bout, float* __restrict__ gv) {
    int wid = threadIdx.x >> 6, lane = threadIdx.x & 63;
    int g = xcd_swz(blockIdx.x, gridDim.x) * 4 + wid;
    int b = g / NN, v = g - b * NN;
    int s0 = rowptr[b * RP + v], s1 = rowptr[b * RP + v + 1];
    float acc = 0.f;
    for (int j = s0 + lane; j < s1; j += 64) {
        int r = csr_row[b * ET + j];
        acc += dinv[b * NN + r] * p[b * NN + r];
    }
    acc = wsum(acc);
    if (lane == 0) gv[g] = lrelu01(acc * dinv[g] + bout[0]);
}

__global__ __launch_bounds__(128) void k_fc(
    const float* __restrict__ gv, const float* __restrict__ W1,
    const float* __restrict__ b1, const float* __restrict__ W2,
    const float* __restrict__ b2, float* __restrict__ outp) {
    __shared__ float gs[NN];
    __shared__ float s1[CC];
    int b = blockIdx.x, tx = threadIdx.x;
    for (int v = tx; v < NN; v += 128) gs[v] = gv[b * NN + v];
    __syncthreads();
    float acc = 0.f;
    for (int v = 0; v < NN; ++v) acc = fmaf(gs[v], W1[v * CC + tx], acc);
    float t = lrelu01(acc + b1[tx]);
    s1[tx] = t;
    __syncthreads();
    float acc2 = 0.f;
#pragma unroll
    for (int k = 0; k < CC; ++k) acc2 = fmaf(s1[k], W2[k * CC + tx], acc2);
    outp[b * CC + tx] = acc2 + b2[tx];
}

extern "C" void kernel_launch(void* const* d_in, const int* in_sizes, int n_in,
                              void* d_out, int out_size, void* d_ws, size_t ws_size,
                              hipStream_t stream) {
    const int*   feature  = (const int*)d_in[0];
    const int*   edges    = (const int*)d_in[1];
    const float* poi      = (const float*)d_in[3];
    const float* cat      = (const float*)d_in[4];
    const float* lat      = (const float*)d_in[5];
    const float* lon      = (const float*)d_in[6];
    const float* W_in     = (const float*)d_in[7];
    const float* b_in     = (const float*)d_in[8];
    const float* gat_W    = (const float*)d_in[9];
    const float* gat_asrc = (const float*)d_in[10];
    const float* gat_adst = (const float*)d_in[11];
    const float* gat_b    = (const float*)d_in[12];
    const float* W_out    = (const float*)d_in[13];
    const float* b_out    = (const float*)d_in[14];
    const float* W_fc1    = (const float*)d_in[15];
    const float* b_fc1    = (const float*)d_in[16];
    const float* W_fc2    = (const float*)d_in[17];
    const float* b_fc2    = (const float*)d_in[18];
    float* outp = (float*)d_out;

    char* ws = (char*)d_ws;
    size_t off = 0;
    auto take = [&](size_t bytes) -> char* {
        char* pp = ws + off;
        off = (off + bytes + 255) & ~(size_t)255;
        return pp;
    };
    int*   row32  = (int*)take((size_t)BB * ET * 4);
    int*   col32  = (int*)take((size_t)BB * ET * 4);
    int*   csr    = (int*)take((size_t)BB * ET * 4);
    int*   rowptr = (int*)take((size_t)BB * RP * 4);
    int*   cursor = (int*)take((size_t)BB * RP * 4);
    float* dinv   = (float*)take((size_t)NBt * 4);
    float* asrc   = (float*)take((size_t)NBt * 4);
    float* adst   = (float*)take((size_t)NBt * 4);
    float* pscal  = (float*)take((size_t)NBt * 4);
    float* gvec   = (float*)take((size_t)NBt * 4);
    float* bufA   = (float*)take((size_t)NBt * CC * 4);
    float* bufB   = (float*)take((size_t)NBt * CC * 4);
    f16*   BWh    = (f16*)take((size_t)KSE * 8 * 64 * 8 * 2);
    f16*   BWl    = (f16*)take((size_t)KSE * 8 * 64 * 8 * 2);
    f16*   BGh    = (f16*)take((size_t)3 * 4 * 8 * 64 * 8 * 2);
    f16*   BGl    = (f16*)take((size_t)3 * 4 * 8 * 64 * 8 * 2);
    float* wsv    = (float*)take((size_t)3 * CC * 4);
    float* wdv    = (float*)take((size_t)3 * CC * 4);

    const int nE = BB * ET;
    hipMemsetAsync(dinv, 0, (size_t)NBt * 4, stream);
    k_edge_prep<<<(nE + 255) / 256, 256, 0, stream>>>(edges, row32, col32, dinv);
    k_scan<<<BB, 1024, 0, stream>>>(dinv, rowptr, cursor);
    k_scatter<<<(nE + 255) / 256, 256, 0, stream>>>(row32, col32, cursor, csr);

    k_pack_Win<<<(KSE * 8 * 64 + 255) / 256, 256, 0, stream>>>(W_in, BWh, BWl);
    k_pack_Wgat<<<(3 * 4 * 8 * 64 + 255) / 256, 256, 0, stream>>>(gat_W, BGh, BGl);
    k_wsd<<<3, 128, 0, stream>>>(gat_W, gat_asrc, gat_adst, wsv, wdv);

    k_embed_gemm<<<NBt / 64, 256, 0, stream>>>(feature, poi, cat, lat, lon, BWh, BWl, bufB);
    k_agg<2><<<NBt / 4, 256, 0, stream>>>(bufB, dinv, nullptr, rowptr, csr, b_in, bufA);

    for (int i = 0; i < 3; ++i) {
        const f16* bh = BGh + (size_t)i * 4 * 8 * 64 * 8;
        const f16* bl = BGl + (size_t)i * 4 * 8 * 64 * 8;
        const float* ws_i = wsv + (size_t)i * CC;
        const float* wd_i = wdv + (size_t)i * CC;
        const float* gb = gat_b + (size_t)i * CC;
        k_gat_gemm<<<NBt / 64, 256, 0, stream>>>(bufA, bh, bl, ws_i, wd_i, bufB, asrc, adst);
        k_agg<0><<<NBt / 4, 256, 0, stream>>>(bufB, asrc, adst, rowptr, csr, gb, bufA);
        k_gat_gemm<<<NBt / 64, 256, 0, stream>>>(bufA, bh, bl, ws_i, wd_i, bufB, asrc, adst);
        k_agg<1><<<NBt / 4, 256, 0, stream>>>(bufB, asrc, adst, rowptr, csr, gb, bufA);
    }

    k_out_dot<<<NBt / 4, 256, 0, stream>>>(bufA, W_out, pscal);
    k_out_agg<<<NBt / 4, 256, 0, stream>>>(pscal, dinv, rowptr, csr, b_out, gvec);
    k_fc<<<BB, 128, 0, stream>>>(gvec, W_fc1, b_fc1, W_fc2, b_fc2, outp);
}

// Round 6
// 482.089 us; speedup vs baseline: 2.7167x; 1.0211x over previous
//
#include <hip/hip_runtime.h>

// UserGraphNet: B=64 graphs, n=714 nodes, E=16384 edges (+n self loops), C=128.
// Round 5: double-buffered LDS staging in embed GEMM (gather latency hidden under
// MFMA); agg phase-2 with 4 accumulator chains (8 edges in flight) and deferred
// softmax normalization. XCD-aware bijective swizzle (T1) throughout.

#define BB 64
#define NN 714
#define EE 16384
#define ET (EE + NN)          // 17098 edges incl self loops
#define NBt (BB * NN)         // 45696 total nodes
#define CC 128
#define RP (NN + 1)           // rowptr entries per graph
#define KSE 26                // embed k-steps (K=800 padded to 832)
#define CHE 13                // embed 64-wide k-chunks
#define DMAX 128              // max degree on the fast agg path (deg~24, max~50)

typedef _Float16 f16;
typedef __attribute__((ext_vector_type(8))) _Float16 f16x8;
typedef __attribute__((ext_vector_type(4))) float f32x4;

__device__ __forceinline__ float lrelu01(float x) { return x > 0.f ? x : 0.01f * x; }
__device__ __forceinline__ float lrelu2(float x)  { return x > 0.f ? x : 0.2f  * x; }

__device__ __forceinline__ float wsum(float x) {
#pragma unroll
    for (int o = 32; o > 0; o >>= 1) x += __shfl_xor(x, o);
    return x;
}
__device__ __forceinline__ float wmax(float x) {
#pragma unroll
    for (int o = 32; o > 0; o >>= 1) x = fmaxf(x, __shfl_xor(x, o));
    return x;
}

// Bijective XCD swizzle (m204): hw round-robins bid->XCD bid%8; remap so XCD x
// processes a contiguous chunk of work. Valid for any nwg.
__device__ __forceinline__ int xcd_swz(int bid, int nwg) {
    int q = nwg >> 3, r = nwg & 7;
    int x = bid & 7, l = bid >> 3;
    int base = (x < r) ? x * (q + 1) : r * (q + 1) + (x - r) * q;
    return base + l;
}

// ---- edge prep ----
__global__ void k_edge_prep(const int* __restrict__ edges, int* __restrict__ row32,
                            int* __restrict__ col32, float* __restrict__ deg) {
    int idx = blockIdx.x * blockDim.x + threadIdx.x;
    if (idx >= BB * ET) return;
    int b = idx / ET, e = idx - b * ET;
    int r, c;
    if (e < EE) { r = edges[b * 2 * EE + e]; c = edges[b * 2 * EE + EE + e]; }
    else        { r = c = e - EE; }
    row32[idx] = r; col32[idx] = c;
    atomicAdd(&deg[b * NN + c], 1.0f);
}

__global__ void k_scan(float* degdinv, int* __restrict__ rowptr, int* __restrict__ cursor) {
    __shared__ int s[1024];
    int b = blockIdx.x, v = threadIdx.x;
    int cnt = 0; float d = 0.f;
    if (v < NN) { d = degdinv[b * NN + v]; cnt = (int)d; }
    s[v] = cnt;
    __syncthreads();
    for (int off = 1; off < 1024; off <<= 1) {
        int val = (v >= off) ? s[v - off] : 0;
        __syncthreads();
        s[v] += val;
        __syncthreads();
    }
    if (v < NN) {
        degdinv[b * NN + v] = d > 0.f ? rsqrtf(d) : 0.f;
        rowptr[b * RP + v + 1] = s[v];
        cursor[b * RP + v] = (v == 0) ? 0 : s[v - 1];
    }
    if (v == 0) rowptr[b * RP] = 0;
}

__global__ void k_scatter(const int* __restrict__ row32, const int* __restrict__ col32,
                          int* __restrict__ cursor, int* __restrict__ csr_row) {
    int idx = blockIdx.x * blockDim.x + threadIdx.x;
    if (idx >= BB * ET) return;
    int b = idx / ET;
    int c = col32[idx];
    int slot = atomicAdd(&cursor[b * RP + c], 1);
    csr_row[b * ET + slot] = row32[idx];
}

// ---- pack W_in (800x128, K padded to 832) into frag layout hi/lo ----
__global__ void k_pack_Win(const float* __restrict__ W, f16* __restrict__ Bh, f16* __restrict__ Bl) {
    int idx = blockIdx.x * 256 + threadIdx.x;     // (ks*8+ct)*64 + lane
    if (idx >= KSE * 8 * 64) return;
    int lane = idx & 63, tc = idx >> 6;
    int ct = tc & 7, ks = tc >> 3;
    f16x8 ph, pl;
#pragma unroll
    for (int j = 0; j < 8; ++j) {
        int k = ks * 32 + (lane >> 4) * 8 + j;
        int c = ct * 16 + (lane & 15);
        float v = (k < 800) ? W[k * CC + c] : 0.f;
        f16 hi = (f16)v;
        ph[j] = hi; pl[j] = (f16)(v - (float)hi);
    }
    *(f16x8*)(Bh + (size_t)idx * 8) = ph;
    *(f16x8*)(Bl + (size_t)idx * 8) = pl;
}

// ---- pack gat_W (3 x 128x128) into frag layout hi/lo ----
__global__ void k_pack_Wgat(const float* __restrict__ W, f16* __restrict__ Bh, f16* __restrict__ Bl) {
    int idx = blockIdx.x * 256 + threadIdx.x;     // ((i*4+ks)*8+ct)*64 + lane
    if (idx >= 3 * 4 * 8 * 64) return;
    int lane = idx & 63, tc = idx >> 6;
    int ct = tc & 7; tc >>= 3;
    int ks = tc & 3, li = tc >> 2;
    const float* Wl = W + (size_t)li * CC * CC;
    f16x8 ph, pl;
#pragma unroll
    for (int j = 0; j < 8; ++j) {
        int k = ks * 32 + (lane >> 4) * 8 + j;
        int c = ct * 16 + (lane & 15);
        float v = Wl[k * CC + c];
        f16 hi = (f16)v;
        ph[j] = hi; pl[j] = (f16)(v - (float)hi);
    }
    *(f16x8*)(Bh + (size_t)idx * 8) = ph;
    *(f16x8*)(Bl + (size_t)idx * 8) = pl;
}

// ---- w_s = W.a_src, w_d = W.a_dst per layer ----
__global__ void k_wsd(const float* __restrict__ gat_W, const float* __restrict__ a_s,
                      const float* __restrict__ a_d, float* __restrict__ wsv, float* __restrict__ wdv) {
    int i = blockIdx.x, k = threadIdx.x;
    const float* W = gat_W + (size_t)i * CC * CC;
    float s = 0.f, d = 0.f;
#pragma unroll 4
    for (int c = 0; c < CC; ++c) {
        float w = W[k * CC + c];
        s = fmaf(w, a_s[i * CC + c], s);
        d = fmaf(w, a_d[i * CC + c], d);
    }
    wsv[i * CC + k] = s; wdv[i * CC + k] = d;
}

// ---- fused embedding-gather + X@W_in via MFMA split-f16, double-buffered LDS ----
__global__ __launch_bounds__(256) void k_embed_gemm(
    const int* __restrict__ feature, const float* __restrict__ poi,
    const float* __restrict__ cat, const float* __restrict__ lat,
    const float* __restrict__ lon, const f16* __restrict__ Bh,
    const f16* __restrict__ Bl, float* __restrict__ out) {
    __shared__ __align__(16) f16 Ah[2][64 * 64];
    __shared__ __align__(16) f16 Al[2][64 * 64];
    int t = threadIdx.x;
    int g0 = xcd_swz(blockIdx.x, gridDim.x) * 64;
    int lane = t & 63, w = t >> 6;
    int sr = t >> 2;            // staging row
    int skb = (t & 3) * 16;     // staging k base within chunk
    const int* f = feature + (size_t)(g0 + sr) * 5;
    int f0 = f[0], f1 = f[1], f3 = f[3], f4 = f[4];

    auto loadv = [&](int ch, float* v) {
        int gk = ch * 64 + skb;
        if (gk >= 800) {
#pragma unroll
            for (int m = 0; m < 16; ++m) v[m] = 0.f;
        } else if (gk == 288 || gk == 592) {
            // block crosses a concat-segment boundary (300 or 600): scalar ladder
#pragma unroll
            for (int m = 0; m < 16; ++m) {
                int k = gk + m;
                float val;
                if (k < 300)      val = poi[(size_t)f0 * 300 + k];
                else if (k < 400) val = cat[(size_t)f1 * 100 + (k - 300)];
                else if (k < 600) val = lat[(size_t)f3 * 200 + (k - 400)];
                else              val = lon[(size_t)f4 * 200 + (k - 600)];
                v[m] = val;
            }
        } else {
            const float* src;
            if (gk >= 600)      src = lon + (size_t)f4 * 200 + (gk - 600);
            else if (gk >= 400) src = lat + (size_t)f3 * 200 + (gk - 400);
            else if (gk >= 300) src = cat + (size_t)f1 * 100 + (gk - 300);
            else                src = poi + (size_t)f0 * 300 + gk;
            const float4* s4 = (const float4*)src;
#pragma unroll
            for (int q = 0; q < 4; ++q) {
                float4 x = s4[q];
                v[q * 4 + 0] = x.x; v[q * 4 + 1] = x.y; v[q * 4 + 2] = x.z; v[q * 4 + 3] = x.w;
            }
        }
    };
    auto writebuf = [&](int buf, const float* v) {
        f16x8 ph0, ph1, pl0, pl1;
#pragma unroll
        for (int j = 0; j < 8; ++j) {
            f16 h0 = (f16)v[j];     ph0[j] = h0; pl0[j] = (f16)(v[j] - (float)h0);
            f16 h1 = (f16)v[8 + j]; ph1[j] = h1; pl1[j] = (f16)(v[8 + j] - (float)h1);
        }
        int kg0 = skb >> 3;
        int a0i = sr * 64 + ((kg0 ^ (sr & 7)) << 3);
        int a1i = sr * 64 + (((kg0 + 1) ^ (sr & 7)) << 3);
        *(f16x8*)&Ah[buf][a0i] = ph0; *(f16x8*)&Ah[buf][a1i] = ph1;
        *(f16x8*)&Al[buf][a0i] = pl0; *(f16x8*)&Al[buf][a1i] = pl1;
    };

    f32x4 acc[4][2];
#pragma unroll
    for (int rt = 0; rt < 4; ++rt)
#pragma unroll
        for (int c = 0; c < 2; ++c) acc[rt][c] = (f32x4){0.f, 0.f, 0.f, 0.f};
    int ct0 = w * 2;

    {
        float vc[16];
        loadv(0, vc);
        writebuf(0, vc);
    }
    __syncthreads();
    int cur = 0;
    for (int ch = 0; ch < CHE; ++ch) {
        float vn[16];
        bool more = (ch + 1 < CHE);
        if (more) loadv(ch + 1, vn);      // issue next-chunk gathers early
        // ---- 2 k-steps of MFMA on buf[cur] ----
#pragma unroll
        for (int kh = 0; kh < 2; ++kh) {
            int ks = ch * 2 + kh;
            f16x8 ahf[4], alf[4];
#pragma unroll
            for (int rt = 0; rt < 4; ++rt) {
                int r = rt * 16 + (lane & 15);
                int kg = (lane >> 4) + kh * 4;
                int ad = r * 64 + ((kg ^ (r & 7)) << 3);
                ahf[rt] = *(const f16x8*)&Ah[cur][ad];
                alf[rt] = *(const f16x8*)&Al[cur][ad];
            }
#pragma unroll
            for (int cti = 0; cti < 2; ++cti) {
                int ct = ct0 + cti;
                f16x8 bh = *(const f16x8*)(Bh + ((size_t)(ks * 8 + ct) * 64 + lane) * 8);
                f16x8 bl = *(const f16x8*)(Bl + ((size_t)(ks * 8 + ct) * 64 + lane) * 8);
#pragma unroll
                for (int rt = 0; rt < 4; ++rt) {
                    acc[rt][cti] = __builtin_amdgcn_mfma_f32_16x16x32_f16(ahf[rt], bh, acc[rt][cti], 0, 0, 0);
                    acc[rt][cti] = __builtin_amdgcn_mfma_f32_16x16x32_f16(alf[rt], bh, acc[rt][cti], 0, 0, 0);
                    acc[rt][cti] = __builtin_amdgcn_mfma_f32_16x16x32_f16(ahf[rt], bl, acc[rt][cti], 0, 0, 0);
                }
            }
        }
        if (more) writebuf(cur ^ 1, vn);  // write other buffer; reads of it finished last iter
        __syncthreads();
        cur ^= 1;
    }
#pragma unroll
    for (int rt = 0; rt < 4; ++rt)
#pragma unroll
        for (int cti = 0; cti < 2; ++cti)
#pragma unroll
            for (int i = 0; i < 4; ++i) {
                int row = g0 + rt * 16 + (lane >> 4) * 4 + i;
                int col = (ct0 + cti) * 16 + (lane & 15);
                out[(size_t)row * CC + col] = acc[rt][cti][i];
            }
}

// ---- GAT gemm via MFMA split-f16; asrc/adst fused into staging ----
__global__ __launch_bounds__(256) void k_gat_gemm(
    const float* __restrict__ hin, const f16* __restrict__ Bh, const f16* __restrict__ Bl,
    const float* __restrict__ wsv, const float* __restrict__ wdv,
    float* __restrict__ Hp, float* __restrict__ asrc, float* __restrict__ adst) {
    __shared__ __align__(16) f16 Ah[64 * 128];
    __shared__ __align__(16) f16 Al[64 * 128];
    __shared__ float reds[256], redd[256];
    int t = threadIdx.x;
    int g0 = xcd_swz(blockIdx.x, gridDim.x) * 64;
    int lane = t & 63, w = t >> 6;
    int sr = t >> 2, skb = (t & 3) * 32;
    const float4* hrow = (const float4*)(hin + (size_t)(g0 + sr) * CC + skb);
    float v[32];
    float ps = 0.f, pd = 0.f;
#pragma unroll
    for (int q = 0; q < 8; ++q) {
        float4 x = hrow[q];
        v[q * 4 + 0] = x.x; v[q * 4 + 1] = x.y; v[q * 4 + 2] = x.z; v[q * 4 + 3] = x.w;
    }
#pragma unroll
    for (int m = 0; m < 32; ++m) {
        ps = fmaf(v[m], wsv[skb + m], ps);
        pd = fmaf(v[m], wdv[skb + m], pd);
    }
#pragma unroll
    for (int q = 0; q < 4; ++q) {
        f16x8 ph, pl;
#pragma unroll
        for (int j = 0; j < 8; ++j) {
            float x = v[q * 8 + j];
            f16 hi = (f16)x;
            ph[j] = hi; pl[j] = (f16)(x - (float)hi);
        }
        int kg = (skb >> 3) + q;
        int ad = sr * 128 + ((kg ^ (sr & 7)) << 3);
        *(f16x8*)&Ah[ad] = ph; *(f16x8*)&Al[ad] = pl;
    }
    reds[t] = ps; redd[t] = pd;
    __syncthreads();
    if (t < 64) {
        asrc[g0 + t] = reds[t * 4] + reds[t * 4 + 1] + reds[t * 4 + 2] + reds[t * 4 + 3];
        adst[g0 + t] = redd[t * 4] + redd[t * 4 + 1] + redd[t * 4 + 2] + redd[t * 4 + 3];
    }
    f32x4 acc[4][2];
#pragma unroll
    for (int rt = 0; rt < 4; ++rt)
#pragma unroll
        for (int c = 0; c < 2; ++c) acc[rt][c] = (f32x4){0.f, 0.f, 0.f, 0.f};
    int ct0 = w * 2;
#pragma unroll
    for (int ks = 0; ks < 4; ++ks) {
        f16x8 ahf[4], alf[4];
#pragma unroll
        for (int rt = 0; rt < 4; ++rt) {
            int r = rt * 16 + (lane & 15);
            int kg = (lane >> 4) + ks * 4;
            int ad = r * 128 + ((kg ^ (r & 7)) << 3);
            ahf[rt] = *(const f16x8*)&Ah[ad];
            alf[rt] = *(const f16x8*)&Al[ad];
        }
#pragma unroll
        for (int cti = 0; cti < 2; ++cti) {
            int ct = ct0 + cti;
            f16x8 bh = *(const f16x8*)(Bh + ((size_t)(ks * 8 + ct) * 64 + lane) * 8);
            f16x8 bl = *(const f16x8*)(Bl + ((size_t)(ks * 8 + ct) * 64 + lane) * 8);
#pragma unroll
            for (int rt = 0; rt < 4; ++rt) {
                acc[rt][cti] = __builtin_amdgcn_mfma_f32_16x16x32_f16(ahf[rt], bh, acc[rt][cti], 0, 0, 0);
                acc[rt][cti] = __builtin_amdgcn_mfma_f32_16x16x32_f16(alf[rt], bh, acc[rt][cti], 0, 0, 0);
                acc[rt][cti] = __builtin_amdgcn_mfma_f32_16x16x32_f16(ahf[rt], bl, acc[rt][cti], 0, 0, 0);
            }
        }
    }
#pragma unroll
    for (int rt = 0; rt < 4; ++rt)
#pragma unroll
        for (int cti = 0; cti < 2; ++cti)
#pragma unroll
            for (int i = 0; i < 4; ++i) {
                int row = g0 + rt * 16 + (lane >> 4) * 4 + i;
                int col = (ct0 + cti) * 16 + (lane & 15);
                Hp[(size_t)row * CC + col] = acc[rt][cti][i];
            }
}

// ---- unified aggregate kernel ----
// MODE 0: GAT, out = lrelu01(t)+t. MODE 1: GAT, out = lrelu01(t). MODE 2: GCN.
// Phase 1: per-edge (weight,row) into LDS (softmax normalization deferred to the
// final scale). Phase 2: float4 half-wave gather, 4 chains / 8 edges in flight.
template <int MODE>
__global__ __launch_bounds__(256) void k_agg(
    const float* __restrict__ Hp, const float* __restrict__ aux,
    const float* __restrict__ adst, const int* __restrict__ rowptr,
    const int* __restrict__ csr_row, const float* __restrict__ bias,
    float* __restrict__ out) {
    __shared__ float2 pr[4][DMAX];
    int wid = threadIdx.x >> 6, lane = threadIdx.x & 63;
    int g = xcd_swz(blockIdx.x, gridDim.x) * 4 + wid;
    int b = g / NN, v = g - b * NN;
    int bN = b * NN, bE = b * ET;
    int s0 = rowptr[b * RP + v], s1 = rowptr[b * RP + v + 1];
    int deg = s1 - s0;
    int half = lane >> 5, fl = lane & 31;

    if (deg <= DMAX) {
        float inv = 1.f;
        // ---- phase 1: per-edge (weight, row) into LDS ----
        if (MODE == 2) {
            float dv = aux[g];
            for (int jj = lane; jj < deg; jj += 64) {
                int r = csr_row[bE + s0 + jj];
                pr[wid][jj] = make_float2(aux[bN + r] * dv, __int_as_float(r));
            }
        } else {
            float adv = adst[g];
            float m = -3.0e38f;
            for (int jj = lane; jj < deg; jj += 64) {
                int r = csr_row[bE + s0 + jj];
                float e = lrelu2(aux[bN + r] + adv);
                pr[wid][jj] = make_float2(e, __int_as_float(r));
                m = fmaxf(m, e);
            }
            m = wmax(m);
            float ss = 0.f;
            for (int jj = lane; jj < deg; jj += 64) {
                float w = __expf(pr[wid][jj].x - m);
                ss += w;
                pr[wid][jj].x = w;
            }
            ss = wsum(ss);
            inv = 1.f / (ss + 1e-16f);   // applied once at the end
        }
        // DS pipe is in-order per wave: phase-2 reads see this wave's phase-1 writes.
        // ---- phase 2: float4 gather, 8 edges in flight (4 chains x half-wave) ----
        const float* Hb = Hp + (size_t)bN * CC;
        float4 a0 = {0.f, 0.f, 0.f, 0.f}, a1 = a0, a2 = a0, a3 = a0;
        int jj = 0;
        for (; jj + 7 < deg; jj += 8) {
            float2 p0 = pr[wid][jj + half];
            float2 p1 = pr[wid][jj + 2 + half];
            float2 p2 = pr[wid][jj + 4 + half];
            float2 p3 = pr[wid][jj + 6 + half];
            float4 h0 = ((const float4*)(Hb + (size_t)__float_as_int(p0.y) * CC))[fl];
            float4 h1 = ((const float4*)(Hb + (size_t)__float_as_int(p1.y) * CC))[fl];
            float4 h2 = ((const float4*)(Hb + (size_t)__float_as_int(p2.y) * CC))[fl];
            float4 h3 = ((const float4*)(Hb + (size_t)__float_as_int(p3.y) * CC))[fl];
            a0.x = fmaf(p0.x, h0.x, a0.x); a0.y = fmaf(p0.x, h0.y, a0.y);
            a0.z = fmaf(p0.x, h0.z, a0.z); a0.w = fmaf(p0.x, h0.w, a0.w);
            a1.x = fmaf(p1.x, h1.x, a1.x); a1.y = fmaf(p1.x, h1.y, a1.y);
            a1.z = fmaf(p1.x, h1.z, a1.z); a1.w = fmaf(p1.x, h1.w, a1.w);
            a2.x = fmaf(p2.x, h2.x, a2.x); a2.y = fmaf(p2.x, h2.y, a2.y);
            a2.z = fmaf(p2.x, h2.z, a2.z); a2.w = fmaf(p2.x, h2.w, a2.w);
            a3.x = fmaf(p3.x, h3.x, a3.x); a3.y = fmaf(p3.x, h3.y, a3.y);
            a3.z = fmaf(p3.x, h3.z, a3.z); a3.w = fmaf(p3.x, h3.w, a3.w);
        }
        for (; jj + 3 < deg; jj += 4) {
            float2 p0 = pr[wid][jj + half];
            float2 p1 = pr[wid][jj + 2 + half];
            float4 h0 = ((const float4*)(Hb + (size_t)__float_as_int(p0.y) * CC))[fl];
            float4 h1 = ((const float4*)(Hb + (size_t)__float_as_int(p1.y) * CC))[fl];
            a0.x = fmaf(p0.x, h0.x, a0.x); a0.y = fmaf(p0.x, h0.y, a0.y);
            a0.z = fmaf(p0.x, h0.z, a0.z); a0.w = fmaf(p0.x, h0.w, a0.w);
            a1.x = fmaf(p1.x, h1.x, a1.x); a1.y = fmaf(p1.x, h1.y, a1.y);
            a1.z = fmaf(p1.x, h1.z, a1.z); a1.w = fmaf(p1.x, h1.w, a1.w);
        }
        for (; jj + 1 < deg; jj += 2) {
            float2 p0 = pr[wid][jj + half];
            float4 h0 = ((const float4*)(Hb + (size_t)__float_as_int(p0.y) * CC))[fl];
            a0.x = fmaf(p0.x, h0.x, a0.x); a0.y = fmaf(p0.x, h0.y, a0.y);
            a0.z = fmaf(p0.x, h0.z, a0.z); a0.w = fmaf(p0.x, h0.w, a0.w);
        }
        if (jj < deg && half == 0) {
            float2 p0 = pr[wid][jj];
            float4 h0 = ((const float4*)(Hb + (size_t)__float_as_int(p0.y) * CC))[fl];
            a0.x = fmaf(p0.x, h0.x, a0.x); a0.y = fmaf(p0.x, h0.y, a0.y);
            a0.z = fmaf(p0.x, h0.z, a0.z); a0.w = fmaf(p0.x, h0.w, a0.w);
        }
        a0.x += a1.x + a2.x + a3.x; a0.y += a1.y + a2.y + a3.y;
        a0.z += a1.z + a2.z + a3.z; a0.w += a1.w + a2.w + a3.w;
        a0.x += __shfl_xor(a0.x, 32); a0.y += __shfl_xor(a0.y, 32);
        a0.z += __shfl_xor(a0.z, 32); a0.w += __shfl_xor(a0.w, 32);
        if (half == 0) {
            float4 bb = ((const float4*)bias)[fl];
            float sc = (MODE == 2) ? 1.f : inv;
            float t0 = a0.x * sc + bb.x, t1 = a0.y * sc + bb.y;
            float t2 = a0.z * sc + bb.z, t3 = a0.w * sc + bb.w;
            float4 o;
            if (MODE == 0) {
                o.x = lrelu01(t0) + t0; o.y = lrelu01(t1) + t1;
                o.z = lrelu01(t2) + t2; o.w = lrelu01(t3) + t3;
            } else {
                o.x = lrelu01(t0); o.y = lrelu01(t1);
                o.z = lrelu01(t2); o.w = lrelu01(t3);
            }
            ((float4*)(out + (size_t)g * CC))[fl] = o;
        }
        return;
    }
    // ---- fallback deg > DMAX (float2 full-wave path; practically never taken) ----
    if (MODE == 2) {
        float dv = aux[g];
        float x0 = 0.f, x1 = 0.f;
        for (int j = s0; j < s1; ++j) {
            int r = csr_row[bE + j];
            float d0 = aux[bN + r];
            float2 h = ((const float2*)(Hp + (size_t)(bN + r) * CC))[lane];
            x0 = fmaf(d0, h.x, x0); x1 = fmaf(d0, h.y, x1);
        }
        float2 bb = ((const float2*)bias)[lane];
        float2 o;
        o.x = lrelu01(x0 * dv + bb.x);
        o.y = lrelu01(x1 * dv + bb.y);
        ((float2*)(out + (size_t)g * CC))[lane] = o;
    } else {
        float adv = adst[g];
        float m = -3.0e38f;
        for (int j = s0 + lane; j < s1; j += 64)
            m = fmaxf(m, lrelu2(aux[bN + csr_row[bE + j]] + adv));
        m = wmax(m);
        float ssum = 0.f;
        for (int j = s0 + lane; j < s1; j += 64)
            ssum += __expf(lrelu2(aux[bN + csr_row[bE + j]] + adv) - m);
        ssum = wsum(ssum);
        float inv = 1.f / (ssum + 1e-16f);
        float x0 = 0.f, x1 = 0.f;
        for (int j = s0; j < s1; ++j) {
            int r = csr_row[bE + j];
            float wj = __expf(lrelu2(aux[bN + r] + adv) - m) * inv;
            float2 h = ((const float2*)(Hp + (size_t)(bN + r) * CC))[lane];
            x0 = fmaf(wj, h.x, x0); x1 = fmaf(wj, h.y, x1);
        }
        float2 bb = ((const float2*)bias)[lane];
        float t0 = x0 + bb.x, t1 = x1 + bb.y;
        float2 o;
        if (MODE == 0) { o.x = lrelu01(t0) + t0; o.y = lrelu01(t1) + t1; }
        else           { o.x = lrelu01(t0);      o.y = lrelu01(t1); }
        ((float2*)(out + (size_t)g * CC))[lane] = o;
    }
}

// ---- GCN2 per-node dot ----
__global__ __launch_bounds__(256) void k_out_dot(
    const float* __restrict__ h, const float* __restrict__ Wout,
    float* __restrict__ p) {
    int wid = threadIdx.x >> 6, lane = threadIdx.x & 63;
    int g = blockIdx.x * 4 + wid;
    float2 h2 = ((const float2*)(h + (size_t)g * CC))[lane];
    float2 w2 = ((const float2*)Wout)[lane];
    float x = wsum(h2.x * w2.x + h2.y * w2.y);
    if (lane == 0) p[g] = x;
}

__global__ __launch_bounds__(256) void k_out_agg(
    const float* __restrict__ p, const float* __restrict__ dinv,
    const int* __restrict__ rowptr, const int* __restrict__ csr_row,
    const float* __restrict__ bout, float* __restrict__ gv) {
    int wid = threadIdx.x >> 6, lane = threadIdx.x & 63;
    int g = xcd_swz(blockIdx.x, gridDim.x) * 4 + wid;
    int b = g / NN, v = g - b * NN;
    int s0 = rowptr[b * RP + v], s1 = rowptr[b * RP + v + 1];
    float acc = 0.f;
    for (int j = s0 + lane; j < s1; j += 64) {
        int r = csr_row[b * ET + j];
        acc += dinv[b * NN + r] * p[b * NN + r];
    }
    acc = wsum(acc);
    if (lane == 0) gv[g] = lrelu01(acc * dinv[g] + bout[0]);
}

__global__ __launch_bounds__(128) void k_fc(
    const float* __restrict__ gv, const float* __restrict__ W1,
    const float* __restrict__ b1, const float* __restrict__ W2,
    const float* __restrict__ b2, float* __restrict__ outp) {
    __shared__ float gs[NN];
    __shared__ float s1[CC];
    int b = blockIdx.x, tx = threadIdx.x;
    for (int v = tx; v < NN; v += 128) gs[v] = gv[b * NN + v];
    __syncthreads();
    float acc = 0.f;
    for (int v = 0; v < NN; ++v) acc = fmaf(gs[v], W1[v * CC + tx], acc);
    float t = lrelu01(acc + b1[tx]);
    s1[tx] = t;
    __syncthreads();
    float acc2 = 0.f;
#pragma unroll
    for (int k = 0; k < CC; ++k) acc2 = fmaf(s1[k], W2[k * CC + tx], acc2);
    outp[b * CC + tx] = acc2 + b2[tx];
}

extern "C" void kernel_launch(void* const* d_in, const int* in_sizes, int n_in,
                              void* d_out, int out_size, void* d_ws, size_t ws_size,
                              hipStream_t stream) {
    const int*   feature  = (const int*)d_in[0];
    const int*   edges    = (const int*)d_in[1];
    const float* poi      = (const float*)d_in[3];
    const float* cat      = (const float*)d_in[4];
    const float* lat      = (const float*)d_in[5];
    const float* lon      = (const float*)d_in[6];
    const float* W_in     = (const float*)d_in[7];
    const float* b_in     = (const float*)d_in[8];
    const float* gat_W    = (const float*)d_in[9];
    const float* gat_asrc = (const float*)d_in[10];
    const float* gat_adst = (const float*)d_in[11];
    const float* gat_b    = (const float*)d_in[12];
    const float* W_out    = (const float*)d_in[13];
    const float* b_out    = (const float*)d_in[14];
    const float* W_fc1    = (const float*)d_in[15];
    const float* b_fc1    = (const float*)d_in[16];
    const float* W_fc2    = (const float*)d_in[17];
    const float* b_fc2    = (const float*)d_in[18];
    float* outp = (float*)d_out;

    char* ws = (char*)d_ws;
    size_t off = 0;
    auto take = [&](size_t bytes) -> char* {
        char* pp = ws + off;
        off = (off + bytes + 255) & ~(size_t)255;
        return pp;
    };
    int*   row32  = (int*)take((size_t)BB * ET * 4);
    int*   col32  = (int*)take((size_t)BB * ET * 4);
    int*   csr    = (int*)take((size_t)BB * ET * 4);
    int*   rowptr = (int*)take((size_t)BB * RP * 4);
    int*   cursor = (int*)take((size_t)BB * RP * 4);
    float* dinv   = (float*)take((size_t)NBt * 4);
    float* asrc   = (float*)take((size_t)NBt * 4);
    float* adst   = (float*)take((size_t)NBt * 4);
    float* pscal  = (float*)take((size_t)NBt * 4);
    float* gvec   = (float*)take((size_t)NBt * 4);
    float* bufA   = (float*)take((size_t)NBt * CC * 4);
    float* bufB   = (float*)take((size_t)NBt * CC * 4);
    f16*   BWh    = (f16*)take((size_t)KSE * 8 * 64 * 8 * 2);
    f16*   BWl    = (f16*)take((size_t)KSE * 8 * 64 * 8 * 2);
    f16*   BGh    = (f16*)take((size_t)3 * 4 * 8 * 64 * 8 * 2);
    f16*   BGl    = (f16*)take((size_t)3 * 4 * 8 * 64 * 8 * 2);
    float* wsv    = (float*)take((size_t)3 * CC * 4);
    float* wdv    = (float*)take((size_t)3 * CC * 4);

    const int nE = BB * ET;
    hipMemsetAsync(dinv, 0, (size_t)NBt * 4, stream);
    k_edge_prep<<<(nE + 255) / 256, 256, 0, stream>>>(edges, row32, col32, dinv);
    k_scan<<<BB, 1024, 0, stream>>>(dinv, rowptr, cursor);
    k_scatter<<<(nE + 255) / 256, 256, 0, stream>>>(row32, col32, cursor, csr);

    k_pack_Win<<<(KSE * 8 * 64 + 255) / 256, 256, 0, stream>>>(W_in, BWh, BWl);
    k_pack_Wgat<<<(3 * 4 * 8 * 64 + 255) / 256, 256, 0, stream>>>(gat_W, BGh, BGl);
    k_wsd<<<3, 128, 0, stream>>>(gat_W, gat_asrc, gat_adst, wsv, wdv);

    k_embed_gemm<<<NBt / 64, 256, 0, stream>>>(feature, poi, cat, lat, lon, BWh, BWl, bufB);
    k_agg<2><<<NBt / 4, 256, 0, stream>>>(bufB, dinv, nullptr, rowptr, csr, b_in, bufA);

    for (int i = 0; i < 3; ++i) {
        const f16* bh = BGh + (size_t)i * 4 * 8 * 64 * 8;
        const f16* bl = BGl + (size_t)i * 4 * 8 * 64 * 8;
        const float* ws_i = wsv + (size_t)i * CC;
        const float* wd_i = wdv + (size_t)i * CC;
        const float* gb = gat_b + (size_t)i * CC;
        k_gat_gemm<<<NBt / 64, 256, 0, stream>>>(bufA, bh, bl, ws_i, wd_i, bufB, asrc, adst);
        k_agg<0><<<NBt / 4, 256, 0, stream>>>(bufB, asrc, adst, rowptr, csr, gb, bufA);
        k_gat_gemm<<<NBt / 64, 256, 0, stream>>>(bufA, bh, bl, ws_i, wd_i, bufB, asrc, adst);
        k_agg<1><<<NBt / 4, 256, 0, stream>>>(bufB, asrc, adst, rowptr, csr, gb, bufA);
    }

    k_out_dot<<<NBt / 4, 256, 0, stream>>>(bufA, W_out, pscal);
    k_out_agg<<<NBt / 4, 256, 0, stream>>>(pscal, dinv, rowptr, csr, b_out, gvec);
    k_fc<<<BB, 128, 0, stream>>>(gvec, W_fc1, b_fc1, W_fc2, b_fc2, outp);
}

// Round 7
// 442.082 us; speedup vs baseline: 2.9626x; 1.0905x over previous
//
#include <hip/hip_runtime.h>

// UserGraphNet: B=64 graphs, n=714 nodes, E=16384 edges (+n self loops), C=128.
// Round 6: 32-row GEMM tiles (1428 blocks, 2x occupancy — was grid-limited at 714);
// node-feature matrix for aggregation (bufB/Hp) stored as f16 (halves agg gather
// bytes; fp32 accumulate). Split-f16 MFMA GEMMs; CSR aggs; XCD swizzle throughout.

#define BB 64
#define NN 714
#define EE 16384
#define ET (EE + NN)          // 17098 edges incl self loops
#define NBt (BB * NN)         // 45696 total nodes
#define CC 128
#define RP (NN + 1)           // rowptr entries per graph
#define KSE 26                // embed k-steps (K=800 padded to 832)
#define CHE 13                // embed 64-wide k-chunks
#define DMAX 128              // max degree on the fast agg path (deg~24)

typedef _Float16 f16;
typedef __attribute__((ext_vector_type(8))) _Float16 f16x8;
typedef __attribute__((ext_vector_type(4))) _Float16 f16x4;
typedef __attribute__((ext_vector_type(4))) float f32x4;

__device__ __forceinline__ float lrelu01(float x) { return x > 0.f ? x : 0.01f * x; }
__device__ __forceinline__ float lrelu2(float x)  { return x > 0.f ? x : 0.2f  * x; }

__device__ __forceinline__ float wsum(float x) {
#pragma unroll
    for (int o = 32; o > 0; o >>= 1) x += __shfl_xor(x, o);
    return x;
}
__device__ __forceinline__ float wmax(float x) {
#pragma unroll
    for (int o = 32; o > 0; o >>= 1) x = fmaxf(x, __shfl_xor(x, o));
    return x;
}

// Bijective XCD swizzle (m204)
__device__ __forceinline__ int xcd_swz(int bid, int nwg) {
    int q = nwg >> 3, r = nwg & 7;
    int x = bid & 7, l = bid >> 3;
    int base = (x < r) ? x * (q + 1) : r * (q + 1) + (x - r) * q;
    return base + l;
}

// ---- edge prep ----
__global__ void k_edge_prep(const int* __restrict__ edges, int* __restrict__ row32,
                            int* __restrict__ col32, float* __restrict__ deg) {
    int idx = blockIdx.x * blockDim.x + threadIdx.x;
    if (idx >= BB * ET) return;
    int b = idx / ET, e = idx - b * ET;
    int r, c;
    if (e < EE) { r = edges[b * 2 * EE + e]; c = edges[b * 2 * EE + EE + e]; }
    else        { r = c = e - EE; }
    row32[idx] = r; col32[idx] = c;
    atomicAdd(&deg[b * NN + c], 1.0f);
}

__global__ void k_scan(float* degdinv, int* __restrict__ rowptr, int* __restrict__ cursor) {
    __shared__ int s[1024];
    int b = blockIdx.x, v = threadIdx.x;
    int cnt = 0; float d = 0.f;
    if (v < NN) { d = degdinv[b * NN + v]; cnt = (int)d; }
    s[v] = cnt;
    __syncthreads();
    for (int off = 1; off < 1024; off <<= 1) {
        int val = (v >= off) ? s[v - off] : 0;
        __syncthreads();
        s[v] += val;
        __syncthreads();
    }
    if (v < NN) {
        degdinv[b * NN + v] = d > 0.f ? rsqrtf(d) : 0.f;
        rowptr[b * RP + v + 1] = s[v];
        cursor[b * RP + v] = (v == 0) ? 0 : s[v - 1];
    }
    if (v == 0) rowptr[b * RP] = 0;
}

__global__ void k_scatter(const int* __restrict__ row32, const int* __restrict__ col32,
                          int* __restrict__ cursor, int* __restrict__ csr_row) {
    int idx = blockIdx.x * blockDim.x + threadIdx.x;
    if (idx >= BB * ET) return;
    int b = idx / ET;
    int c = col32[idx];
    int slot = atomicAdd(&cursor[b * RP + c], 1);
    csr_row[b * ET + slot] = row32[idx];
}

// ---- pack W_in into frag layout hi/lo ----
__global__ void k_pack_Win(const float* __restrict__ W, f16* __restrict__ Bh, f16* __restrict__ Bl) {
    int idx = blockIdx.x * 256 + threadIdx.x;     // (ks*8+ct)*64 + lane
    if (idx >= KSE * 8 * 64) return;
    int lane = idx & 63, tc = idx >> 6;
    int ct = tc & 7, ks = tc >> 3;
    f16x8 ph, pl;
#pragma unroll
    for (int j = 0; j < 8; ++j) {
        int k = ks * 32 + (lane >> 4) * 8 + j;
        int c = ct * 16 + (lane & 15);
        float v = (k < 800) ? W[k * CC + c] : 0.f;
        f16 hi = (f16)v;
        ph[j] = hi; pl[j] = (f16)(v - (float)hi);
    }
    *(f16x8*)(Bh + (size_t)idx * 8) = ph;
    *(f16x8*)(Bl + (size_t)idx * 8) = pl;
}

// ---- pack gat_W into frag layout hi/lo ----
__global__ void k_pack_Wgat(const float* __restrict__ W, f16* __restrict__ Bh, f16* __restrict__ Bl) {
    int idx = blockIdx.x * 256 + threadIdx.x;     // ((i*4+ks)*8+ct)*64 + lane
    if (idx >= 3 * 4 * 8 * 64) return;
    int lane = idx & 63, tc = idx >> 6;
    int ct = tc & 7; tc >>= 3;
    int ks = tc & 3, li = tc >> 2;
    const float* Wl = W + (size_t)li * CC * CC;
    f16x8 ph, pl;
#pragma unroll
    for (int j = 0; j < 8; ++j) {
        int k = ks * 32 + (lane >> 4) * 8 + j;
        int c = ct * 16 + (lane & 15);
        float v = Wl[k * CC + c];
        f16 hi = (f16)v;
        ph[j] = hi; pl[j] = (f16)(v - (float)hi);
    }
    *(f16x8*)(Bh + (size_t)idx * 8) = ph;
    *(f16x8*)(Bl + (size_t)idx * 8) = pl;
}

// ---- w_s = W.a_src, w_d = W.a_dst per layer ----
__global__ void k_wsd(const float* __restrict__ gat_W, const float* __restrict__ a_s,
                      const float* __restrict__ a_d, float* __restrict__ wsv, float* __restrict__ wdv) {
    int i = blockIdx.x, k = threadIdx.x;
    const float* W = gat_W + (size_t)i * CC * CC;
    float s = 0.f, d = 0.f;
#pragma unroll 4
    for (int c = 0; c < CC; ++c) {
        float w = W[k * CC + c];
        s = fmaf(w, a_s[i * CC + c], s);
        d = fmaf(w, a_d[i * CC + c], d);
    }
    wsv[i * CC + k] = s; wdv[i * CC + k] = d;
}

// ---- fused embedding-gather + X@W_in, 32-row tile, double-buffered, f16 out ----
__global__ __launch_bounds__(256) void k_embed_gemm(
    const int* __restrict__ feature, const float* __restrict__ poi,
    const float* __restrict__ cat, const float* __restrict__ lat,
    const float* __restrict__ lon, const f16* __restrict__ Bh,
    const f16* __restrict__ Bl, f16* __restrict__ out) {
    __shared__ __align__(16) f16 Ah[2][32 * 64];
    __shared__ __align__(16) f16 Al[2][32 * 64];
    int t = threadIdx.x;
    int g0 = xcd_swz(blockIdx.x, gridDim.x) * 32;
    int lane = t & 63, w = t >> 6;
    int sr = t >> 3;            // staging row (0..31)
    int skb = (t & 7) * 8;      // staging k base within 64-wide chunk
    const int* f = feature + (size_t)(g0 + sr) * 5;
    int f0 = f[0], f1 = f[1], f3 = f[3], f4 = f[4];

    auto loadv = [&](int ch, float* v) {
        int gk = ch * 64 + skb;
        if (gk >= 800) {
#pragma unroll
            for (int m = 0; m < 8; ++m) v[m] = 0.f;
        } else if (gk == 296) {
            // 8-block crossing the poi/cat boundary at 300 (others are 8-aligned)
#pragma unroll
            for (int m = 0; m < 8; ++m) {
                int k = gk + m;
                v[m] = (k < 300) ? poi[(size_t)f0 * 300 + k] : cat[(size_t)f1 * 100 + (k - 300)];
            }
        } else {
            const float* src;
            if (gk >= 600)      src = lon + (size_t)f4 * 200 + (gk - 600);
            else if (gk >= 400) src = lat + (size_t)f3 * 200 + (gk - 400);
            else if (gk >= 300) src = cat + (size_t)f1 * 100 + (gk - 300);
            else                src = poi + (size_t)f0 * 300 + gk;
            const float4* s4 = (const float4*)src;
#pragma unroll
            for (int q = 0; q < 2; ++q) {
                float4 x = s4[q];
                v[q * 4 + 0] = x.x; v[q * 4 + 1] = x.y; v[q * 4 + 2] = x.z; v[q * 4 + 3] = x.w;
            }
        }
    };
    auto writebuf = [&](int buf, const float* v) {
        f16x8 ph, pl;
#pragma unroll
        for (int j = 0; j < 8; ++j) {
            f16 hi = (f16)v[j];
            ph[j] = hi; pl[j] = (f16)(v[j] - (float)hi);
        }
        int kg0 = t & 7;
        int ai = sr * 64 + ((kg0 ^ (sr & 7)) << 3);
        *(f16x8*)&Ah[buf][ai] = ph;
        *(f16x8*)&Al[buf][ai] = pl;
    };

    f32x4 acc[2][2];
#pragma unroll
    for (int rt = 0; rt < 2; ++rt)
#pragma unroll
        for (int c = 0; c < 2; ++c) acc[rt][c] = (f32x4){0.f, 0.f, 0.f, 0.f};
    int ct0 = w * 2;

    {
        float vc[8];
        loadv(0, vc);
        writebuf(0, vc);
    }
    __syncthreads();
    int cur = 0;
    for (int ch = 0; ch < CHE; ++ch) {
        float vn[8];
        bool more = (ch + 1 < CHE);
        if (more) loadv(ch + 1, vn);      // issue next-chunk gathers early
#pragma unroll
        for (int kh = 0; kh < 2; ++kh) {
            int ks = ch * 2 + kh;
            f16x8 ahf[2], alf[2];
#pragma unroll
            for (int rt = 0; rt < 2; ++rt) {
                int r = rt * 16 + (lane & 15);
                int kg = (lane >> 4) + kh * 4;
                int ad = r * 64 + ((kg ^ (r & 7)) << 3);
                ahf[rt] = *(const f16x8*)&Ah[cur][ad];
                alf[rt] = *(const f16x8*)&Al[cur][ad];
            }
#pragma unroll
            for (int cti = 0; cti < 2; ++cti) {
                int ct = ct0 + cti;
                f16x8 bh = *(const f16x8*)(Bh + ((size_t)(ks * 8 + ct) * 64 + lane) * 8);
                f16x8 bl = *(const f16x8*)(Bl + ((size_t)(ks * 8 + ct) * 64 + lane) * 8);
#pragma unroll
                for (int rt = 0; rt < 2; ++rt) {
                    acc[rt][cti] = __builtin_amdgcn_mfma_f32_16x16x32_f16(ahf[rt], bh, acc[rt][cti], 0, 0, 0);
                    acc[rt][cti] = __builtin_amdgcn_mfma_f32_16x16x32_f16(alf[rt], bh, acc[rt][cti], 0, 0, 0);
                    acc[rt][cti] = __builtin_amdgcn_mfma_f32_16x16x32_f16(ahf[rt], bl, acc[rt][cti], 0, 0, 0);
                }
            }
        }
        if (more) writebuf(cur ^ 1, vn);
        __syncthreads();
        cur ^= 1;
    }
#pragma unroll
    for (int rt = 0; rt < 2; ++rt)
#pragma unroll
        for (int cti = 0; cti < 2; ++cti)
#pragma unroll
            for (int i = 0; i < 4; ++i) {
                int row = g0 + rt * 16 + (lane >> 4) * 4 + i;
                int col = (ct0 + cti) * 16 + (lane & 15);
                out[(size_t)row * CC + col] = (f16)acc[rt][cti][i];
            }
}

// ---- GAT gemm, 32-row tile; asrc/adst fused; f16 Hp out ----
__global__ __launch_bounds__(256) void k_gat_gemm(
    const float* __restrict__ hin, const f16* __restrict__ Bh, const f16* __restrict__ Bl,
    const float* __restrict__ wsv, const float* __restrict__ wdv,
    f16* __restrict__ Hp, float* __restrict__ asrc, float* __restrict__ adst) {
    __shared__ __align__(16) f16 Ah[32 * 128];
    __shared__ __align__(16) f16 Al[32 * 128];
    __shared__ float reds[256], redd[256];
    int t = threadIdx.x;
    int g0 = xcd_swz(blockIdx.x, gridDim.x) * 32;
    int lane = t & 63, w = t >> 6;
    int sr = t >> 3, skb = (t & 7) * 16;
    const float4* hrow = (const float4*)(hin + (size_t)(g0 + sr) * CC + skb);
    float v[16];
    float ps = 0.f, pd = 0.f;
#pragma unroll
    for (int q = 0; q < 4; ++q) {
        float4 x = hrow[q];
        v[q * 4 + 0] = x.x; v[q * 4 + 1] = x.y; v[q * 4 + 2] = x.z; v[q * 4 + 3] = x.w;
    }
#pragma unroll
    for (int m = 0; m < 16; ++m) {
        ps = fmaf(v[m], wsv[skb + m], ps);
        pd = fmaf(v[m], wdv[skb + m], pd);
    }
#pragma unroll
    for (int q = 0; q < 2; ++q) {
        f16x8 ph, pl;
#pragma unroll
        for (int j = 0; j < 8; ++j) {
            float x = v[q * 8 + j];
            f16 hi = (f16)x;
            ph[j] = hi; pl[j] = (f16)(x - (float)hi);
        }
        int kg = (skb >> 3) + q;
        int ad = sr * 128 + ((kg ^ (sr & 7)) << 3);
        *(f16x8*)&Ah[ad] = ph; *(f16x8*)&Al[ad] = pl;
    }
    reds[t] = ps; redd[t] = pd;
    __syncthreads();
    if (t < 32) {
        float s = 0.f, d = 0.f;
#pragma unroll
        for (int q = 0; q < 8; ++q) { s += reds[t * 8 + q]; d += redd[t * 8 + q]; }
        asrc[g0 + t] = s; adst[g0 + t] = d;
    }
    f32x4 acc[2][2];
#pragma unroll
    for (int rt = 0; rt < 2; ++rt)
#pragma unroll
        for (int c = 0; c < 2; ++c) acc[rt][c] = (f32x4){0.f, 0.f, 0.f, 0.f};
    int ct0 = w * 2;
#pragma unroll
    for (int ks = 0; ks < 4; ++ks) {
        f16x8 ahf[2], alf[2];
#pragma unroll
        for (int rt = 0; rt < 2; ++rt) {
            int r = rt * 16 + (lane & 15);
            int kg = (lane >> 4) + ks * 4;
            int ad = r * 128 + ((kg ^ (r & 7)) << 3);
            ahf[rt] = *(const f16x8*)&Ah[ad];
            alf[rt] = *(const f16x8*)&Al[ad];
        }
#pragma unroll
        for (int cti = 0; cti < 2; ++cti) {
            int ct = ct0 + cti;
            f16x8 bh = *(const f16x8*)(Bh + ((size_t)(ks * 8 + ct) * 64 + lane) * 8);
            f16x8 bl = *(const f16x8*)(Bl + ((size_t)(ks * 8 + ct) * 64 + lane) * 8);
#pragma unroll
            for (int rt = 0; rt < 2; ++rt) {
                acc[rt][cti] = __builtin_amdgcn_mfma_f32_16x16x32_f16(ahf[rt], bh, acc[rt][cti], 0, 0, 0);
                acc[rt][cti] = __builtin_amdgcn_mfma_f32_16x16x32_f16(alf[rt], bh, acc[rt][cti], 0, 0, 0);
                acc[rt][cti] = __builtin_amdgcn_mfma_f32_16x16x32_f16(ahf[rt], bl, acc[rt][cti], 0, 0, 0);
            }
        }
    }
#pragma unroll
    for (int rt = 0; rt < 2; ++rt)
#pragma unroll
        for (int cti = 0; cti < 2; ++cti)
#pragma unroll
            for (int i = 0; i < 4; ++i) {
                int row = g0 + rt * 16 + (lane >> 4) * 4 + i;
                int col = (ct0 + cti) * 16 + (lane & 15);
                Hp[(size_t)row * CC + col] = (f16)acc[rt][cti][i];
            }
}

// ---- unified aggregate kernel (H input is f16) ----
// MODE 0: GAT, out = lrelu01(t)+t. MODE 1: GAT, out = lrelu01(t). MODE 2: GCN.
template <int MODE>
__global__ __launch_bounds__(256) void k_agg(
    const f16* __restrict__ Hp, const float* __restrict__ aux,
    const float* __restrict__ adst, const int* __restrict__ rowptr,
    const int* __restrict__ csr_row, const float* __restrict__ bias,
    float* __restrict__ out) {
    __shared__ float2 pr[4][DMAX];
    int wid = threadIdx.x >> 6, lane = threadIdx.x & 63;
    int g = xcd_swz(blockIdx.x, gridDim.x) * 4 + wid;
    int b = g / NN, v = g - b * NN;
    int bN = b * NN, bE = b * ET;
    int s0 = rowptr[b * RP + v], s1 = rowptr[b * RP + v + 1];
    int deg = s1 - s0;
    int half = lane >> 5, fl = lane & 31;

    if (deg <= DMAX) {
        float inv = 1.f;
        // ---- phase 1: per-edge (weight, row) into LDS ----
        if (MODE == 2) {
            float dv = aux[g];
            for (int jj = lane; jj < deg; jj += 64) {
                int r = csr_row[bE + s0 + jj];
                pr[wid][jj] = make_float2(aux[bN + r] * dv, __int_as_float(r));
            }
        } else {
            float adv = adst[g];
            float m = -3.0e38f;
            for (int jj = lane; jj < deg; jj += 64) {
                int r = csr_row[bE + s0 + jj];
                float e = lrelu2(aux[bN + r] + adv);
                pr[wid][jj] = make_float2(e, __int_as_float(r));
                m = fmaxf(m, e);
            }
            m = wmax(m);
            float ss = 0.f;
            for (int jj = lane; jj < deg; jj += 64) {
                float w = __expf(pr[wid][jj].x - m);
                ss += w;
                pr[wid][jj].x = w;
            }
            ss = wsum(ss);
            inv = 1.f / (ss + 1e-16f);   // applied once at the end
        }
        // ---- phase 2: f16x4 gather (8B/lane), 8 edges in flight ----
        const f16* Hb = Hp + (size_t)bN * CC;
        float4 a0 = {0.f, 0.f, 0.f, 0.f}, a1 = a0, a2 = a0, a3 = a0;
        int jj = 0;
        for (; jj + 7 < deg; jj += 8) {
            float2 p0 = pr[wid][jj + half];
            float2 p1 = pr[wid][jj + 2 + half];
            float2 p2 = pr[wid][jj + 4 + half];
            float2 p3 = pr[wid][jj + 6 + half];
            f16x4 h0 = *(const f16x4*)(Hb + (size_t)__float_as_int(p0.y) * CC + fl * 4);
            f16x4 h1 = *(const f16x4*)(Hb + (size_t)__float_as_int(p1.y) * CC + fl * 4);
            f16x4 h2 = *(const f16x4*)(Hb + (size_t)__float_as_int(p2.y) * CC + fl * 4);
            f16x4 h3 = *(const f16x4*)(Hb + (size_t)__float_as_int(p3.y) * CC + fl * 4);
            a0.x = fmaf(p0.x, (float)h0[0], a0.x); a0.y = fmaf(p0.x, (float)h0[1], a0.y);
            a0.z = fmaf(p0.x, (float)h0[2], a0.z); a0.w = fmaf(p0.x, (float)h0[3], a0.w);
            a1.x = fmaf(p1.x, (float)h1[0], a1.x); a1.y = fmaf(p1.x, (float)h1[1], a1.y);
            a1.z = fmaf(p1.x, (float)h1[2], a1.z); a1.w = fmaf(p1.x, (float)h1[3], a1.w);
            a2.x = fmaf(p2.x, (float)h2[0], a2.x); a2.y = fmaf(p2.x, (float)h2[1], a2.y);
            a2.z = fmaf(p2.x, (float)h2[2], a2.z); a2.w = fmaf(p2.x, (float)h2[3], a2.w);
            a3.x = fmaf(p3.x, (float)h3[0], a3.x); a3.y = fmaf(p3.x, (float)h3[1], a3.y);
            a3.z = fmaf(p3.x, (float)h3[2], a3.z); a3.w = fmaf(p3.x, (float)h3[3], a3.w);
        }
        for (; jj + 3 < deg; jj += 4) {
            float2 p0 = pr[wid][jj + half];
            float2 p1 = pr[wid][jj + 2 + half];
            f16x4 h0 = *(const f16x4*)(Hb + (size_t)__float_as_int(p0.y) * CC + fl * 4);
            f16x4 h1 = *(const f16x4*)(Hb + (size_t)__float_as_int(p1.y) * CC + fl * 4);
            a0.x = fmaf(p0.x, (float)h0[0], a0.x); a0.y = fmaf(p0.x, (float)h0[1], a0.y);
            a0.z = fmaf(p0.x, (float)h0[2], a0.z); a0.w = fmaf(p0.x, (float)h0[3], a0.w);
            a1.x = fmaf(p1.x, (float)h1[0], a1.x); a1.y = fmaf(p1.x, (float)h1[1], a1.y);
            a1.z = fmaf(p1.x, (float)h1[2], a1.z); a1.w = fmaf(p1.x, (float)h1[3], a1.w);
        }
        for (; jj + 1 < deg; jj += 2) {
            float2 p0 = pr[wid][jj + half];
            f16x4 h0 = *(const f16x4*)(Hb + (size_t)__float_as_int(p0.y) * CC + fl * 4);
            a0.x = fmaf(p0.x, (float)h0[0], a0.x); a0.y = fmaf(p0.x, (float)h0[1], a0.y);
            a0.z = fmaf(p0.x, (float)h0[2], a0.z); a0.w = fmaf(p0.x, (float)h0[3], a0.w);
        }
        if (jj < deg && half == 0) {
            float2 p0 = pr[wid][jj];
            f16x4 h0 = *(const f16x4*)(Hb + (size_t)__float_as_int(p0.y) * CC + fl * 4);
            a0.x = fmaf(p0.x, (float)h0[0], a0.x); a0.y = fmaf(p0.x, (float)h0[1], a0.y);
            a0.z = fmaf(p0.x, (float)h0[2], a0.z); a0.w = fmaf(p0.x, (float)h0[3], a0.w);
        }
        a0.x += a1.x + a2.x + a3.x; a0.y += a1.y + a2.y + a3.y;
        a0.z += a1.z + a2.z + a3.z; a0.w += a1.w + a2.w + a3.w;
        a0.x += __shfl_xor(a0.x, 32); a0.y += __shfl_xor(a0.y, 32);
        a0.z += __shfl_xor(a0.z, 32); a0.w += __shfl_xor(a0.w, 32);
        if (half == 0) {
            float4 bb = ((const float4*)bias)[fl];
            float sc = (MODE == 2) ? 1.f : inv;
            float t0 = a0.x * sc + bb.x, t1 = a0.y * sc + bb.y;
            float t2 = a0.z * sc + bb.z, t3 = a0.w * sc + bb.w;
            float4 o;
            if (MODE == 0) {
                o.x = lrelu01(t0) + t0; o.y = lrelu01(t1) + t1;
                o.z = lrelu01(t2) + t2; o.w = lrelu01(t3) + t3;
            } else {
                o.x = lrelu01(t0); o.y = lrelu01(t1);
                o.z = lrelu01(t2); o.w = lrelu01(t3);
            }
            ((float4*)(out + (size_t)g * CC))[fl] = o;
        }
        return;
    }
    // ---- fallback deg > DMAX (scalar f16 reads; practically never taken) ----
    {
        float wsc0 = 0.f;
        float m = 0.f, inv = 1.f, adv = 0.f;
        if (MODE != 2) {
            adv = adst[g];
            m = -3.0e38f;
            for (int j = s0 + lane; j < s1; j += 64)
                m = fmaxf(m, lrelu2(aux[bN + csr_row[bE + j]] + adv));
            m = wmax(m);
            float ssum = 0.f;
            for (int j = s0 + lane; j < s1; j += 64)
                ssum += __expf(lrelu2(aux[bN + csr_row[bE + j]] + adv) - m);
            ssum = wsum(ssum);
            inv = 1.f / (ssum + 1e-16f);
        } else {
            wsc0 = aux[g];
        }
        float x0 = 0.f, x1 = 0.f;
        for (int j = s0; j < s1; ++j) {
            int r = csr_row[bE + j];
            float wj = (MODE == 2) ? aux[bN + r]
                                   : __expf(lrelu2(aux[bN + r] + adv) - m) * inv;
            const f16* Hr = Hp + (size_t)(bN + r) * CC;
            x0 = fmaf(wj, (float)Hr[lane * 2], x0);
            x1 = fmaf(wj, (float)Hr[lane * 2 + 1], x1);
        }
        if (MODE == 2) { x0 *= wsc0; x1 *= wsc0; }
        float t0 = x0 + bias[lane * 2], t1 = x1 + bias[lane * 2 + 1];
        float2 o;
        if (MODE == 0) { o.x = lrelu01(t0) + t0; o.y = lrelu01(t1) + t1; }
        else           { o.x = lrelu01(t0);      o.y = lrelu01(t1); }
        ((float2*)(out + (size_t)g * CC))[lane] = o;
    }
}

// ---- GCN2 per-node dot ----
__global__ __launch_bounds__(256) void k_out_dot(
    const float* __restrict__ h, const float* __restrict__ Wout,
    float* __restrict__ p) {
    int wid = threadIdx.x >> 6, lane = threadIdx.x & 63;
    int g = blockIdx.x * 4 + wid;
    float2 h2 = ((const float2*)(h + (size_t)g * CC))[lane];
    float2 w2 = ((const float2*)Wout)[lane];
    float x = wsum(h2.x * w2.x + h2.y * w2.y);
    if (lane == 0) p[g] = x;
}

__global__ __launch_bounds__(256) void k_out_agg(
    const float* __restrict__ p, const float* __restrict__ dinv,
    const int* __restrict__ rowptr, const int* __restrict__ csr_row,
    const float* __restrict__ bout, float* __restrict__ gv) {
    int wid = threadIdx.x >> 6, lane = threadIdx.x & 63;
    int g = xcd_swz(blockIdx.x, gridDim.x) * 4 + wid;
    int b = g / NN, v = g - b * NN;
    int s0 = rowptr[b * RP + v], s1 = rowptr[b * RP + v + 1];
    float acc = 0.f;
    for (int j = s0 + lane; j < s1; j += 64) {
        int r = csr_row[b * ET + j];
        acc += dinv[b * NN + r] * p[b * NN + r];
    }
    acc = wsum(acc);
    if (lane == 0) gv[g] = lrelu01(acc * dinv[g] + bout[0]);
}

__global__ __launch_bounds__(128) void k_fc(
    const float* __restrict__ gv, const float* __restrict__ W1,
    const float* __restrict__ b1, const float* __restrict__ W2,
    const float* __restrict__ b2, float* __restrict__ outp) {
    __shared__ float gs[NN];
    __shared__ float s1[CC];
    int b = blockIdx.x, tx = threadIdx.x;
    for (int v = tx; v < NN; v += 128) gs[v] = gv[b * NN + v];
    __syncthreads();
    float acc = 0.f;
    for (int v = 0; v < NN; ++v) acc = fmaf(gs[v], W1[v * CC + tx], acc);
    float t = lrelu01(acc + b1[tx]);
    s1[tx] = t;
    __syncthreads();
    float acc2 = 0.f;
#pragma unroll
    for (int k = 0; k < CC; ++k) acc2 = fmaf(s1[k], W2[k * CC + tx], acc2);
    outp[b * CC + tx] = acc2 + b2[tx];
}

extern "C" void kernel_launch(void* const* d_in, const int* in_sizes, int n_in,
                              void* d_out, int out_size, void* d_ws, size_t ws_size,
                              hipStream_t stream) {
    const int*   feature  = (const int*)d_in[0];
    const int*   edges    = (const int*)d_in[1];
    const float* poi      = (const float*)d_in[3];
    const float* cat      = (const float*)d_in[4];
    const float* lat      = (const float*)d_in[5];
    const float* lon      = (const float*)d_in[6];
    const float* W_in     = (const float*)d_in[7];
    const float* b_in     = (const float*)d_in[8];
    const float* gat_W    = (const float*)d_in[9];
    const float* gat_asrc = (const float*)d_in[10];
    const float* gat_adst = (const float*)d_in[11];
    const float* gat_b    = (const float*)d_in[12];
    const float* W_out    = (const float*)d_in[13];
    const float* b_out    = (const float*)d_in[14];
    const float* W_fc1    = (const float*)d_in[15];
    const float* b_fc1    = (const float*)d_in[16];
    const float* W_fc2    = (const float*)d_in[17];
    const float* b_fc2    = (const float*)d_in[18];
    float* outp = (float*)d_out;

    char* ws = (char*)d_ws;
    size_t off = 0;
    auto take = [&](size_t bytes) -> char* {
        char* pp = ws + off;
        off = (off + bytes + 255) & ~(size_t)255;
        return pp;
    };
    int*   row32  = (int*)take((size_t)BB * ET * 4);
    int*   col32  = (int*)take((size_t)BB * ET * 4);
    int*   csr    = (int*)take((size_t)BB * ET * 4);
    int*   rowptr = (int*)take((size_t)BB * RP * 4);
    int*   cursor = (int*)take((size_t)BB * RP * 4);
    float* dinv   = (float*)take((size_t)NBt * 4);
    float* asrc   = (float*)take((size_t)NBt * 4);
    float* adst   = (float*)take((size_t)NBt * 4);
    float* pscal  = (float*)take((size_t)NBt * 4);
    float* gvec   = (float*)take((size_t)NBt * 4);
    float* bufA   = (float*)take((size_t)NBt * CC * 4);
    f16*   bufB   = (f16*)take((size_t)NBt * CC * 2);   // f16 node features for aggs
    f16*   BWh    = (f16*)take((size_t)KSE * 8 * 64 * 8 * 2);
    f16*   BWl    = (f16*)take((size_t)KSE * 8 * 64 * 8 * 2);
    f16*   BGh    = (f16*)take((size_t)3 * 4 * 8 * 64 * 8 * 2);
    f16*   BGl    = (f16*)take((size_t)3 * 4 * 8 * 64 * 8 * 2);
    float* wsv    = (float*)take((size_t)3 * CC * 4);
    float* wdv    = (float*)take((size_t)3 * CC * 4);

    const int nE = BB * ET;
    hipMemsetAsync(dinv, 0, (size_t)NBt * 4, stream);
    k_edge_prep<<<(nE + 255) / 256, 256, 0, stream>>>(edges, row32, col32, dinv);
    k_scan<<<BB, 1024, 0, stream>>>(dinv, rowptr, cursor);
    k_scatter<<<(nE + 255) / 256, 256, 0, stream>>>(row32, col32, cursor, csr);

    k_pack_Win<<<(KSE * 8 * 64 + 255) / 256, 256, 0, stream>>>(W_in, BWh, BWl);
    k_pack_Wgat<<<(3 * 4 * 8 * 64 + 255) / 256, 256, 0, stream>>>(gat_W, BGh, BGl);
    k_wsd<<<3, 128, 0, stream>>>(gat_W, gat_asrc, gat_adst, wsv, wdv);

    k_embed_gemm<<<NBt / 32, 256, 0, stream>>>(feature, poi, cat, lat, lon, BWh, BWl, bufB);
    k_agg<2><<<NBt / 4, 256, 0, stream>>>(bufB, dinv, nullptr, rowptr, csr, b_in, bufA);

    for (int i = 0; i < 3; ++i) {
        const f16* bh = BGh + (size_t)i * 4 * 8 * 64 * 8;
        const f16* bl = BGl + (size_t)i * 4 * 8 * 64 * 8;
        const float* ws_i = wsv + (size_t)i * CC;
        const float* wd_i = wdv + (size_t)i * CC;
        const float* gb = gat_b + (size_t)i * CC;
        k_gat_gemm<<<NBt / 32, 256, 0, stream>>>(bufA, bh, bl, ws_i, wd_i, bufB, asrc, adst);
        k_agg<0><<<NBt / 4, 256, 0, stream>>>(bufB, asrc, adst, rowptr, csr, gb, bufA);
        k_gat_gemm<<<NBt / 32, 256, 0, stream>>>(bufA, bh, bl, ws_i, wd_i, bufB, asrc, adst);
        k_agg<1><<<NBt / 4, 256, 0, stream>>>(bufB, asrc, adst, rowptr, csr, gb, bufA);
    }

    k_out_dot<<<NBt / 4, 256, 0, stream>>>(bufA, W_out, pscal);
    k_out_agg<<<NBt / 4, 256, 0, stream>>>(pscal, dinv, rowptr, csr, b_out, gvec);
    k_fc<<<BB, 128, 0, stream>>>(gvec, W_fc1, b_fc1, W_fc2, b_fc2, outp);
}

// Round 8
// 430.833 us; speedup vs baseline: 3.0399x; 1.0261x over previous
//
#include <hip/hip_runtime.h>

// UserGraphNet: B=64 graphs, n=714 nodes, E=16384 edges (+n self loops), C=128.
// Round 7: embed GEMM restructured algebraically — project embedding TABLES through
// W_in slices once (4 dense MFMA GEMMs, 19021 rows total, no gathers), then per-node
// assemble = sum of 4 L2-resident projection rows. Replaces the 43us gather-GEMM.
// GAT GEMMs split-f16 MFMA; f16 node features; CSR aggs; XCD swizzle throughout.

#define BB 64
#define NN 714
#define EE 16384
#define ET (EE + NN)          // 17098 edges incl self loops
#define NBt (BB * NN)         // 45696 total nodes
#define CC 128
#define RP (NN + 1)           // rowptr entries per graph
#define DMAX 128              // max degree on the fast agg path (deg~24)
#define KSP 28                // total padded k-steps across 4 table projections
#define PROJ_ROWS 19021       // 5099 + 400 + 7128 + 6394

typedef _Float16 f16;
typedef __attribute__((ext_vector_type(8))) _Float16 f16x8;
typedef __attribute__((ext_vector_type(4))) _Float16 f16x4;
typedef __attribute__((ext_vector_type(4))) float f32x4;

__device__ __forceinline__ float lrelu01(float x) { return x > 0.f ? x : 0.01f * x; }
__device__ __forceinline__ float lrelu2(float x)  { return x > 0.f ? x : 0.2f  * x; }

__device__ __forceinline__ float wsum(float x) {
#pragma unroll
    for (int o = 32; o > 0; o >>= 1) x += __shfl_xor(x, o);
    return x;
}
__device__ __forceinline__ float wmax(float x) {
#pragma unroll
    for (int o = 32; o > 0; o >>= 1) x = fmaxf(x, __shfl_xor(x, o));
    return x;
}

// Bijective XCD swizzle (m204)
__device__ __forceinline__ int xcd_swz(int bid, int nwg) {
    int q = nwg >> 3, r = nwg & 7;
    int x = bid & 7, l = bid >> 3;
    int base = (x < r) ? x * (q + 1) : r * (q + 1) + (x - r) * q;
    return base + l;
}

// ---- edge prep ----
__global__ void k_edge_prep(const int* __restrict__ edges, int* __restrict__ row32,
                            int* __restrict__ col32, float* __restrict__ deg) {
    int idx = blockIdx.x * blockDim.x + threadIdx.x;
    if (idx >= BB * ET) return;
    int b = idx / ET, e = idx - b * ET;
    int r, c;
    if (e < EE) { r = edges[b * 2 * EE + e]; c = edges[b * 2 * EE + EE + e]; }
    else        { r = c = e - EE; }
    row32[idx] = r; col32[idx] = c;
    atomicAdd(&deg[b * NN + c], 1.0f);
}

__global__ void k_scan(float* degdinv, int* __restrict__ rowptr, int* __restrict__ cursor) {
    __shared__ int s[1024];
    int b = blockIdx.x, v = threadIdx.x;
    int cnt = 0; float d = 0.f;
    if (v < NN) { d = degdinv[b * NN + v]; cnt = (int)d; }
    s[v] = cnt;
    __syncthreads();
    for (int off = 1; off < 1024; off <<= 1) {
        int val = (v >= off) ? s[v - off] : 0;
        __syncthreads();
        s[v] += val;
        __syncthreads();
    }
    if (v < NN) {
        degdinv[b * NN + v] = d > 0.f ? rsqrtf(d) : 0.f;
        rowptr[b * RP + v + 1] = s[v];
        cursor[b * RP + v] = (v == 0) ? 0 : s[v - 1];
    }
    if (v == 0) rowptr[b * RP] = 0;
}

__global__ void k_scatter(const int* __restrict__ row32, const int* __restrict__ col32,
                          int* __restrict__ cursor, int* __restrict__ csr_row) {
    int idx = blockIdx.x * blockDim.x + threadIdx.x;
    if (idx >= BB * ET) return;
    int b = idx / ET;
    int c = col32[idx];
    int slot = atomicAdd(&cursor[b * RP + c], 1);
    csr_row[b * ET + slot] = row32[idx];
}

// ---- pack W_in table-slices into frag layout hi/lo (K padded per table) ----
// tables: poi K=300 (10 ks), cat K=100 (4 ks), lat K=200 (7 ks), lon K=200 (7 ks)
__global__ void k_pack_Wseg(const float* __restrict__ W, f16* __restrict__ Bh, f16* __restrict__ Bl) {
    int idx = blockIdx.x * 256 + threadIdx.x;     // (ks_global*8+ct)*64 + lane
    if (idx >= KSP * 8 * 64) return;
    int lane = idx & 63, tc = idx >> 6;
    int ct = tc & 7, ks = tc >> 3;
    int t  = ks < 10 ? 0 : ks < 14 ? 1 : ks < 21 ? 2 : 3;
    int k0 = t == 0 ? 0 : t == 1 ? 10 : t == 2 ? 14 : 21;
    const int Ktab[4] = {300, 100, 200, 200};
    const int Koff[4] = {0, 300, 400, 600};
    int ksl = ks - k0;
    f16x8 ph, pl;
#pragma unroll
    for (int j = 0; j < 8; ++j) {
        int k = ksl * 32 + (lane >> 4) * 8 + j;
        int c = ct * 16 + (lane & 15);
        float v = (k < Ktab[t]) ? W[(size_t)(Koff[t] + k) * CC + c] : 0.f;
        f16 hi = (f16)v;
        ph[j] = hi; pl[j] = (f16)(v - (float)hi);
    }
    *(f16x8*)(Bh + (size_t)idx * 8) = ph;
    *(f16x8*)(Bl + (size_t)idx * 8) = pl;
}

// ---- pack gat_W into frag layout hi/lo ----
__global__ void k_pack_Wgat(const float* __restrict__ W, f16* __restrict__ Bh, f16* __restrict__ Bl) {
    int idx = blockIdx.x * 256 + threadIdx.x;     // ((i*4+ks)*8+ct)*64 + lane
    if (idx >= 3 * 4 * 8 * 64) return;
    int lane = idx & 63, tc = idx >> 6;
    int ct = tc & 7; tc >>= 3;
    int ks = tc & 3, li = tc >> 2;
    const float* Wl = W + (size_t)li * CC * CC;
    f16x8 ph, pl;
#pragma unroll
    for (int j = 0; j < 8; ++j) {
        int k = ks * 32 + (lane >> 4) * 8 + j;
        int c = ct * 16 + (lane & 15);
        float v = Wl[k * CC + c];
        f16 hi = (f16)v;
        ph[j] = hi; pl[j] = (f16)(v - (float)hi);
    }
    *(f16x8*)(Bh + (size_t)idx * 8) = ph;
    *(f16x8*)(Bl + (size_t)idx * 8) = pl;
}

// ---- w_s = W.a_src, w_d = W.a_dst per layer ----
__global__ void k_wsd(const float* __restrict__ gat_W, const float* __restrict__ a_s,
                      const float* __restrict__ a_d, float* __restrict__ wsv, float* __restrict__ wdv) {
    int i = blockIdx.x, k = threadIdx.x;
    const float* W = gat_W + (size_t)i * CC * CC;
    float s = 0.f, d = 0.f;
#pragma unroll 4
    for (int c = 0; c < CC; ++c) {
        float w = W[k * CC + c];
        s = fmaf(w, a_s[i * CC + c], s);
        d = fmaf(w, a_d[i * CC + c], d);
    }
    wsv[i * CC + k] = s; wdv[i * CC + k] = d;
}

// ---- table-projection GEMM: P[t] = table[t] @ W_in[Koff:Koff+K]  (f32 out) ----
// grid 596 blocks x 32 rows; no LDS, no barriers — direct global A-frag loads.
__global__ __launch_bounds__(256) void k_proj(
    const float* __restrict__ poi, const float* __restrict__ cat,
    const float* __restrict__ lat, const float* __restrict__ lon,
    const f16* __restrict__ Bh, const f16* __restrict__ Bl,
    float* __restrict__ P) {
    int bid = blockIdx.x;
    int t, r0;
    if (bid < 160)      { t = 0; r0 = bid * 32; }
    else if (bid < 173) { t = 1; r0 = (bid - 160) * 32; }
    else if (bid < 396) { t = 2; r0 = (bid - 173) * 32; }
    else                { t = 3; r0 = (bid - 396) * 32; }
    const int Ktab[4] = {300, 100, 200, 200};
    const int Rtab[4] = {5099, 400, 7128, 6394};
    const int Rofs[4] = {0, 5099, 5499, 12627};
    const int Kst[4]  = {10, 4, 7, 7};
    const int Bks0[4] = {0, 10, 14, 21};
    const float* tab = t == 0 ? poi : t == 1 ? cat : t == 2 ? lat : lon;
    int K = Ktab[t], R = Rtab[t], nks = Kst[t], bks = Bks0[t];
    int lane = threadIdx.x & 63, w = threadIdx.x >> 6;
    int ct0 = w * 2;
    f32x4 acc[2][2];
#pragma unroll
    for (int rt = 0; rt < 2; ++rt)
#pragma unroll
        for (int c = 0; c < 2; ++c) acc[rt][c] = (f32x4){0.f, 0.f, 0.f, 0.f};

    for (int ks = 0; ks < nks; ++ks) {
        int kbase = ks * 32 + (lane >> 4) * 8;
        f16x8 ah[2], al[2];
#pragma unroll
        for (int rt = 0; rt < 2; ++rt) {
            int row = r0 + rt * 16 + (lane & 15);
            int rowc = row < R ? row : R - 1;
            const float* rp = tab + (size_t)rowc * K;
            float v[8];
            if (kbase + 8 <= K) {
                float4 x0 = ((const float4*)(rp + kbase))[0];
                float4 x1 = ((const float4*)(rp + kbase))[1];
                v[0] = x0.x; v[1] = x0.y; v[2] = x0.z; v[3] = x0.w;
                v[4] = x1.x; v[5] = x1.y; v[6] = x1.z; v[7] = x1.w;
            } else if (kbase >= K) {
#pragma unroll
                for (int m = 0; m < 8; ++m) v[m] = 0.f;   // W is zero-padded there too
            } else {
#pragma unroll
                for (int m = 0; m < 8; ++m) v[m] = (kbase + m < K) ? rp[kbase + m] : 0.f;
            }
#pragma unroll
            for (int j = 0; j < 8; ++j) {
                f16 hi = (f16)v[j];
                ah[rt][j] = hi; al[rt][j] = (f16)(v[j] - (float)hi);
            }
        }
#pragma unroll
        for (int cti = 0; cti < 2; ++cti) {
            int ct = ct0 + cti;
            f16x8 bh = *(const f16x8*)(Bh + ((size_t)((bks + ks) * 8 + ct) * 64 + lane) * 8);
            f16x8 bl = *(const f16x8*)(Bl + ((size_t)((bks + ks) * 8 + ct) * 64 + lane) * 8);
#pragma unroll
            for (int rt = 0; rt < 2; ++rt) {
                acc[rt][cti] = __builtin_amdgcn_mfma_f32_16x16x32_f16(ah[rt], bh, acc[rt][cti], 0, 0, 0);
                acc[rt][cti] = __builtin_amdgcn_mfma_f32_16x16x32_f16(al[rt], bh, acc[rt][cti], 0, 0, 0);
                acc[rt][cti] = __builtin_amdgcn_mfma_f32_16x16x32_f16(ah[rt], bl, acc[rt][cti], 0, 0, 0);
            }
        }
    }
#pragma unroll
    for (int rt = 0; rt < 2; ++rt)
#pragma unroll
        for (int cti = 0; cti < 2; ++cti)
#pragma unroll
            for (int i = 0; i < 4; ++i) {
                int row = r0 + rt * 16 + (lane >> 4) * 4 + i;
                if (row < R) {
                    int col = (ct0 + cti) * 16 + (lane & 15);
                    P[(size_t)(Rofs[t] + row) * CC + col] = acc[rt][cti][i];
                }
            }
}

// ---- per-node assembly: bufB[g] = P_poi[f0] + P_cat[f1] + P_lat[f3] + P_lon[f4] ----
__global__ __launch_bounds__(256) void k_assemble(
    const int* __restrict__ feature, const float* __restrict__ P,
    f16* __restrict__ out) {
    int tid = xcd_swz(blockIdx.x, gridDim.x) * 256 + threadIdx.x;
    int g = tid >> 4, c8 = (tid & 15) * 8;
    const int* f = feature + (size_t)g * 5;
    const float4* p0 = (const float4*)(P + (size_t)f[0] * CC + c8);
    const float4* p1 = (const float4*)(P + (size_t)(5099 + f[1]) * CC + c8);
    const float4* p2 = (const float4*)(P + (size_t)(5499 + f[3]) * CC + c8);
    const float4* p3 = (const float4*)(P + (size_t)(12627 + f[4]) * CC + c8);
    float4 a0 = p0[0], a1 = p0[1];
    float4 b0 = p1[0], b1 = p1[1];
    float4 c0 = p2[0], c1 = p2[1];
    float4 d0 = p3[0], d1 = p3[1];
    f16x8 r;
    r[0] = (f16)(a0.x + b0.x + c0.x + d0.x);
    r[1] = (f16)(a0.y + b0.y + c0.y + d0.y);
    r[2] = (f16)(a0.z + b0.z + c0.z + d0.z);
    r[3] = (f16)(a0.w + b0.w + c0.w + d0.w);
    r[4] = (f16)(a1.x + b1.x + c1.x + d1.x);
    r[5] = (f16)(a1.y + b1.y + c1.y + d1.y);
    r[6] = (f16)(a1.z + b1.z + c1.z + d1.z);
    r[7] = (f16)(a1.w + b1.w + c1.w + d1.w);
    *(f16x8*)(out + (size_t)g * CC + c8) = r;
}

// ---- GAT gemm, 32-row tile; asrc/adst fused; f16 Hp out ----
__global__ __launch_bounds__(256) void k_gat_gemm(
    const float* __restrict__ hin, const f16* __restrict__ Bh, const f16* __restrict__ Bl,
    const float* __restrict__ wsv, const float* __restrict__ wdv,
    f16* __restrict__ Hp, float* __restrict__ asrc, float* __restrict__ adst) {
    __shared__ __align__(16) f16 Ah[32 * 128];
    __shared__ __align__(16) f16 Al[32 * 128];
    __shared__ float reds[256], redd[256];
    int t = threadIdx.x;
    int g0 = xcd_swz(blockIdx.x, gridDim.x) * 32;
    int lane = t & 63, w = t >> 6;
    int sr = t >> 3, skb = (t & 7) * 16;
    const float4* hrow = (const float4*)(hin + (size_t)(g0 + sr) * CC + skb);
    float v[16];
    float ps = 0.f, pd = 0.f;
#pragma unroll
    for (int q = 0; q < 4; ++q) {
        float4 x = hrow[q];
        v[q * 4 + 0] = x.x; v[q * 4 + 1] = x.y; v[q * 4 + 2] = x.z; v[q * 4 + 3] = x.w;
    }
#pragma unroll
    for (int m = 0; m < 16; ++m) {
        ps = fmaf(v[m], wsv[skb + m], ps);
        pd = fmaf(v[m], wdv[skb + m], pd);
    }
#pragma unroll
    for (int q = 0; q < 2; ++q) {
        f16x8 ph, pl;
#pragma unroll
        for (int j = 0; j < 8; ++j) {
            float x = v[q * 8 + j];
            f16 hi = (f16)x;
            ph[j] = hi; pl[j] = (f16)(x - (float)hi);
        }
        int kg = (skb >> 3) + q;
        int ad = sr * 128 + ((kg ^ (sr & 7)) << 3);
        *(f16x8*)&Ah[ad] = ph; *(f16x8*)&Al[ad] = pl;
    }
    reds[t] = ps; redd[t] = pd;
    __syncthreads();
    if (t < 32) {
        float s = 0.f, d = 0.f;
#pragma unroll
        for (int q = 0; q < 8; ++q) { s += reds[t * 8 + q]; d += redd[t * 8 + q]; }
        asrc[g0 + t] = s; adst[g0 + t] = d;
    }
    f32x4 acc[2][2];
#pragma unroll
    for (int rt = 0; rt < 2; ++rt)
#pragma unroll
        for (int c = 0; c < 2; ++c) acc[rt][c] = (f32x4){0.f, 0.f, 0.f, 0.f};
    int ct0 = w * 2;
#pragma unroll
    for (int ks = 0; ks < 4; ++ks) {
        f16x8 ahf[2], alf[2];
#pragma unroll
        for (int rt = 0; rt < 2; ++rt) {
            int r = rt * 16 + (lane & 15);
            int kg = (lane >> 4) + ks * 4;
            int ad = r * 128 + ((kg ^ (r & 7)) << 3);
            ahf[rt] = *(const f16x8*)&Ah[ad];
            alf[rt] = *(const f16x8*)&Al[ad];
        }
#pragma unroll
        for (int cti = 0; cti < 2; ++cti) {
            int ct = ct0 + cti;
            f16x8 bh = *(const f16x8*)(Bh + ((size_t)(ks * 8 + ct) * 64 + lane) * 8);
            f16x8 bl = *(const f16x8*)(Bl + ((size_t)(ks * 8 + ct) * 64 + lane) * 8);
#pragma unroll
            for (int rt = 0; rt < 2; ++rt) {
                acc[rt][cti] = __builtin_amdgcn_mfma_f32_16x16x32_f16(ahf[rt], bh, acc[rt][cti], 0, 0, 0);
                acc[rt][cti] = __builtin_amdgcn_mfma_f32_16x16x32_f16(alf[rt], bh, acc[rt][cti], 0, 0, 0);
                acc[rt][cti] = __builtin_amdgcn_mfma_f32_16x16x32_f16(ahf[rt], bl, acc[rt][cti], 0, 0, 0);
            }
        }
    }
#pragma unroll
    for (int rt = 0; rt < 2; ++rt)
#pragma unroll
        for (int cti = 0; cti < 2; ++cti)
#pragma unroll
            for (int i = 0; i < 4; ++i) {
                int row = g0 + rt * 16 + (lane >> 4) * 4 + i;
                int col = (ct0 + cti) * 16 + (lane & 15);
                Hp[(size_t)row * CC + col] = (f16)acc[rt][cti][i];
            }
}

// ---- unified aggregate kernel (H input is f16) ----
// MODE 0: GAT, out = lrelu01(t)+t. MODE 1: GAT, out = lrelu01(t). MODE 2: GCN.
template <int MODE>
__global__ __launch_bounds__(256) void k_agg(
    const f16* __restrict__ Hp, const float* __restrict__ aux,
    const float* __restrict__ adst, const int* __restrict__ rowptr,
    const int* __restrict__ csr_row, const float* __restrict__ bias,
    float* __restrict__ out) {
    __shared__ float2 pr[4][DMAX];
    int wid = threadIdx.x >> 6, lane = threadIdx.x & 63;
    int g = xcd_swz(blockIdx.x, gridDim.x) * 4 + wid;
    int b = g / NN, v = g - b * NN;
    int bN = b * NN, bE = b * ET;
    int s0 = rowptr[b * RP + v], s1 = rowptr[b * RP + v + 1];
    int deg = s1 - s0;
    int half = lane >> 5, fl = lane & 31;

    if (deg <= DMAX) {
        float inv = 1.f;
        // ---- phase 1: per-edge (weight, row) into LDS ----
        if (MODE == 2) {
            float dv = aux[g];
            for (int jj = lane; jj < deg; jj += 64) {
                int r = csr_row[bE + s0 + jj];
                pr[wid][jj] = make_float2(aux[bN + r] * dv, __int_as_float(r));
            }
        } else {
            float adv = adst[g];
            float m = -3.0e38f;
            for (int jj = lane; jj < deg; jj += 64) {
                int r = csr_row[bE + s0 + jj];
                float e = lrelu2(aux[bN + r] + adv);
                pr[wid][jj] = make_float2(e, __int_as_float(r));
                m = fmaxf(m, e);
            }
            m = wmax(m);
            float ss = 0.f;
            for (int jj = lane; jj < deg; jj += 64) {
                float w = __expf(pr[wid][jj].x - m);
                ss += w;
                pr[wid][jj].x = w;
            }
            ss = wsum(ss);
            inv = 1.f / (ss + 1e-16f);   // applied once at the end
        }
        // ---- phase 2: f16x4 gather (8B/lane), 8 edges in flight ----
        const f16* Hb = Hp + (size_t)bN * CC;
        float4 a0 = {0.f, 0.f, 0.f, 0.f}, a1 = a0, a2 = a0, a3 = a0;
        int jj = 0;
        for (; jj + 7 < deg; jj += 8) {
            float2 p0 = pr[wid][jj + half];
            float2 p1 = pr[wid][jj + 2 + half];
            float2 p2 = pr[wid][jj + 4 + half];
            float2 p3 = pr[wid][jj + 6 + half];
            f16x4 h0 = *(const f16x4*)(Hb + (size_t)__float_as_int(p0.y) * CC + fl * 4);
            f16x4 h1 = *(const f16x4*)(Hb + (size_t)__float_as_int(p1.y) * CC + fl * 4);
            f16x4 h2 = *(const f16x4*)(Hb + (size_t)__float_as_int(p2.y) * CC + fl * 4);
            f16x4 h3 = *(const f16x4*)(Hb + (size_t)__float_as_int(p3.y) * CC + fl * 4);
            a0.x = fmaf(p0.x, (float)h0[0], a0.x); a0.y = fmaf(p0.x, (float)h0[1], a0.y);
            a0.z = fmaf(p0.x, (float)h0[2], a0.z); a0.w = fmaf(p0.x, (float)h0[3], a0.w);
            a1.x = fmaf(p1.x, (float)h1[0], a1.x); a1.y = fmaf(p1.x, (float)h1[1], a1.y);
            a1.z = fmaf(p1.x, (float)h1[2], a1.z); a1.w = fmaf(p1.x, (float)h1[3], a1.w);
            a2.x = fmaf(p2.x, (float)h2[0], a2.x); a2.y = fmaf(p2.x, (float)h2[1], a2.y);
            a2.z = fmaf(p2.x, (float)h2[2], a2.z); a2.w = fmaf(p2.x, (float)h2[3], a2.w);
            a3.x = fmaf(p3.x, (float)h3[0], a3.x); a3.y = fmaf(p3.x, (float)h3[1], a3.y);
            a3.z = fmaf(p3.x, (float)h3[2], a3.z); a3.w = fmaf(p3.x, (float)h3[3], a3.w);
        }
        for (; jj + 3 < deg; jj += 4) {
            float2 p0 = pr[wid][jj + half];
            float2 p1 = pr[wid][jj + 2 + half];
            f16x4 h0 = *(const f16x4*)(Hb + (size_t)__float_as_int(p0.y) * CC + fl * 4);
            f16x4 h1 = *(const f16x4*)(Hb + (size_t)__float_as_int(p1.y) * CC + fl * 4);
            a0.x = fmaf(p0.x, (float)h0[0], a0.x); a0.y = fmaf(p0.x, (float)h0[1], a0.y);
            a0.z = fmaf(p0.x, (float)h0[2], a0.z); a0.w = fmaf(p0.x, (float)h0[3], a0.w);
            a1.x = fmaf(p1.x, (float)h1[0], a1.x); a1.y = fmaf(p1.x, (float)h1[1], a1.y);
            a1.z = fmaf(p1.x, (float)h1[2], a1.z); a1.w = fmaf(p1.x, (float)h1[3], a1.w);
        }
        for (; jj + 1 < deg; jj += 2) {
            float2 p0 = pr[wid][jj + half];
            f16x4 h0 = *(const f16x4*)(Hb + (size_t)__float_as_int(p0.y) * CC + fl * 4);
            a0.x = fmaf(p0.x, (float)h0[0], a0.x); a0.y = fmaf(p0.x, (float)h0[1], a0.y);
            a0.z = fmaf(p0.x, (float)h0[2], a0.z); a0.w = fmaf(p0.x, (float)h0[3], a0.w);
        }
        if (jj < deg && half == 0) {
            float2 p0 = pr[wid][jj];
            f16x4 h0 = *(const f16x4*)(Hb + (size_t)__float_as_int(p0.y) * CC + fl * 4);
            a0.x = fmaf(p0.x, (float)h0[0], a0.x); a0.y = fmaf(p0.x, (float)h0[1], a0.y);
            a0.z = fmaf(p0.x, (float)h0[2], a0.z); a0.w = fmaf(p0.x, (float)h0[3], a0.w);
        }
        a0.x += a1.x + a2.x + a3.x; a0.y += a1.y + a2.y + a3.y;
        a0.z += a1.z + a2.z + a3.z; a0.w += a1.w + a2.w + a3.w;
        a0.x += __shfl_xor(a0.x, 32); a0.y += __shfl_xor(a0.y, 32);
        a0.z += __shfl_xor(a0.z, 32); a0.w += __shfl_xor(a0.w, 32);
        if (half == 0) {
            float4 bb = ((const float4*)bias)[fl];
            float sc = (MODE == 2) ? 1.f : inv;
            float t0 = a0.x * sc + bb.x, t1 = a0.y * sc + bb.y;
            float t2 = a0.z * sc + bb.z, t3 = a0.w * sc + bb.w;
            float4 o;
            if (MODE == 0) {
                o.x = lrelu01(t0) + t0; o.y = lrelu01(t1) + t1;
                o.z = lrelu01(t2) + t2; o.w = lrelu01(t3) + t3;
            } else {
                o.x = lrelu01(t0); o.y = lrelu01(t1);
                o.z = lrelu01(t2); o.w = lrelu01(t3);
            }
            ((float4*)(out + (size_t)g * CC))[fl] = o;
        }
        return;
    }
    // ---- fallback deg > DMAX (scalar f16 reads; practically never taken) ----
    {
        float wsc0 = 0.f;
        float m = 0.f, inv = 1.f, adv = 0.f;
        if (MODE != 2) {
            adv = adst[g];
            m = -3.0e38f;
            for (int j = s0 + lane; j < s1; j += 64)
                m = fmaxf(m, lrelu2(aux[bN + csr_row[bE + j]] + adv));
            m = wmax(m);
            float ssum = 0.f;
            for (int j = s0 + lane; j < s1; j += 64)
                ssum += __expf(lrelu2(aux[bN + csr_row[bE + j]] + adv) - m);
            ssum = wsum(ssum);
            inv = 1.f / (ssum + 1e-16f);
        } else {
            wsc0 = aux[g];
        }
        float x0 = 0.f, x1 = 0.f;
        for (int j = s0; j < s1; ++j) {
            int r = csr_row[bE + j];
            float wj = (MODE == 2) ? aux[bN + r]
                                   : __expf(lrelu2(aux[bN + r] + adv) - m) * inv;
            const f16* Hr = Hp + (size_t)(bN + r) * CC;
            x0 = fmaf(wj, (float)Hr[lane * 2], x0);
            x1 = fmaf(wj, (float)Hr[lane * 2 + 1], x1);
        }
        if (MODE == 2) { x0 *= wsc0; x1 *= wsc0; }
        float t0 = x0 + bias[lane * 2], t1 = x1 + bias[lane * 2 + 1];
        float2 o;
        if (MODE == 0) { o.x = lrelu01(t0) + t0; o.y = lrelu01(t1) + t1; }
        else           { o.x = lrelu01(t0);      o.y = lrelu01(t1); }
        ((float2*)(out + (size_t)g * CC))[lane] = o;
    }
}

// ---- GCN2 per-node dot ----
__global__ __launch_bounds__(256) void k_out_dot(
    const float* __restrict__ h, const float* __restrict__ Wout,
    float* __restrict__ p) {
    int wid = threadIdx.x >> 6, lane = threadIdx.x & 63;
    int g = blockIdx.x * 4 + wid;
    float2 h2 = ((const float2*)(h + (size_t)g * CC))[lane];
    float2 w2 = ((const float2*)Wout)[lane];
    float x = wsum(h2.x * w2.x + h2.y * w2.y);
    if (lane == 0) p[g] = x;
}

__global__ __launch_bounds__(256) void k_out_agg(
    const float* __restrict__ p, const float* __restrict__ dinv,
    const int* __restrict__ rowptr, const int* __restrict__ csr_row,
    const float* __restrict__ bout, float* __restrict__ gv) {
    int wid = threadIdx.x >> 6, lane = threadIdx.x & 63;
    int g = xcd_swz(blockIdx.x, gridDim.x) * 4 + wid;
    int b = g / NN, v = g - b * NN;
    int s0 = rowptr[b * RP + v], s1 = rowptr[b * RP + v + 1];
    float acc = 0.f;
    for (int j = s0 + lane; j < s1; j += 64) {
        int r = csr_row[b * ET + j];
        acc += dinv[b * NN + r] * p[b * NN + r];
    }
    acc = wsum(acc);
    if (lane == 0) gv[g] = lrelu01(acc * dinv[g] + bout[0]);
}

__global__ __launch_bounds__(128) void k_fc(
    const float* __restrict__ gv, const float* __restrict__ W1,
    const float* __restrict__ b1, const float* __restrict__ W2,
    const float* __restrict__ b2, float* __restrict__ outp) {
    __shared__ float gs[NN];
    __shared__ float s1[CC];
    int b = blockIdx.x, tx = threadIdx.x;
    for (int v = tx; v < NN; v += 128) gs[v] = gv[b * NN + v];
    __syncthreads();
    float acc = 0.f;
    for (int v = 0; v < NN; ++v) acc = fmaf(gs[v], W1[v * CC + tx], acc);
    float t = lrelu01(acc + b1[tx]);
    s1[tx] = t;
    __syncthreads();
    float acc2 = 0.f;
#pragma unroll
    for (int k = 0; k < CC; ++k) acc2 = fmaf(s1[k], W2[k * CC + tx], acc2);
    outp[b * CC + tx] = acc2 + b2[tx];
}

extern "C" void kernel_launch(void* const* d_in, const int* in_sizes, int n_in,
                              void* d_out, int out_size, void* d_ws, size_t ws_size,
                              hipStream_t stream) {
    const int*   feature  = (const int*)d_in[0];
    const int*   edges    = (const int*)d_in[1];
    const float* poi      = (const float*)d_in[3];
    const float* cat      = (const float*)d_in[4];
    const float* lat      = (const float*)d_in[5];
    const float* lon      = (const float*)d_in[6];
    const float* W_in     = (const float*)d_in[7];
    const float* b_in     = (const float*)d_in[8];
    const float* gat_W    = (const float*)d_in[9];
    const float* gat_asrc = (const float*)d_in[10];
    const float* gat_adst = (const float*)d_in[11];
    const float* gat_b    = (const float*)d_in[12];
    const float* W_out    = (const float*)d_in[13];
    const float* b_out    = (const float*)d_in[14];
    const float* W_fc1    = (const float*)d_in[15];
    const float* b_fc1    = (const float*)d_in[16];
    const float* W_fc2    = (const float*)d_in[17];
    const float* b_fc2    = (const float*)d_in[18];
    float* outp = (float*)d_out;

    char* ws = (char*)d_ws;
    size_t off = 0;
    auto take = [&](size_t bytes) -> char* {
        char* pp = ws + off;
        off = (off + bytes + 255) & ~(size_t)255;
        return pp;
    };
    int*   row32  = (int*)take((size_t)BB * ET * 4);
    int*   col32  = (int*)take((size_t)BB * ET * 4);
    int*   csr    = (int*)take((size_t)BB * ET * 4);
    int*   rowptr = (int*)take((size_t)BB * RP * 4);
    int*   cursor = (int*)take((size_t)BB * RP * 4);
    float* dinv   = (float*)take((size_t)NBt * 4);
    float* asrc   = (float*)take((size_t)NBt * 4);
    float* adst   = (float*)take((size_t)NBt * 4);
    float* pscal  = (float*)take((size_t)NBt * 4);
    float* gvec   = (float*)take((size_t)NBt * 4);
    float* bufA   = (float*)take((size_t)NBt * CC * 4);
    f16*   bufB   = (f16*)take((size_t)NBt * CC * 2);       // f16 node features
    float* P      = (float*)take((size_t)PROJ_ROWS * CC * 4); // table projections
    f16*   BWh    = (f16*)take((size_t)KSP * 8 * 64 * 8 * 2);
    f16*   BWl    = (f16*)take((size_t)KSP * 8 * 64 * 8 * 2);
    f16*   BGh    = (f16*)take((size_t)3 * 4 * 8 * 64 * 8 * 2);
    f16*   BGl    = (f16*)take((size_t)3 * 4 * 8 * 64 * 8 * 2);
    float* wsv    = (float*)take((size_t)3 * CC * 4);
    float* wdv    = (float*)take((size_t)3 * CC * 4);

    const int nE = BB * ET;
    hipMemsetAsync(dinv, 0, (size_t)NBt * 4, stream);
    k_edge_prep<<<(nE + 255) / 256, 256, 0, stream>>>(edges, row32, col32, dinv);
    k_scan<<<BB, 1024, 0, stream>>>(dinv, rowptr, cursor);
    k_scatter<<<(nE + 255) / 256, 256, 0, stream>>>(row32, col32, cursor, csr);

    k_pack_Wseg<<<(KSP * 8 * 64 + 255) / 256, 256, 0, stream>>>(W_in, BWh, BWl);
    k_pack_Wgat<<<(3 * 4 * 8 * 64 + 255) / 256, 256, 0, stream>>>(gat_W, BGh, BGl);
    k_wsd<<<3, 128, 0, stream>>>(gat_W, gat_asrc, gat_adst, wsv, wdv);

    k_proj<<<596, 256, 0, stream>>>(poi, cat, lat, lon, BWh, BWl, P);
    k_assemble<<<NBt * 16 / 256, 256, 0, stream>>>(feature, P, bufB);
    k_agg<2><<<NBt / 4, 256, 0, stream>>>(bufB, dinv, nullptr, rowptr, csr, b_in, bufA);

    for (int i = 0; i < 3; ++i) {
        const f16* bh = BGh + (size_t)i * 4 * 8 * 64 * 8;
        const f16* bl = BGl + (size_t)i * 4 * 8 * 64 * 8;
        const float* ws_i = wsv + (size_t)i * CC;
        const float* wd_i = wdv + (size_t)i * CC;
        const float* gb = gat_b + (size_t)i * CC;
        k_gat_gemm<<<NBt / 32, 256, 0, stream>>>(bufA, bh, bl, ws_i, wd_i, bufB, asrc, adst);
        k_agg<0><<<NBt / 4, 256, 0, stream>>>(bufB, asrc, adst, rowptr, csr, gb, bufA);
        k_gat_gemm<<<NBt / 32, 256, 0, stream>>>(bufA, bh, bl, ws_i, wd_i, bufB, asrc, adst);
        k_agg<1><<<NBt / 4, 256, 0, stream>>>(bufB, asrc, adst, rowptr, csr, gb, bufA);
    }

    k_out_dot<<<NBt / 4, 256, 0, stream>>>(bufA, W_out, pscal);
    k_out_agg<<<NBt / 4, 256, 0, stream>>>(pscal, dinv, rowptr, csr, b_out, gvec);
    k_fc<<<BB, 128, 0, stream>>>(gvec, W_fc1, b_fc1, W_fc2, b_fc2, outp);
}

// Round 9
// 411.081 us; speedup vs baseline: 3.1860x; 1.0481x over previous
//
#include <hip/hip_runtime.h>

// UserGraphNet: B=64 graphs, n=714 nodes, E=16384 edges (+n self loops), C=128.
// Round 8: fused per-graph CSR build (LDS histogram+scan+scatter, zero global
// atomics, replaces 3 kernels); agg phase-2 with quarter-wave f16x8 gathers
// (4 edges/instruction, 16 in flight, zero-pad sentinel edges kill tail code).
// Embed path = table projection + assemble (round 7). Split-f16 MFMA GEMMs.

#define BB 64
#define NN 714
#define EE 16384
#define ET (EE + NN)          // 17098 edges incl self loops
#define NBt (BB * NN)         // 45696 total nodes
#define CC 128
#define RP (NN + 1)           // rowptr entries per graph
#define DMAX 128              // max degree on the fast agg path (deg~24)
#define KSP 28                // total padded k-steps across 4 table projections
#define PROJ_ROWS 19021       // 5099 + 400 + 7128 + 6394

typedef _Float16 f16;
typedef __attribute__((ext_vector_type(8))) _Float16 f16x8;
typedef __attribute__((ext_vector_type(4))) _Float16 f16x4;
typedef __attribute__((ext_vector_type(4))) float f32x4;
typedef __attribute__((ext_vector_type(8))) float f32x8;

__device__ __forceinline__ float lrelu01(float x) { return x > 0.f ? x : 0.01f * x; }
__device__ __forceinline__ float lrelu2(float x)  { return x > 0.f ? x : 0.2f  * x; }

__device__ __forceinline__ float wsum(float x) {
#pragma unroll
    for (int o = 32; o > 0; o >>= 1) x += __shfl_xor(x, o);
    return x;
}
__device__ __forceinline__ float wmax(float x) {
#pragma unroll
    for (int o = 32; o > 0; o >>= 1) x = fmaxf(x, __shfl_xor(x, o));
    return x;
}

// Bijective XCD swizzle (m204)
__device__ __forceinline__ int xcd_swz(int bid, int nwg) {
    int q = nwg >> 3, r = nwg & 7;
    int x = bid & 7, l = bid >> 3;
    int base = (x < r) ? x * (q + 1) : r * (q + 1) + (x - r) * q;
    return base + l;
}

// ---- fused CSR build: one block per graph; LDS histogram + scan + scatter ----
__global__ __launch_bounds__(1024) void k_build(
    const int* __restrict__ edges, int* __restrict__ rowptr,
    int* __restrict__ csr_row, float* __restrict__ dinv) {
    __shared__ int degs[NN];
    __shared__ int scan[1024];
    __shared__ int curs[NN];
    int b = blockIdx.x, t = threadIdx.x;
    if (t < NN) degs[t] = 0;
    __syncthreads();
    int rr[17], cc[17];
#pragma unroll
    for (int q = 0; q < 17; ++q) {
        int e = q * 1024 + t;
        int r = -1, c = -1;
        if (e < ET) {
            if (e < EE) { r = edges[b * 2 * EE + e]; c = edges[b * 2 * EE + EE + e]; }
            else        { r = c = e - EE; }
            atomicAdd(&degs[c], 1);
        }
        rr[q] = r; cc[q] = c;
    }
    __syncthreads();
    int cnt = (t < NN) ? degs[t] : 0;
    scan[t] = cnt;
    __syncthreads();
    for (int off = 1; off < 1024; off <<= 1) {
        int val = (t >= off) ? scan[t - off] : 0;
        __syncthreads();
        scan[t] += val;
        __syncthreads();
    }
    if (t < NN) {
        rowptr[b * RP + t + 1] = scan[t];
        curs[t] = scan[t] - cnt;                       // exclusive prefix
        dinv[b * NN + t] = cnt > 0 ? rsqrtf((float)cnt) : 0.f;
    }
    if (t == 0) rowptr[b * RP] = 0;
    __syncthreads();
#pragma unroll
    for (int q = 0; q < 17; ++q) {
        if (cc[q] >= 0) {
            int slot = atomicAdd(&curs[cc[q]], 1);     // LDS atomic, no contention cost
            csr_row[b * ET + slot] = rr[q];
        }
    }
}

// ---- pack W_in table-slices into frag layout hi/lo (K padded per table) ----
__global__ void k_pack_Wseg(const float* __restrict__ W, f16* __restrict__ Bh, f16* __restrict__ Bl) {
    int idx = blockIdx.x * 256 + threadIdx.x;     // (ks_global*8+ct)*64 + lane
    if (idx >= KSP * 8 * 64) return;
    int lane = idx & 63, tc = idx >> 6;
    int ct = tc & 7, ks = tc >> 3;
    int t  = ks < 10 ? 0 : ks < 14 ? 1 : ks < 21 ? 2 : 3;
    int k0 = t == 0 ? 0 : t == 1 ? 10 : t == 2 ? 14 : 21;
    const int Ktab[4] = {300, 100, 200, 200};
    const int Koff[4] = {0, 300, 400, 600};
    int ksl = ks - k0;
    f16x8 ph, pl;
#pragma unroll
    for (int j = 0; j < 8; ++j) {
        int k = ksl * 32 + (lane >> 4) * 8 + j;
        int c = ct * 16 + (lane & 15);
        float v = (k < Ktab[t]) ? W[(size_t)(Koff[t] + k) * CC + c] : 0.f;
        f16 hi = (f16)v;
        ph[j] = hi; pl[j] = (f16)(v - (float)hi);
    }
    *(f16x8*)(Bh + (size_t)idx * 8) = ph;
    *(f16x8*)(Bl + (size_t)idx * 8) = pl;
}

// ---- pack gat_W into frag layout hi/lo ----
__global__ void k_pack_Wgat(const float* __restrict__ W, f16* __restrict__ Bh, f16* __restrict__ Bl) {
    int idx = blockIdx.x * 256 + threadIdx.x;     // ((i*4+ks)*8+ct)*64 + lane
    if (idx >= 3 * 4 * 8 * 64) return;
    int lane = idx & 63, tc = idx >> 6;
    int ct = tc & 7; tc >>= 3;
    int ks = tc & 3, li = tc >> 2;
    const float* Wl = W + (size_t)li * CC * CC;
    f16x8 ph, pl;
#pragma unroll
    for (int j = 0; j < 8; ++j) {
        int k = ks * 32 + (lane >> 4) * 8 + j;
        int c = ct * 16 + (lane & 15);
        float v = Wl[k * CC + c];
        f16 hi = (f16)v;
        ph[j] = hi; pl[j] = (f16)(v - (float)hi);
    }
    *(f16x8*)(Bh + (size_t)idx * 8) = ph;
    *(f16x8*)(Bl + (size_t)idx * 8) = pl;
}

// ---- w_s = W.a_src, w_d = W.a_dst per layer ----
__global__ void k_wsd(const float* __restrict__ gat_W, const float* __restrict__ a_s,
                      const float* __restrict__ a_d, float* __restrict__ wsv, float* __restrict__ wdv) {
    int i = blockIdx.x, k = threadIdx.x;
    const float* W = gat_W + (size_t)i * CC * CC;
    float s = 0.f, d = 0.f;
#pragma unroll 4
    for (int c = 0; c < CC; ++c) {
        float w = W[k * CC + c];
        s = fmaf(w, a_s[i * CC + c], s);
        d = fmaf(w, a_d[i * CC + c], d);
    }
    wsv[i * CC + k] = s; wdv[i * CC + k] = d;
}

// ---- table-projection GEMM: P[t] = table[t] @ W_in[Koff:Koff+K]  (f32 out) ----
__global__ __launch_bounds__(256) void k_proj(
    const float* __restrict__ poi, const float* __restrict__ cat,
    const float* __restrict__ lat, const float* __restrict__ lon,
    const f16* __restrict__ Bh, const f16* __restrict__ Bl,
    float* __restrict__ P) {
    int bid = blockIdx.x;
    int t, r0;
    if (bid < 160)      { t = 0; r0 = bid * 32; }
    else if (bid < 173) { t = 1; r0 = (bid - 160) * 32; }
    else if (bid < 396) { t = 2; r0 = (bid - 173) * 32; }
    else                { t = 3; r0 = (bid - 396) * 32; }
    const int Ktab[4] = {300, 100, 200, 200};
    const int Rtab[4] = {5099, 400, 7128, 6394};
    const int Rofs[4] = {0, 5099, 5499, 12627};
    const int Kst[4]  = {10, 4, 7, 7};
    const int Bks0[4] = {0, 10, 14, 21};
    const float* tab = t == 0 ? poi : t == 1 ? cat : t == 2 ? lat : lon;
    int K = Ktab[t], R = Rtab[t], nks = Kst[t], bks = Bks0[t];
    int lane = threadIdx.x & 63, w = threadIdx.x >> 6;
    int ct0 = w * 2;
    f32x4 acc[2][2];
#pragma unroll
    for (int rt = 0; rt < 2; ++rt)
#pragma unroll
        for (int c = 0; c < 2; ++c) acc[rt][c] = (f32x4){0.f, 0.f, 0.f, 0.f};

    for (int ks = 0; ks < nks; ++ks) {
        int kbase = ks * 32 + (lane >> 4) * 8;
        f16x8 ah[2], al[2];
#pragma unroll
        for (int rt = 0; rt < 2; ++rt) {
            int row = r0 + rt * 16 + (lane & 15);
            int rowc = row < R ? row : R - 1;
            const float* rp = tab + (size_t)rowc * K;
            float v[8];
            if (kbase + 8 <= K) {
                float4 x0 = ((const float4*)(rp + kbase))[0];
                float4 x1 = ((const float4*)(rp + kbase))[1];
                v[0] = x0.x; v[1] = x0.y; v[2] = x0.z; v[3] = x0.w;
                v[4] = x1.x; v[5] = x1.y; v[6] = x1.z; v[7] = x1.w;
            } else if (kbase >= K) {
#pragma unroll
                for (int m = 0; m < 8; ++m) v[m] = 0.f;
            } else {
#pragma unroll
                for (int m = 0; m < 8; ++m) v[m] = (kbase + m < K) ? rp[kbase + m] : 0.f;
            }
#pragma unroll
            for (int j = 0; j < 8; ++j) {
                f16 hi = (f16)v[j];
                ah[rt][j] = hi; al[rt][j] = (f16)(v[j] - (float)hi);
            }
        }
#pragma unroll
        for (int cti = 0; cti < 2; ++cti) {
            int ct = ct0 + cti;
            f16x8 bh = *(const f16x8*)(Bh + ((size_t)((bks + ks) * 8 + ct) * 64 + lane) * 8);
            f16x8 bl = *(const f16x8*)(Bl + ((size_t)((bks + ks) * 8 + ct) * 64 + lane) * 8);
#pragma unroll
            for (int rt = 0; rt < 2; ++rt) {
                acc[rt][cti] = __builtin_amdgcn_mfma_f32_16x16x32_f16(ah[rt], bh, acc[rt][cti], 0, 0, 0);
                acc[rt][cti] = __builtin_amdgcn_mfma_f32_16x16x32_f16(al[rt], bh, acc[rt][cti], 0, 0, 0);
                acc[rt][cti] = __builtin_amdgcn_mfma_f32_16x16x32_f16(ah[rt], bl, acc[rt][cti], 0, 0, 0);
            }
        }
    }
#pragma unroll
    for (int rt = 0; rt < 2; ++rt)
#pragma unroll
        for (int cti = 0; cti < 2; ++cti)
#pragma unroll
            for (int i = 0; i < 4; ++i) {
                int row = r0 + rt * 16 + (lane >> 4) * 4 + i;
                if (row < R) {
                    int col = (ct0 + cti) * 16 + (lane & 15);
                    P[(size_t)(Rofs[t] + row) * CC + col] = acc[rt][cti][i];
                }
            }
}

// ---- per-node assembly: bufB[g] = P_poi[f0] + P_cat[f1] + P_lat[f3] + P_lon[f4] ----
__global__ __launch_bounds__(256) void k_assemble(
    const int* __restrict__ feature, const float* __restrict__ P,
    f16* __restrict__ out) {
    int tid = xcd_swz(blockIdx.x, gridDim.x) * 256 + threadIdx.x;
    int g = tid >> 4, c8 = (tid & 15) * 8;
    const int* f = feature + (size_t)g * 5;
    const float4* p0 = (const float4*)(P + (size_t)f[0] * CC + c8);
    const float4* p1 = (const float4*)(P + (size_t)(5099 + f[1]) * CC + c8);
    const float4* p2 = (const float4*)(P + (size_t)(5499 + f[3]) * CC + c8);
    const float4* p3 = (const float4*)(P + (size_t)(12627 + f[4]) * CC + c8);
    float4 a0 = p0[0], a1 = p0[1];
    float4 b0 = p1[0], b1 = p1[1];
    float4 c0 = p2[0], c1 = p2[1];
    float4 d0 = p3[0], d1 = p3[1];
    f16x8 r;
    r[0] = (f16)(a0.x + b0.x + c0.x + d0.x);
    r[1] = (f16)(a0.y + b0.y + c0.y + d0.y);
    r[2] = (f16)(a0.z + b0.z + c0.z + d0.z);
    r[3] = (f16)(a0.w + b0.w + c0.w + d0.w);
    r[4] = (f16)(a1.x + b1.x + c1.x + d1.x);
    r[5] = (f16)(a1.y + b1.y + c1.y + d1.y);
    r[6] = (f16)(a1.z + b1.z + c1.z + d1.z);
    r[7] = (f16)(a1.w + b1.w + c1.w + d1.w);
    *(f16x8*)(out + (size_t)g * CC + c8) = r;
}

// ---- GAT gemm, 32-row tile; asrc/adst fused; f16 Hp out ----
__global__ __launch_bounds__(256) void k_gat_gemm(
    const float* __restrict__ hin, const f16* __restrict__ Bh, const f16* __restrict__ Bl,
    const float* __restrict__ wsv, const float* __restrict__ wdv,
    f16* __restrict__ Hp, float* __restrict__ asrc, float* __restrict__ adst) {
    __shared__ __align__(16) f16 Ah[32 * 128];
    __shared__ __align__(16) f16 Al[32 * 128];
    __shared__ float reds[256], redd[256];
    int t = threadIdx.x;
    int g0 = xcd_swz(blockIdx.x, gridDim.x) * 32;
    int lane = t & 63, w = t >> 6;
    int sr = t >> 3, skb = (t & 7) * 16;
    const float4* hrow = (const float4*)(hin + (size_t)(g0 + sr) * CC + skb);
    float v[16];
    float ps = 0.f, pd = 0.f;
#pragma unroll
    for (int q = 0; q < 4; ++q) {
        float4 x = hrow[q];
        v[q * 4 + 0] = x.x; v[q * 4 + 1] = x.y; v[q * 4 + 2] = x.z; v[q * 4 + 3] = x.w;
    }
#pragma unroll
    for (int m = 0; m < 16; ++m) {
        ps = fmaf(v[m], wsv[skb + m], ps);
        pd = fmaf(v[m], wdv[skb + m], pd);
    }
#pragma unroll
    for (int q = 0; q < 2; ++q) {
        f16x8 ph, pl;
#pragma unroll
        for (int j = 0; j < 8; ++j) {
            float x = v[q * 8 + j];
            f16 hi = (f16)x;
            ph[j] = hi; pl[j] = (f16)(x - (float)hi);
        }
        int kg = (skb >> 3) + q;
        int ad = sr * 128 + ((kg ^ (sr & 7)) << 3);
        *(f16x8*)&Ah[ad] = ph; *(f16x8*)&Al[ad] = pl;
    }
    reds[t] = ps; redd[t] = pd;
    __syncthreads();
    if (t < 32) {
        float s = 0.f, d = 0.f;
#pragma unroll
        for (int q = 0; q < 8; ++q) { s += reds[t * 8 + q]; d += redd[t * 8 + q]; }
        asrc[g0 + t] = s; adst[g0 + t] = d;
    }
    f32x4 acc[2][2];
#pragma unroll
    for (int rt = 0; rt < 2; ++rt)
#pragma unroll
        for (int c = 0; c < 2; ++c) acc[rt][c] = (f32x4){0.f, 0.f, 0.f, 0.f};
    int ct0 = w * 2;
#pragma unroll
    for (int ks = 0; ks < 4; ++ks) {
        f16x8 ahf[2], alf[2];
#pragma unroll
        for (int rt = 0; rt < 2; ++rt) {
            int r = rt * 16 + (lane & 15);
            int kg = (lane >> 4) + ks * 4;
            int ad = r * 128 + ((kg ^ (r & 7)) << 3);
            ahf[rt] = *(const f16x8*)&Ah[ad];
            alf[rt] = *(const f16x8*)&Al[ad];
        }
#pragma unroll
        for (int cti = 0; cti < 2; ++cti) {
            int ct = ct0 + cti;
            f16x8 bh = *(const f16x8*)(Bh + ((size_t)(ks * 8 + ct) * 64 + lane) * 8);
            f16x8 bl = *(const f16x8*)(Bl + ((size_t)(ks * 8 + ct) * 64 + lane) * 8);
#pragma unroll
            for (int rt = 0; rt < 2; ++rt) {
                acc[rt][cti] = __builtin_amdgcn_mfma_f32_16x16x32_f16(ahf[rt], bh, acc[rt][cti], 0, 0, 0);
                acc[rt][cti] = __builtin_amdgcn_mfma_f32_16x16x32_f16(alf[rt], bh, acc[rt][cti], 0, 0, 0);
                acc[rt][cti] = __builtin_amdgcn_mfma_f32_16x16x32_f16(ahf[rt], bl, acc[rt][cti], 0, 0, 0);
            }
        }
    }
#pragma unroll
    for (int rt = 0; rt < 2; ++rt)
#pragma unroll
        for (int cti = 0; cti < 2; ++cti)
#pragma unroll
            for (int i = 0; i < 4; ++i) {
                int row = g0 + rt * 16 + (lane >> 4) * 4 + i;
                int col = (ct0 + cti) * 16 + (lane & 15);
                Hp[(size_t)row * CC + col] = (f16)acc[rt][cti][i];
            }
}

// ---- unified aggregate kernel (H input is f16) ----
// MODE 0: GAT, out = lrelu01(t)+t. MODE 1: GAT, out = lrelu01(t). MODE 2: GCN.
// Phase 1 pads pr[] to a multiple of 4 with zero-weight edges at row 0, so
// phase 2 is a branch-free quarter-wave f16x8 gather (4 edges per instruction).
template <int MODE>
__global__ __launch_bounds__(256) void k_agg(
    const f16* __restrict__ Hp, const float* __restrict__ aux,
    const float* __restrict__ adst, const int* __restrict__ rowptr,
    const int* __restrict__ csr_row, const float* __restrict__ bias,
    float* __restrict__ out) {
    __shared__ float2 pr[4][DMAX];
    int wid = threadIdx.x >> 6, lane = threadIdx.x & 63;
    int g = xcd_swz(blockIdx.x, gridDim.x) * 4 + wid;
    int b = g / NN, v = g - b * NN;
    int bN = b * NN, bE = b * ET;
    int s0 = rowptr[b * RP + v], s1 = rowptr[b * RP + v + 1];
    int deg = s1 - s0;

    if (deg <= DMAX) {
        int degp = (deg + 3) & ~3;                 // pad to multiple of 4
        float inv = 1.f;
        // ---- phase 1: per-edge (weight, row) into LDS ----
        if (MODE == 2) {
            float dv = aux[g];
            for (int jj = lane; jj < degp; jj += 64) {
                if (jj < deg) {
                    int r = csr_row[bE + s0 + jj];
                    pr[wid][jj] = make_float2(aux[bN + r] * dv, __int_as_float(r));
                } else {
                    pr[wid][jj] = make_float2(0.f, __int_as_float(0));
                }
            }
        } else {
            float adv = adst[g];
            float m = -3.0e38f;
            for (int jj = lane; jj < degp; jj += 64) {
                if (jj < deg) {
                    int r = csr_row[bE + s0 + jj];
                    float e = lrelu2(aux[bN + r] + adv);
                    pr[wid][jj] = make_float2(e, __int_as_float(r));
                    m = fmaxf(m, e);
                } else {
                    pr[wid][jj] = make_float2(-3.0e38f, __int_as_float(0));
                }
            }
            m = wmax(m);
            float ss = 0.f;
            for (int jj = lane; jj < degp; jj += 64) {
                float w = __expf(pr[wid][jj].x - m);   // pads: exp(-huge) = 0
                ss += w;
                pr[wid][jj].x = w;
            }
            ss = wsum(ss);
            inv = 1.f / (ss + 1e-16f);                 // applied once at the end
        }
        // ---- phase 2: quarter-wave f16x8 gather (16B/lane), 16 edges in flight ----
        int qt = lane >> 4, ql = lane & 15;
        const f16* Hb = Hp + (size_t)bN * CC;
        f32x8 a0 = {0,0,0,0,0,0,0,0}, a1 = a0, a2 = a0, a3 = a0;
        int jj = 0;
        for (; jj + 16 <= degp; jj += 16) {
            float2 p0 = pr[wid][jj + qt];
            float2 p1 = pr[wid][jj + 4 + qt];
            float2 p2 = pr[wid][jj + 8 + qt];
            float2 p3 = pr[wid][jj + 12 + qt];
            f16x8 h0 = *(const f16x8*)(Hb + (size_t)__float_as_int(p0.y) * CC + ql * 8);
            f16x8 h1 = *(const f16x8*)(Hb + (size_t)__float_as_int(p1.y) * CC + ql * 8);
            f16x8 h2 = *(const f16x8*)(Hb + (size_t)__float_as_int(p2.y) * CC + ql * 8);
            f16x8 h3 = *(const f16x8*)(Hb + (size_t)__float_as_int(p3.y) * CC + ql * 8);
            a0 += p0.x * __builtin_convertvector(h0, f32x8);
            a1 += p1.x * __builtin_convertvector(h1, f32x8);
            a2 += p2.x * __builtin_convertvector(h2, f32x8);
            a3 += p3.x * __builtin_convertvector(h3, f32x8);
        }
        for (; jj < degp; jj += 4) {
            float2 p0 = pr[wid][jj + qt];
            f16x8 h0 = *(const f16x8*)(Hb + (size_t)__float_as_int(p0.y) * CC + ql * 8);
            a0 += p0.x * __builtin_convertvector(h0, f32x8);
        }
        a0 += a1 + a2 + a3;
#pragma unroll
        for (int j = 0; j < 8; ++j) {
            float x = a0[j];
            x += __shfl_xor(x, 16);
            x += __shfl_xor(x, 32);
            a0[j] = x;
        }
        if (qt == 0) {
            float sc = (MODE == 2) ? 1.f : inv;
            float4 bb0 = ((const float4*)bias)[ql * 2];
            float4 bb1 = ((const float4*)bias)[ql * 2 + 1];
            float tv[8];
            tv[0] = a0[0] * sc + bb0.x; tv[1] = a0[1] * sc + bb0.y;
            tv[2] = a0[2] * sc + bb0.z; tv[3] = a0[3] * sc + bb0.w;
            tv[4] = a0[4] * sc + bb1.x; tv[5] = a0[5] * sc + bb1.y;
            tv[6] = a0[6] * sc + bb1.z; tv[7] = a0[7] * sc + bb1.w;
            float4 o0, o1;
            if (MODE == 0) {
                o0.x = lrelu01(tv[0]) + tv[0]; o0.y = lrelu01(tv[1]) + tv[1];
                o0.z = lrelu01(tv[2]) + tv[2]; o0.w = lrelu01(tv[3]) + tv[3];
                o1.x = lrelu01(tv[4]) + tv[4]; o1.y = lrelu01(tv[5]) + tv[5];
                o1.z = lrelu01(tv[6]) + tv[6]; o1.w = lrelu01(tv[7]) + tv[7];
            } else {
                o0.x = lrelu01(tv[0]); o0.y = lrelu01(tv[1]);
                o0.z = lrelu01(tv[2]); o0.w = lrelu01(tv[3]);
                o1.x = lrelu01(tv[4]); o1.y = lrelu01(tv[5]);
                o1.z = lrelu01(tv[6]); o1.w = lrelu01(tv[7]);
            }
            ((float4*)(out + (size_t)g * CC))[ql * 2]     = o0;
            ((float4*)(out + (size_t)g * CC))[ql * 2 + 1] = o1;
        }
        return;
    }
    // ---- fallback deg > DMAX (scalar f16 reads; practically never taken) ----
    {
        float wsc0 = 0.f;
        float m = 0.f, inv = 1.f, adv = 0.f;
        if (MODE != 2) {
            adv = adst[g];
            m = -3.0e38f;
            for (int j = s0 + lane; j < s1; j += 64)
                m = fmaxf(m, lrelu2(aux[bN + csr_row[bE + j]] + adv));
            m = wmax(m);
            float ssum = 0.f;
            for (int j = s0 + lane; j < s1; j += 64)
                ssum += __expf(lrelu2(aux[bN + csr_row[bE + j]] + adv) - m);
            ssum = wsum(ssum);
            inv = 1.f / (ssum + 1e-16f);
        } else {
            wsc0 = aux[g];
        }
        float x0 = 0.f, x1 = 0.f;
        for (int j = s0; j < s1; ++j) {
            int r = csr_row[bE + j];
            float wj = (MODE == 2) ? aux[bN + r]
                                   : __expf(lrelu2(aux[bN + r] + adv) - m) * inv;
            const f16* Hr = Hp + (size_t)(bN + r) * CC;
            x0 = fmaf(wj, (float)Hr[lane * 2], x0);
            x1 = fmaf(wj, (float)Hr[lane * 2 + 1], x1);
        }
        if (MODE == 2) { x0 *= wsc0; x1 *= wsc0; }
        float t0 = x0 + bias[lane * 2], t1 = x1 + bias[lane * 2 + 1];
        float2 o;
        if (MODE == 0) { o.x = lrelu01(t0) + t0; o.y = lrelu01(t1) + t1; }
        else           { o.x = lrelu01(t0);      o.y = lrelu01(t1); }
        ((float2*)(out + (size_t)g * CC))[lane] = o;
    }
}

// ---- GCN2 per-node dot ----
__global__ __launch_bounds__(256) void k_out_dot(
    const float* __restrict__ h, const float* __restrict__ Wout,
    float* __restrict__ p) {
    int wid = threadIdx.x >> 6, lane = threadIdx.x & 63;
    int g = blockIdx.x * 4 + wid;
    float2 h2 = ((const float2*)(h + (size_t)g * CC))[lane];
    float2 w2 = ((const float2*)Wout)[lane];
    float x = wsum(h2.x * w2.x + h2.y * w2.y);
    if (lane == 0) p[g] = x;
}

__global__ __launch_bounds__(256) void k_out_agg(
    const float* __restrict__ p, const float* __restrict__ dinv,
    const int* __restrict__ rowptr, const int* __restrict__ csr_row,
    const float* __restrict__ bout, float* __restrict__ gv) {
    int wid = threadIdx.x >> 6, lane = threadIdx.x & 63;
    int g = xcd_swz(blockIdx.x, gridDim.x) * 4 + wid;
    int b = g / NN, v = g - b * NN;
    int s0 = rowptr[b * RP + v], s1 = rowptr[b * RP + v + 1];
    float acc = 0.f;
    for (int j = s0 + lane; j < s1; j += 64) {
        int r = csr_row[b * ET + j];
        acc += dinv[b * NN + r] * p[b * NN + r];
    }
    acc = wsum(acc);
    if (lane == 0) gv[g] = lrelu01(acc * dinv[g] + bout[0]);
}

__global__ __launch_bounds__(128) void k_fc(
    const float* __restrict__ gv, const float* __restrict__ W1,
    const float* __restrict__ b1, const float* __restrict__ W2,
    const float* __restrict__ b2, float* __restrict__ outp) {
    __shared__ float gs[NN];
    __shared__ float s1[CC];
    int b = blockIdx.x, tx = threadIdx.x;
    for (int v = tx; v < NN; v += 128) gs[v] = gv[b * NN + v];
    __syncthreads();
    float acc = 0.f;
    for (int v = 0; v < NN; ++v) acc = fmaf(gs[v], W1[v * CC + tx], acc);
    float t = lrelu01(acc + b1[tx]);
    s1[tx] = t;
    __syncthreads();
    float acc2 = 0.f;
#pragma unroll
    for (int k = 0; k < CC; ++k) acc2 = fmaf(s1[k], W2[k * CC + tx], acc2);
    outp[b * CC + tx] = acc2 + b2[tx];
}

extern "C" void kernel_launch(void* const* d_in, const int* in_sizes, int n_in,
                              void* d_out, int out_size, void* d_ws, size_t ws_size,
                              hipStream_t stream) {
    const int*   feature  = (const int*)d_in[0];
    const int*   edges    = (const int*)d_in[1];
    const float* poi      = (const float*)d_in[3];
    const float* cat      = (const float*)d_in[4];
    const float* lat      = (const float*)d_in[5];
    const float* lon      = (const float*)d_in[6];
    const float* W_in     = (const float*)d_in[7];
    const float* b_in     = (const float*)d_in[8];
    const float* gat_W    = (const float*)d_in[9];
    const float* gat_asrc = (const float*)d_in[10];
    const float* gat_adst = (const float*)d_in[11];
    const float* gat_b    = (const float*)d_in[12];
    const float* W_out    = (const float*)d_in[13];
    const float* b_out    = (const float*)d_in[14];
    const float* W_fc1    = (const float*)d_in[15];
    const float* b_fc1    = (const float*)d_in[16];
    const float* W_fc2    = (const float*)d_in[17];
    const float* b_fc2    = (const float*)d_in[18];
    float* outp = (float*)d_out;

    char* ws = (char*)d_ws;
    size_t off = 0;
    auto take = [&](size_t bytes) -> char* {
        char* pp = ws + off;
        off = (off + bytes + 255) & ~(size_t)255;
        return pp;
    };
    int*   csr    = (int*)take((size_t)BB * ET * 4);
    int*   rowptr = (int*)take((size_t)BB * RP * 4);
    float* dinv   = (float*)take((size_t)NBt * 4);
    float* asrc   = (float*)take((size_t)NBt * 4);
    float* adst   = (float*)take((size_t)NBt * 4);
    float* pscal  = (float*)take((size_t)NBt * 4);
    float* gvec   = (float*)take((size_t)NBt * 4);
    float* bufA   = (float*)take((size_t)NBt * CC * 4);
    f16*   bufB   = (f16*)take((size_t)NBt * CC * 2);       // f16 node features
    float* P      = (float*)take((size_t)PROJ_ROWS * CC * 4); // table projections
    f16*   BWh    = (f16*)take((size_t)KSP * 8 * 64 * 8 * 2);
    f16*   BWl    = (f16*)take((size_t)KSP * 8 * 64 * 8 * 2);
    f16*   BGh    = (f16*)take((size_t)3 * 4 * 8 * 64 * 8 * 2);
    f16*   BGl    = (f16*)take((size_t)3 * 4 * 8 * 64 * 8 * 2);
    float* wsv    = (float*)take((size_t)3 * CC * 4);
    float* wdv    = (float*)take((size_t)3 * CC * 4);

    k_build<<<BB, 1024, 0, stream>>>(edges, rowptr, csr, dinv);

    k_pack_Wseg<<<(KSP * 8 * 64 + 255) / 256, 256, 0, stream>>>(W_in, BWh, BWl);
    k_pack_Wgat<<<(3 * 4 * 8 * 64 + 255) / 256, 256, 0, stream>>>(gat_W, BGh, BGl);
    k_wsd<<<3, 128, 0, stream>>>(gat_W, gat_asrc, gat_adst, wsv, wdv);

    k_proj<<<596, 256, 0, stream>>>(poi, cat, lat, lon, BWh, BWl, P);
    k_assemble<<<NBt * 16 / 256, 256, 0, stream>>>(feature, P, bufB);
    k_agg<2><<<NBt / 4, 256, 0, stream>>>(bufB, dinv, nullptr, rowptr, csr, b_in, bufA);

    for (int i = 0; i < 3; ++i) {
        const f16* bh = BGh + (size_t)i * 4 * 8 * 64 * 8;
        const f16* bl = BGl + (size_t)i * 4 * 8 * 64 * 8;
        const float* ws_i = wsv + (size_t)i * CC;
        const float* wd_i = wdv + (size_t)i * CC;
        const float* gb = gat_b + (size_t)i * CC;
        k_gat_gemm<<<NBt / 32, 256, 0, stream>>>(bufA, bh, bl, ws_i, wd_i, bufB, asrc, adst);
        k_agg<0><<<NBt / 4, 256, 0, stream>>>(bufB, asrc, adst, rowptr, csr, gb, bufA);
        k_gat_gemm<<<NBt / 32, 256, 0, stream>>>(bufA, bh, bl, ws_i, wd_i, bufB, asrc, adst);
        k_agg<1><<<NBt / 4, 256, 0, stream>>>(bufB, asrc, adst, rowptr, csr, gb, bufA);
    }

    k_out_dot<<<NBt / 4, 256, 0, stream>>>(bufA, W_out, pscal);
    k_out_agg<<<NBt / 4, 256, 0, stream>>>(pscal, dinv, rowptr, csr, b_out, gvec);
    k_fc<<<BB, 128, 0, stream>>>(gvec, W_fc1, b_fc1, W_fc2, b_fc2, outp);
}

// Round 10
// 357.218 us; speedup vs baseline: 3.6664x; 1.1508x over previous
//
#include <hip/hip_runtime.h>

// UserGraphNet: B=64 graphs, n=714 nodes, E=16384 edges (+n self loops), C=128.
// Round 9: f16 node features end-to-end (bufA f16 -> GEMM A-operand exact f16,
// no A-split: 2-term MFMA, half staging); final agg fuses the W_out dot (kills
// k_out_dot); 3 prep kernels merged into k_prep. CSR build + projection-embed
// + quarter-wave f16x8 agg gathers as round 8. XCD swizzle throughout.

#define BB 64
#define NN 714
#define EE 16384
#define ET (EE + NN)          // 17098 edges incl self loops
#define NBt (BB * NN)         // 45696 total nodes
#define CC 128
#define RP (NN + 1)           // rowptr entries per graph
#define DMAX 128              // max degree on the fast agg path (deg~24)
#define KSP 28                // total padded k-steps across 4 table projections
#define PROJ_ROWS 19021       // 5099 + 400 + 7128 + 6394

typedef _Float16 f16;
typedef __attribute__((ext_vector_type(8))) _Float16 f16x8;
typedef __attribute__((ext_vector_type(4))) float f32x4;
typedef __attribute__((ext_vector_type(8))) float f32x8;

__device__ __forceinline__ float lrelu01(float x) { return x > 0.f ? x : 0.01f * x; }
__device__ __forceinline__ float lrelu2(float x)  { return x > 0.f ? x : 0.2f  * x; }

__device__ __forceinline__ float wsum(float x) {
#pragma unroll
    for (int o = 32; o > 0; o >>= 1) x += __shfl_xor(x, o);
    return x;
}
__device__ __forceinline__ float wmax(float x) {
#pragma unroll
    for (int o = 32; o > 0; o >>= 1) x = fmaxf(x, __shfl_xor(x, o));
    return x;
}

// Bijective XCD swizzle (m204)
__device__ __forceinline__ int xcd_swz(int bid, int nwg) {
    int q = nwg >> 3, r = nwg & 7;
    int x = bid & 7, l = bid >> 3;
    int base = (x < r) ? x * (q + 1) : r * (q + 1) + (x - r) * q;
    return base + l;
}

// ---- fused CSR build: one block per graph; LDS histogram + scan + scatter ----
__global__ __launch_bounds__(1024) void k_build(
    const int* __restrict__ edges, int* __restrict__ rowptr,
    int* __restrict__ csr_row, float* __restrict__ dinv) {
    __shared__ int degs[NN];
    __shared__ int scan[1024];
    __shared__ int curs[NN];
    int b = blockIdx.x, t = threadIdx.x;
    if (t < NN) degs[t] = 0;
    __syncthreads();
    int rr[17], cc[17];
#pragma unroll
    for (int q = 0; q < 17; ++q) {
        int e = q * 1024 + t;
        int r = -1, c = -1;
        if (e < ET) {
            if (e < EE) { r = edges[b * 2 * EE + e]; c = edges[b * 2 * EE + EE + e]; }
            else        { r = c = e - EE; }
            atomicAdd(&degs[c], 1);
        }
        rr[q] = r; cc[q] = c;
    }
    __syncthreads();
    int cnt = (t < NN) ? degs[t] : 0;
    scan[t] = cnt;
    __syncthreads();
    for (int off = 1; off < 1024; off <<= 1) {
        int val = (t >= off) ? scan[t - off] : 0;
        __syncthreads();
        scan[t] += val;
        __syncthreads();
    }
    if (t < NN) {
        rowptr[b * RP + t + 1] = scan[t];
        curs[t] = scan[t] - cnt;                       // exclusive prefix
        dinv[b * NN + t] = cnt > 0 ? rsqrtf((float)cnt) : 0.f;
    }
    if (t == 0) rowptr[b * RP] = 0;
    __syncthreads();
#pragma unroll
    for (int q = 0; q < 17; ++q) {
        if (cc[q] >= 0) {
            int slot = atomicAdd(&curs[cc[q]], 1);     // LDS atomic
            csr_row[b * ET + slot] = rr[q];
        }
    }
}

// ---- merged prep: pack W_in table-slices, pack gat_W, compute w_s/w_d ----
#define NSEG (KSP * 8 * 64)
#define NGAT (3 * 4 * 8 * 64)
__global__ void k_prep(const float* __restrict__ W, const float* __restrict__ gat_W,
                       const float* __restrict__ a_s, const float* __restrict__ a_d,
                       f16* __restrict__ BWh, f16* __restrict__ BWl,
                       f16* __restrict__ BGh, f16* __restrict__ BGl,
                       float* __restrict__ wsv, float* __restrict__ wdv) {
    int idx = blockIdx.x * 256 + threadIdx.x;
    if (idx < NSEG) {
        int lane = idx & 63, tc = idx >> 6;
        int ct = tc & 7, ks = tc >> 3;
        int t  = ks < 10 ? 0 : ks < 14 ? 1 : ks < 21 ? 2 : 3;
        int k0 = t == 0 ? 0 : t == 1 ? 10 : t == 2 ? 14 : 21;
        const int Ktab[4] = {300, 100, 200, 200};
        const int Koff[4] = {0, 300, 400, 600};
        int ksl = ks - k0;
        f16x8 ph, pl;
#pragma unroll
        for (int j = 0; j < 8; ++j) {
            int k = ksl * 32 + (lane >> 4) * 8 + j;
            int c = ct * 16 + (lane & 15);
            float v = (k < Ktab[t]) ? W[(size_t)(Koff[t] + k) * CC + c] : 0.f;
            f16 hi = (f16)v;
            ph[j] = hi; pl[j] = (f16)(v - (float)hi);
        }
        *(f16x8*)(BWh + (size_t)idx * 8) = ph;
        *(f16x8*)(BWl + (size_t)idx * 8) = pl;
    } else if (idx < NSEG + NGAT) {
        int i2 = idx - NSEG;
        int lane = i2 & 63, tc = i2 >> 6;
        int ct = tc & 7; tc >>= 3;
        int ks = tc & 3, li = tc >> 2;
        const float* Wl = gat_W + (size_t)li * CC * CC;
        f16x8 ph, pl;
#pragma unroll
        for (int j = 0; j < 8; ++j) {
            int k = ks * 32 + (lane >> 4) * 8 + j;
            int c = ct * 16 + (lane & 15);
            float v = Wl[k * CC + c];
            f16 hi = (f16)v;
            ph[j] = hi; pl[j] = (f16)(v - (float)hi);
        }
        *(f16x8*)(BGh + (size_t)i2 * 8) = ph;
        *(f16x8*)(BGl + (size_t)i2 * 8) = pl;
    } else if (idx < NSEG + NGAT + 3 * CC) {
        int i2 = idx - NSEG - NGAT;
        int i = i2 >> 7, k = i2 & 127;
        const float* Wl = gat_W + (size_t)i * CC * CC;
        float s = 0.f, d = 0.f;
#pragma unroll 4
        for (int c = 0; c < CC; ++c) {
            float w = Wl[k * CC + c];
            s = fmaf(w, a_s[i * CC + c], s);
            d = fmaf(w, a_d[i * CC + c], d);
        }
        wsv[i * CC + k] = s; wdv[i * CC + k] = d;
    }
}

// ---- table-projection GEMM: P[t] = table[t] @ W_in[Koff:Koff+K]  (f32 out) ----
__global__ __launch_bounds__(256) void k_proj(
    const float* __restrict__ poi, const float* __restrict__ cat,
    const float* __restrict__ lat, const float* __restrict__ lon,
    const f16* __restrict__ Bh, const f16* __restrict__ Bl,
    float* __restrict__ P) {
    int bid = blockIdx.x;
    int t, r0;
    if (bid < 160)      { t = 0; r0 = bid * 32; }
    else if (bid < 173) { t = 1; r0 = (bid - 160) * 32; }
    else if (bid < 396) { t = 2; r0 = (bid - 173) * 32; }
    else                { t = 3; r0 = (bid - 396) * 32; }
    const int Ktab[4] = {300, 100, 200, 200};
    const int Rtab[4] = {5099, 400, 7128, 6394};
    const int Rofs[4] = {0, 5099, 5499, 12627};
    const int Kst[4]  = {10, 4, 7, 7};
    const int Bks0[4] = {0, 10, 14, 21};
    const float* tab = t == 0 ? poi : t == 1 ? cat : t == 2 ? lat : lon;
    int K = Ktab[t], R = Rtab[t], nks = Kst[t], bks = Bks0[t];
    int lane = threadIdx.x & 63, w = threadIdx.x >> 6;
    int ct0 = w * 2;
    f32x4 acc[2][2];
#pragma unroll
    for (int rt = 0; rt < 2; ++rt)
#pragma unroll
        for (int c = 0; c < 2; ++c) acc[rt][c] = (f32x4){0.f, 0.f, 0.f, 0.f};

    for (int ks = 0; ks < nks; ++ks) {
        int kbase = ks * 32 + (lane >> 4) * 8;
        f16x8 ah[2], al[2];
#pragma unroll
        for (int rt = 0; rt < 2; ++rt) {
            int row = r0 + rt * 16 + (lane & 15);
            int rowc = row < R ? row : R - 1;
            const float* rp = tab + (size_t)rowc * K;
            float v[8];
            if (kbase + 8 <= K) {
                float4 x0 = ((const float4*)(rp + kbase))[0];
                float4 x1 = ((const float4*)(rp + kbase))[1];
                v[0] = x0.x; v[1] = x0.y; v[2] = x0.z; v[3] = x0.w;
                v[4] = x1.x; v[5] = x1.y; v[6] = x1.z; v[7] = x1.w;
            } else if (kbase >= K) {
#pragma unroll
                for (int m = 0; m < 8; ++m) v[m] = 0.f;
            } else {
#pragma unroll
                for (int m = 0; m < 8; ++m) v[m] = (kbase + m < K) ? rp[kbase + m] : 0.f;
            }
#pragma unroll
            for (int j = 0; j < 8; ++j) {
                f16 hi = (f16)v[j];
                ah[rt][j] = hi; al[rt][j] = (f16)(v[j] - (float)hi);
            }
        }
#pragma unroll
        for (int cti = 0; cti < 2; ++cti) {
            int ct = ct0 + cti;
            f16x8 bh = *(const f16x8*)(Bh + ((size_t)((bks + ks) * 8 + ct) * 64 + lane) * 8);
            f16x8 bl = *(const f16x8*)(Bl + ((size_t)((bks + ks) * 8 + ct) * 64 + lane) * 8);
#pragma unroll
            for (int rt = 0; rt < 2; ++rt) {
                acc[rt][cti] = __builtin_amdgcn_mfma_f32_16x16x32_f16(ah[rt], bh, acc[rt][cti], 0, 0, 0);
                acc[rt][cti] = __builtin_amdgcn_mfma_f32_16x16x32_f16(al[rt], bh, acc[rt][cti], 0, 0, 0);
                acc[rt][cti] = __builtin_amdgcn_mfma_f32_16x16x32_f16(ah[rt], bl, acc[rt][cti], 0, 0, 0);
            }
        }
    }
#pragma unroll
    for (int rt = 0; rt < 2; ++rt)
#pragma unroll
        for (int cti = 0; cti < 2; ++cti)
#pragma unroll
            for (int i = 0; i < 4; ++i) {
                int row = r0 + rt * 16 + (lane >> 4) * 4 + i;
                if (row < R) {
                    int col = (ct0 + cti) * 16 + (lane & 15);
                    P[(size_t)(Rofs[t] + row) * CC + col] = acc[rt][cti][i];
                }
            }
}

// ---- per-node assembly: bufB[g] = P_poi[f0] + P_cat[f1] + P_lat[f3] + P_lon[f4] ----
__global__ __launch_bounds__(256) void k_assemble(
    const int* __restrict__ feature, const float* __restrict__ P,
    f16* __restrict__ out) {
    int tid = xcd_swz(blockIdx.x, gridDim.x) * 256 + threadIdx.x;
    int g = tid >> 4, c8 = (tid & 15) * 8;
    const int* f = feature + (size_t)g * 5;
    const float4* p0 = (const float4*)(P + (size_t)f[0] * CC + c8);
    const float4* p1 = (const float4*)(P + (size_t)(5099 + f[1]) * CC + c8);
    const float4* p2 = (const float4*)(P + (size_t)(5499 + f[3]) * CC + c8);
    const float4* p3 = (const float4*)(P + (size_t)(12627 + f[4]) * CC + c8);
    float4 a0 = p0[0], a1 = p0[1];
    float4 b0 = p1[0], b1 = p1[1];
    float4 c0 = p2[0], c1 = p2[1];
    float4 d0 = p3[0], d1 = p3[1];
    f16x8 r;
    r[0] = (f16)(a0.x + b0.x + c0.x + d0.x);
    r[1] = (f16)(a0.y + b0.y + c0.y + d0.y);
    r[2] = (f16)(a0.z + b0.z + c0.z + d0.z);
    r[3] = (f16)(a0.w + b0.w + c0.w + d0.w);
    r[4] = (f16)(a1.x + b1.x + c1.x + d1.x);
    r[5] = (f16)(a1.y + b1.y + c1.y + d1.y);
    r[6] = (f16)(a1.z + b1.z + c1.z + d1.z);
    r[7] = (f16)(a1.w + b1.w + c1.w + d1.w);
    *(f16x8*)(out + (size_t)g * CC + c8) = r;
}

// ---- GAT gemm, 32-row tile; f16 input (exact A, 2-term MFMA); f16 Hp out ----
__global__ __launch_bounds__(256) void k_gat_gemm(
    const f16* __restrict__ hin, const f16* __restrict__ Bh, const f16* __restrict__ Bl,
    const float* __restrict__ wsv, const float* __restrict__ wdv,
    f16* __restrict__ Hp, float* __restrict__ asrc, float* __restrict__ adst) {
    __shared__ __align__(16) f16 Ah[32 * 128];
    __shared__ float reds[256], redd[256];
    int t = threadIdx.x;
    int g0 = xcd_swz(blockIdx.x, gridDim.x) * 32;
    int lane = t & 63, w = t >> 6;
    int sr = t >> 3, skb = (t & 7) * 16;
    const f16x8* hrow = (const f16x8*)(hin + (size_t)(g0 + sr) * CC + skb);
    f16x8 hv0 = hrow[0], hv1 = hrow[1];
    float ps = 0.f, pd = 0.f;
#pragma unroll
    for (int m = 0; m < 8; ++m) {
        ps = fmaf((float)hv0[m], wsv[skb + m], ps);
        pd = fmaf((float)hv0[m], wdv[skb + m], pd);
        ps = fmaf((float)hv1[m], wsv[skb + 8 + m], ps);
        pd = fmaf((float)hv1[m], wdv[skb + 8 + m], pd);
    }
    {
        int kg0 = (t & 7) * 2;
        int ad0 = sr * 128 + ((kg0 ^ (sr & 7)) << 3);
        int ad1 = sr * 128 + (((kg0 + 1) ^ (sr & 7)) << 3);
        *(f16x8*)&Ah[ad0] = hv0;
        *(f16x8*)&Ah[ad1] = hv1;
    }
    reds[t] = ps; redd[t] = pd;
    __syncthreads();
    if (t < 32) {
        float s = 0.f, d = 0.f;
#pragma unroll
        for (int q = 0; q < 8; ++q) { s += reds[t * 8 + q]; d += redd[t * 8 + q]; }
        asrc[g0 + t] = s; adst[g0 + t] = d;
    }
    f32x4 acc[2][2];
#pragma unroll
    for (int rt = 0; rt < 2; ++rt)
#pragma unroll
        for (int c = 0; c < 2; ++c) acc[rt][c] = (f32x4){0.f, 0.f, 0.f, 0.f};
    int ct0 = w * 2;
#pragma unroll
    for (int ks = 0; ks < 4; ++ks) {
        f16x8 ahf[2];
#pragma unroll
        for (int rt = 0; rt < 2; ++rt) {
            int r = rt * 16 + (lane & 15);
            int kg = (lane >> 4) + ks * 4;
            int ad = r * 128 + ((kg ^ (r & 7)) << 3);
            ahf[rt] = *(const f16x8*)&Ah[ad];
        }
#pragma unroll
        for (int cti = 0; cti < 2; ++cti) {
            int ct = ct0 + cti;
            f16x8 bh = *(const f16x8*)(Bh + ((size_t)(ks * 8 + ct) * 64 + lane) * 8);
            f16x8 bl = *(const f16x8*)(Bl + ((size_t)(ks * 8 + ct) * 64 + lane) * 8);
#pragma unroll
            for (int rt = 0; rt < 2; ++rt) {
                acc[rt][cti] = __builtin_amdgcn_mfma_f32_16x16x32_f16(ahf[rt], bh, acc[rt][cti], 0, 0, 0);
                acc[rt][cti] = __builtin_amdgcn_mfma_f32_16x16x32_f16(ahf[rt], bl, acc[rt][cti], 0, 0, 0);
            }
        }
    }
#pragma unroll
    for (int rt = 0; rt < 2; ++rt)
#pragma unroll
        for (int cti = 0; cti < 2; ++cti)
#pragma unroll
            for (int i = 0; i < 4; ++i) {
                int row = g0 + rt * 16 + (lane >> 4) * 4 + i;
                int col = (ct0 + cti) * 16 + (lane & 15);
                Hp[(size_t)row * CC + col] = (f16)acc[rt][cti][i];
            }
}

// ---- unified aggregate kernel (f16 H in, f16 features out) ----
// MODE 0: GAT, out = lrelu01(t)+t. MODE 1: GAT, out = lrelu01(t).
// MODE 2: GCN, out = lrelu01(t). MODE 3: GAT plain, write only pscal = out.Wout.
template <int MODE>
__global__ __launch_bounds__(256) void k_agg(
    const f16* __restrict__ Hp, const float* __restrict__ aux,
    const float* __restrict__ adst, const int* __restrict__ rowptr,
    const int* __restrict__ csr_row, const float* __restrict__ bias,
    f16* __restrict__ out, const float* __restrict__ Wout, float* __restrict__ pscal) {
    __shared__ float2 pr[4][DMAX];
    int wid = threadIdx.x >> 6, lane = threadIdx.x & 63;
    int g = xcd_swz(blockIdx.x, gridDim.x) * 4 + wid;
    int b = g / NN, v = g - b * NN;
    int bN = b * NN, bE = b * ET;
    int s0 = rowptr[b * RP + v], s1 = rowptr[b * RP + v + 1];
    int deg = s1 - s0;

    if (deg <= DMAX) {
        int degp = (deg + 3) & ~3;                 // pad to multiple of 4
        float inv = 1.f;
        // ---- phase 1: per-edge (weight, row) into LDS ----
        if (MODE == 2) {
            float dv = aux[g];
            for (int jj = lane; jj < degp; jj += 64) {
                if (jj < deg) {
                    int r = csr_row[bE + s0 + jj];
                    pr[wid][jj] = make_float2(aux[bN + r] * dv, __int_as_float(r));
                } else {
                    pr[wid][jj] = make_float2(0.f, __int_as_float(0));
                }
            }
        } else {
            float adv = adst[g];
            float m = -3.0e38f;
            for (int jj = lane; jj < degp; jj += 64) {
                if (jj < deg) {
                    int r = csr_row[bE + s0 + jj];
                    float e = lrelu2(aux[bN + r] + adv);
                    pr[wid][jj] = make_float2(e, __int_as_float(r));
                    m = fmaxf(m, e);
                } else {
                    pr[wid][jj] = make_float2(-3.0e38f, __int_as_float(0));
                }
            }
            m = wmax(m);
            float ss = 0.f;
            for (int jj = lane; jj < degp; jj += 64) {
                float w = __expf(pr[wid][jj].x - m);   // pads: exp(-huge) = 0
                ss += w;
                pr[wid][jj].x = w;
            }
            ss = wsum(ss);
            inv = 1.f / (ss + 1e-16f);                 // applied once at the end
        }
        // ---- phase 2: quarter-wave f16x8 gather (16B/lane), 16 edges in flight ----
        int qt = lane >> 4, ql = lane & 15;
        const f16* Hb = Hp + (size_t)bN * CC;
        f32x8 a0 = {0,0,0,0,0,0,0,0}, a1 = a0, a2 = a0, a3 = a0;
        int jj = 0;
        for (; jj + 16 <= degp; jj += 16) {
            float2 p0 = pr[wid][jj + qt];
            float2 p1 = pr[wid][jj + 4 + qt];
            float2 p2 = pr[wid][jj + 8 + qt];
            float2 p3 = pr[wid][jj + 12 + qt];
            f16x8 h0 = *(const f16x8*)(Hb + (size_t)__float_as_int(p0.y) * CC + ql * 8);
            f16x8 h1 = *(const f16x8*)(Hb + (size_t)__float_as_int(p1.y) * CC + ql * 8);
            f16x8 h2 = *(const f16x8*)(Hb + (size_t)__float_as_int(p2.y) * CC + ql * 8);
            f16x8 h3 = *(const f16x8*)(Hb + (size_t)__float_as_int(p3.y) * CC + ql * 8);
            a0 += p0.x * __builtin_convertvector(h0, f32x8);
            a1 += p1.x * __builtin_convertvector(h1, f32x8);
            a2 += p2.x * __builtin_convertvector(h2, f32x8);
            a3 += p3.x * __builtin_convertvector(h3, f32x8);
        }
        for (; jj < degp; jj += 4) {
            float2 p0 = pr[wid][jj + qt];
            f16x8 h0 = *(const f16x8*)(Hb + (size_t)__float_as_int(p0.y) * CC + ql * 8);
            a0 += p0.x * __builtin_convertvector(h0, f32x8);
        }
        a0 += a1 + a2 + a3;
#pragma unroll
        for (int j = 0; j < 8; ++j) {
            float x = a0[j];
            x += __shfl_xor(x, 16);
            x += __shfl_xor(x, 32);
            a0[j] = x;
        }
        if (qt == 0) {
            float sc = (MODE == 2) ? 1.f : inv;
            float4 bb0 = ((const float4*)bias)[ql * 2];
            float4 bb1 = ((const float4*)bias)[ql * 2 + 1];
            float tv[8];
            tv[0] = a0[0] * sc + bb0.x; tv[1] = a0[1] * sc + bb0.y;
            tv[2] = a0[2] * sc + bb0.z; tv[3] = a0[3] * sc + bb0.w;
            tv[4] = a0[4] * sc + bb1.x; tv[5] = a0[5] * sc + bb1.y;
            tv[6] = a0[6] * sc + bb1.z; tv[7] = a0[7] * sc + bb1.w;
            float ov[8];
#pragma unroll
            for (int j = 0; j < 8; ++j) {
                float l = lrelu01(tv[j]);
                ov[j] = (MODE == 0) ? l + tv[j] : l;
            }
            if (MODE == 3) {
                // fused out_dot: pscal[g] = ov . Wout
                float4 w0 = ((const float4*)Wout)[ql * 2];
                float4 w1 = ((const float4*)Wout)[ql * 2 + 1];
                float p = ov[0] * w0.x + ov[1] * w0.y + ov[2] * w0.z + ov[3] * w0.w
                        + ov[4] * w1.x + ov[5] * w1.y + ov[6] * w1.z + ov[7] * w1.w;
#pragma unroll
                for (int o = 8; o > 0; o >>= 1) p += __shfl_xor(p, o);
                if (ql == 0) pscal[g] = p;
            } else {
                f16x8 r;
#pragma unroll
                for (int j = 0; j < 8; ++j) r[j] = (f16)ov[j];
                *(f16x8*)(out + (size_t)g * CC + ql * 8) = r;
            }
        }
        return;
    }
    // ---- fallback deg > DMAX (scalar f16 reads; practically never taken) ----
    {
        float wsc0 = 0.f;
        float m = 0.f, inv = 1.f, adv = 0.f;
        if (MODE != 2) {
            adv = adst[g];
            m = -3.0e38f;
            for (int j = s0 + lane; j < s1; j += 64)
                m = fmaxf(m, lrelu2(aux[bN + csr_row[bE + j]] + adv));
            m = wmax(m);
            float ssum = 0.f;
            for (int j = s0 + lane; j < s1; j += 64)
                ssum += __expf(lrelu2(aux[bN + csr_row[bE + j]] + adv) - m);
            ssum = wsum(ssum);
            inv = 1.f / (ssum + 1e-16f);
        } else {
            wsc0 = aux[g];
        }
        float x0 = 0.f, x1 = 0.f;
        for (int j = s0; j < s1; ++j) {
            int r = csr_row[bE + j];
            float wj = (MODE == 2) ? aux[bN + r]
                                   : __expf(lrelu2(aux[bN + r] + adv) - m) * inv;
            const f16* Hr = Hp + (size_t)(bN + r) * CC;
            x0 = fmaf(wj, (float)Hr[lane * 2], x0);
            x1 = fmaf(wj, (float)Hr[lane * 2 + 1], x1);
        }
        if (MODE == 2) { x0 *= wsc0; x1 *= wsc0; }
        float t0 = x0 + bias[lane * 2], t1 = x1 + bias[lane * 2 + 1];
        float l0 = lrelu01(t0), l1 = lrelu01(t1);
        float o0 = (MODE == 0) ? l0 + t0 : l0;
        float o1 = (MODE == 0) ? l1 + t1 : l1;
        if (MODE == 3) {
            float p = o0 * Wout[lane * 2] + o1 * Wout[lane * 2 + 1];
            p = wsum(p);
            if (lane == 0) pscal[g] = p;
        } else {
            out[(size_t)g * CC + lane * 2]     = (f16)o0;
            out[(size_t)g * CC + lane * 2 + 1] = (f16)o1;
        }
    }
}

__global__ __launch_bounds__(256) void k_out_agg(
    const float* __restrict__ p, const float* __restrict__ dinv,
    const int* __restrict__ rowptr, const int* __restrict__ csr_row,
    const float* __restrict__ bout, float* __restrict__ gv) {
    int wid = threadIdx.x >> 6, lane = threadIdx.x & 63;
    int g = xcd_swz(blockIdx.x, gridDim.x) * 4 + wid;
    int b = g / NN, v = g - b * NN;
    int s0 = rowptr[b * RP + v], s1 = rowptr[b * RP + v + 1];
    float acc = 0.f;
    for (int j = s0 + lane; j < s1; j += 64) {
        int r = csr_row[b * ET + j];
        acc += dinv[b * NN + r] * p[b * NN + r];
    }
    acc = wsum(acc);
    if (lane == 0) gv[g] = lrelu01(acc * dinv[g] + bout[0]);
}

__global__ __launch_bounds__(128) void k_fc(
    const float* __restrict__ gv, const float* __restrict__ W1,
    const float* __restrict__ b1, const float* __restrict__ W2,
    const float* __restrict__ b2, float* __restrict__ outp) {
    __shared__ float gs[NN];
    __shared__ float s1[CC];
    int b = blockIdx.x, tx = threadIdx.x;
    for (int v = tx; v < NN; v += 128) gs[v] = gv[b * NN + v];
    __syncthreads();
    float acc = 0.f;
    for (int v = 0; v < NN; ++v) acc = fmaf(gs[v], W1[v * CC + tx], acc);
    float t = lrelu01(acc + b1[tx]);
    s1[tx] = t;
    __syncthreads();
    float acc2 = 0.f;
#pragma unroll
    for (int k = 0; k < CC; ++k) acc2 = fmaf(s1[k], W2[k * CC + tx], acc2);
    outp[b * CC + tx] = acc2 + b2[tx];
}

extern "C" void kernel_launch(void* const* d_in, const int* in_sizes, int n_in,
                              void* d_out, int out_size, void* d_ws, size_t ws_size,
                              hipStream_t stream) {
    const int*   feature  = (const int*)d_in[0];
    const int*   edges    = (const int*)d_in[1];
    const float* poi      = (const float*)d_in[3];
    const float* cat      = (const float*)d_in[4];
    const float* lat      = (const float*)d_in[5];
    const float* lon      = (const float*)d_in[6];
    const float* W_in     = (const float*)d_in[7];
    const float* b_in     = (const float*)d_in[8];
    const float* gat_W    = (const float*)d_in[9];
    const float* gat_asrc = (const float*)d_in[10];
    const float* gat_adst = (const float*)d_in[11];
    const float* gat_b    = (const float*)d_in[12];
    const float* W_out    = (const float*)d_in[13];
    const float* b_out    = (const float*)d_in[14];
    const float* W_fc1    = (const float*)d_in[15];
    const float* b_fc1    = (const float*)d_in[16];
    const float* W_fc2    = (const float*)d_in[17];
    const float* b_fc2    = (const float*)d_in[18];
    float* outp = (float*)d_out;

    char* ws = (char*)d_ws;
    size_t off = 0;
    auto take = [&](size_t bytes) -> char* {
        char* pp = ws + off;
        off = (off + bytes + 255) & ~(size_t)255;
        return pp;
    };
    int*   csr    = (int*)take((size_t)BB * ET * 4);
    int*   rowptr = (int*)take((size_t)BB * RP * 4);
    float* dinv   = (float*)take((size_t)NBt * 4);
    float* asrc   = (float*)take((size_t)NBt * 4);
    float* adst   = (float*)take((size_t)NBt * 4);
    float* pscal  = (float*)take((size_t)NBt * 4);
    float* gvec   = (float*)take((size_t)NBt * 4);
    f16*   bufA   = (f16*)take((size_t)NBt * CC * 2);       // f16 node features
    f16*   bufB   = (f16*)take((size_t)NBt * CC * 2);       // f16 node features
    float* P      = (float*)take((size_t)PROJ_ROWS * CC * 4); // table projections
    f16*   BWh    = (f16*)take((size_t)KSP * 8 * 64 * 8 * 2);
    f16*   BWl    = (f16*)take((size_t)KSP * 8 * 64 * 8 * 2);
    f16*   BGh    = (f16*)take((size_t)3 * 4 * 8 * 64 * 8 * 2);
    f16*   BGl    = (f16*)take((size_t)3 * 4 * 8 * 64 * 8 * 2);
    float* wsv    = (float*)take((size_t)3 * CC * 4);
    float* wdv    = (float*)take((size_t)3 * CC * 4);

    k_build<<<BB, 1024, 0, stream>>>(edges, rowptr, csr, dinv);

    k_prep<<<(NSEG + NGAT + 3 * CC + 255) / 256, 256, 0, stream>>>(
        W_in, gat_W, gat_asrc, gat_adst, BWh, BWl, BGh, BGl, wsv, wdv);

    k_proj<<<596, 256, 0, stream>>>(poi, cat, lat, lon, BWh, BWl, P);
    k_assemble<<<NBt * 16 / 256, 256, 0, stream>>>(feature, P, bufB);
    k_agg<2><<<NBt / 4, 256, 0, stream>>>(bufB, dinv, nullptr, rowptr, csr, b_in,
                                          bufA, nullptr, nullptr);

    for (int i = 0; i < 3; ++i) {
        const f16* bh = BGh + (size_t)i * 4 * 8 * 64 * 8;
        const f16* bl = BGl + (size_t)i * 4 * 8 * 64 * 8;
        const float* ws_i = wsv + (size_t)i * CC;
        const float* wd_i = wdv + (size_t)i * CC;
        const float* gb = gat_b + (size_t)i * CC;
        k_gat_gemm<<<NBt / 32, 256, 0, stream>>>(bufA, bh, bl, ws_i, wd_i, bufB, asrc, adst);
        k_agg<0><<<NBt / 4, 256, 0, stream>>>(bufB, asrc, adst, rowptr, csr, gb,
                                              bufA, nullptr, nullptr);
        k_gat_gemm<<<NBt / 32, 256, 0, stream>>>(bufA, bh, bl, ws_i, wd_i, bufB, asrc, adst);
        if (i < 2) {
            k_agg<1><<<NBt / 4, 256, 0, stream>>>(bufB, asrc, adst, rowptr, csr, gb,
                                                  bufA, nullptr, nullptr);
        } else {
            // last agg: fuse the W_out per-node dot, write pscal only
            k_agg<3><<<NBt / 4, 256, 0, stream>>>(bufB, asrc, adst, rowptr, csr, gb,
                                                  bufA, W_out, pscal);
        }
    }

    k_out_agg<<<NBt / 4, 256, 0, stream>>>(pscal, dinv, rowptr, csr, b_out, gvec);
    k_fc<<<BB, 128, 0, stream>>>(gvec, W_fc1, b_fc1, W_fc2, b_fc2, outp);
}